// Round 2
// baseline (563.287 us; speedup 1.0000x reference)
//
#include <hip/hip_runtime.h>

typedef unsigned int  u32;
typedef unsigned short u16;

// Problem constants: B=2, R=C=512, E=256, H=16, D=16, MSH=16. All I/O f32.
#define BB 2
#define RR 512
#define CC 512
#define EE 256
#define HH 16

__device__ __forceinline__ float b2f(u16 u) { union { u32 i; float f; } v; v.i = ((u32)u) << 16; return v.f; }
__device__ __forceinline__ float lo2f(u32 u){ union { u32 i; float f; } v; v.i = u << 16;        return v.f; }
__device__ __forceinline__ float hi2f(u32 u){ union { u32 i; float f; } v; v.i = u & 0xffff0000u; return v.f; }
__device__ __forceinline__ u16   f2b(float f){
  union { float f; u32 i; } v; v.f = f;
  u32 u = v.i;
  u32 r = (u + 0x7fffu + ((u >> 16) & 1u)) >> 16;   // round-to-nearest-even
  return (u16)r;
}

// ---------------------------------------------------------------------------
// Kernel 0: repack MLP weights into per-j f32 records of 36 floats:
//   [0..15]  = W1[j][2h]          (dot coefficients)
//   [16]     = sum_h W1[j][2h+1]  (cost coefficient; cost is head-broadcast)
//   [17..32] = W2[h][j]
// ---------------------------------------------------------------------------
__global__ void prep_wpk(const float* __restrict__ W1, const float* __restrict__ W2,
                         float* __restrict__ wpk) {
  int j = threadIdx.x;            // 256 threads, 1 block
  float osum = 0.f;
  float* w = wpk + j * 36;
#pragma unroll
  for (int h = 0; h < 16; h++) {
    w[h]      = W1[j * 32 + 2 * h];
    osum     += W1[j * 32 + 2 * h + 1];
    w[17 + h] = W2[h * 256 + j];
  }
  w[16] = osum;
  w[33] = 0.f; w[34] = 0.f; w[35] = 0.f;
}

// ---------------------------------------------------------------------------
// Generic C = A @ B^T, f32.  M,N,K multiples of 16.
// ---------------------------------------------------------------------------
__global__ void __launch_bounds__(256, 4)
gemm_bt(const float* __restrict__ A, const float* __restrict__ Bw, float* __restrict__ C,
        int M, int N, int K) {
  __shared__ float As[16][17];
  __shared__ float Bs[16][17];
  int tx = threadIdx.x, ty = threadIdx.y;
  int row  = blockIdx.y * 16 + ty;
  int col0 = blockIdx.x * 16;
  float acc = 0.f;
  for (int k0 = 0; k0 < K; k0 += 16) {
    As[ty][tx] = A[(size_t)row * K + k0 + tx];
    Bs[ty][tx] = Bw[(size_t)(col0 + ty) * K + k0 + tx];
    __syncthreads();
#pragma unroll
    for (int kk = 0; kk < 16; kk++) acc += As[ty][kk] * Bs[tx][kk];
    __syncthreads();
  }
  C[(size_t)row * N + col0 + tx] = acc;
}

// ---------------------------------------------------------------------------
// Fused QK^T * 0.25 + MixedScoreFF MLP.  One thread = 2 adjacent c-cells.
// Tile: 16 r x 32 c per block (256 threads).  Writes ms1[b][h][r][c] (bf16).
// Weights streamed from wpk (wave-uniform -> scalar-cache path).
// ---------------------------------------------------------------------------
__global__ void __launch_bounds__(256, 2)
mixed_score(const float* __restrict__ qv, const float* __restrict__ kv,
            const float* __restrict__ cost, const float* __restrict__ wpk,
            u16* __restrict__ ms1) {
  int t = threadIdx.x;
  int b = blockIdx.z;
  int r = blockIdx.y * 16 + (t >> 4);
  int c = blockIdx.x * 32 + (t & 15) * 2;

  const float4* qrow  = (const float4*)(qv + (((size_t)b * RR + r) << 9));  // q = cols [0,256)
  const float4* krow0 = (const float4*)(kv + (((size_t)b * CC + c) << 9));
  const float4* krow1 = krow0 + 128;                                        // next row (512 f32)

  float dot0[16], dot1[16];
#pragma unroll 2
  for (int h = 0; h < 16; h++) {
    float a0 = 0.f, a1 = 0.f;
#pragma unroll
    for (int dp = 0; dp < 4; dp++) {
      float4 q4 = qrow[h * 4 + dp];
      float4 k0 = krow0[h * 4 + dp];
      float4 k1 = krow1[h * 4 + dp];
      a0 += q4.x * k0.x + q4.y * k0.y + q4.z * k0.z + q4.w * k0.w;
      a1 += q4.x * k1.x + q4.y * k1.y + q4.z * k1.z + q4.w * k1.w;
    }
    dot0[h] = a0 * 0.25f;
    dot1[h] = a1 * 0.25f;
  }

  float2 cpair = *(const float2*)(cost + (size_t)b * 262144 + (size_t)r * 512 + c);
  float cost0 = cpair.x, cost1 = cpair.y;

  float acc0[16], acc1[16];
#pragma unroll
  for (int h = 0; h < 16; h++) { acc0[h] = 0.f; acc1[h] = 0.f; }

  for (int j = 0; j < 256; j++) {
    const float* w = wpk + j * 36;
    float h0 = w[16] * cost0;
    float h1 = w[16] * cost1;
#pragma unroll
    for (int h = 0; h < 16; h++) { float wv = w[h]; h0 += wv * dot0[h]; h1 += wv * dot1[h]; }
    h0 = fmaxf(h0, 0.f);
    h1 = fmaxf(h1, 0.f);
#pragma unroll
    for (int h = 0; h < 16; h++) { float wv = w[17 + h]; acc0[h] += wv * h0; acc1[h] += wv * h1; }
  }

  u32* ms1u = (u32*)ms1;
#pragma unroll
  for (int h = 0; h < 16; h++) {
    u32 pv = (u32)f2b(acc0[h]) | ((u32)f2b(acc1[h]) << 16);
    ms1u[(((size_t)(b * HH + h) * RR + r) << 8) + (c >> 1)] = pv;   // coalesced pair store
  }
}

// ---------------------------------------------------------------------------
// Masked softmax over 512 logits + weighted sum of V.  One wave per (b,h,fix).
// msRed/msFix and mRed/mFix select the ms1 / attn_mask access orientation.
// vbuf rows are 512 f32; V lives in cols [256,512); out rows are 256 f32.
// ---------------------------------------------------------------------------
__global__ void __launch_bounds__(64, 4)
softmax_av(const u16* __restrict__ ms, int msRed, int msFix,
           const int* __restrict__ mask, int mRed, int mFix,
           const float* __restrict__ vbuf, float* __restrict__ obuf) {
  int lane = threadIdx.x;
  int blk  = blockIdx.x;          // b*H*512 + h*512 + fix
  int fix  = blk & 511;
  int bh   = blk >> 9;            // b*16 + h
  int h    = bh & 15;
  int b    = bh >> 4;

  const u16* mbase = ms + (size_t)bh * 262144 + (size_t)fix * msFix;
  const int* kbase = mask + (size_t)b * 262144 + (size_t)fix * mFix;

  float lg[8];
  bool  vd[8];
#pragma unroll
  for (int i = 0; i < 8; i++) {
    int cc = i * 64 + lane;
    lg[i] = b2f(mbase[(size_t)cc * msRed]);
    vd[i] = kbase[(size_t)cc * mRed] != 0;
  }
  bool anyl = false;
#pragma unroll
  for (int i = 0; i < 8; i++) anyl |= vd[i];
  bool useMask = (__ballot(anyl) != 0ULL);   // all-masked row => drop the mask

  float m = -3.4e38f;
#pragma unroll
  for (int i = 0; i < 8; i++)
    if (!(useMask && !vd[i])) m = fmaxf(m, lg[i]);
  for (int off = 32; off; off >>= 1) m = fmaxf(m, __shfl_xor(m, off));

  float p[8], s = 0.f;
#pragma unroll
  for (int i = 0; i < 8; i++) {
    p[i] = (useMask && !vd[i]) ? 0.f : __expf(lg[i] - m);
    s += p[i];
  }
  for (int off = 32; off; off >>= 1) s += __shfl_xor(s, off);

  float acc[16];
#pragma unroll
  for (int d = 0; d < 16; d++) acc[d] = 0.f;

#pragma unroll
  for (int i = 0; i < 8; i++) {
    int cc = i * 64 + lane;
    const float4* vrow = (const float4*)(vbuf + (((size_t)b * 512 + cc) << 9) + 256 + h * 16);
    float4 u0 = vrow[0], u1 = vrow[1], u2 = vrow[2], u3 = vrow[3];
    float pi = p[i];
    acc[0]  += pi * u0.x; acc[1]  += pi * u0.y; acc[2]  += pi * u0.z; acc[3]  += pi * u0.w;
    acc[4]  += pi * u1.x; acc[5]  += pi * u1.y; acc[6]  += pi * u1.z; acc[7]  += pi * u1.w;
    acc[8]  += pi * u2.x; acc[9]  += pi * u2.y; acc[10] += pi * u2.z; acc[11] += pi * u2.w;
    acc[12] += pi * u3.x; acc[13] += pi * u3.y; acc[14] += pi * u3.z; acc[15] += pi * u3.w;
  }
#pragma unroll
  for (int off = 1; off < 64; off <<= 1) {
#pragma unroll
    for (int d = 0; d < 16; d++) acc[d] += __shfl_xor(acc[d], off);
  }
  if (lane < 16) {
    float o = acc[lane] / s;
    obuf[((size_t)b * 512 + fix) * 256 + h * 16 + lane] = o;
  }
}

// ---------------------------------------------------------------------------
extern "C" void kernel_launch(void* const* d_in, const int* in_sizes, int n_in,
                              void* d_out, int out_size, void* d_ws, size_t ws_size,
                              hipStream_t stream) {
  const float* x1    = (const float*)d_in[0];
  const float* x2    = (const float*)d_in[1];
  const int*   attn  = (const int*)d_in[2];
  const float* cost  = (const float*)d_in[3];
  const float* Wqv1  = (const float*)d_in[4];
  const float* Wkv2  = (const float*)d_in[5];
  const float* W1    = (const float*)d_in[6];
  const float* W2    = (const float*)d_in[7];
  const float* Wout1 = (const float*)d_in[8];
  const float* Wout2 = (const float*)d_in[9];
  float* out = (float*)d_out;

  char* ws = (char*)d_ws;
  float* wpk = (float*)ws;                                   //  64 KB slot
  float* qv  = (float*)(ws + (1 << 16));                     //   2 MB  [b][r][512]
  float* kv  = (float*)(ws + (1 << 16) + (2 << 20));         //   2 MB  [b][c][512]
  u16*   ms1 = (u16*)  (ws + (1 << 16) + (4 << 20));         //  16 MB  [b][h][r][c] bf16
  float* o1  = (float*)(ws + (1 << 16) + (20 << 20));        //   1 MB  [b][r][256]
  float* o2  = (float*)(ws + (1 << 16) + (21 << 20));        //   1 MB  [b][c][256]

  dim3 blk16(16, 16);

  prep_wpk<<<1, 256, 0, stream>>>(W1, W2, wpk);
  gemm_bt<<<dim3(32, 64), blk16, 0, stream>>>(x1, Wqv1, qv, 1024, 512, 256);
  gemm_bt<<<dim3(32, 64), blk16, 0, stream>>>(x2, Wkv2, kv, 1024, 512, 256);

  mixed_score<<<dim3(16, 32, 2), 256, 0, stream>>>(qv, kv, cost, wpk, ms1);

  // dir1: rows of ms1 (softmax over c), V = v2 (kv), out = o1[b][r][:]
  softmax_av<<<16384, 64, 0, stream>>>(ms1, 1, 512, attn, 1, 512, kv, o1);
  // dir2: cols of ms1 (softmax over r), V = v1 (qv), out = o2[b][c][:]
  softmax_av<<<16384, 64, 0, stream>>>(ms1, 512, 1, attn, 512, 1, qv, o2);

  gemm_bt<<<dim3(16, 64), blk16, 0, stream>>>(o1, Wout1, out, 1024, 256, 256);
  gemm_bt<<<dim3(16, 64), blk16, 0, stream>>>(o2, Wout2, out + (size_t)262144, 1024, 256, 256);
}

// Round 3
// 433.621 us; speedup vs baseline: 1.2990x; 1.2990x over previous
//
#include <hip/hip_runtime.h>

typedef unsigned int   u32;
typedef unsigned short u16;

typedef __attribute__((ext_vector_type(8))) short sh8;
typedef __attribute__((ext_vector_type(4))) float f32x4;

__device__ __forceinline__ float b2f(u16 u) { union { u32 i; float f; } v; v.i = ((u32)u) << 16; return v.f; }
__device__ __forceinline__ u16   f2b(float f){
  union { float f; u32 i; } v; v.f = f;
  u32 u = v.i;
  u32 r = (u + 0x7fffu + ((u >> 16) & 1u)) >> 16;   // RNE
  return (u16)r;
}

__device__ __forceinline__ f32x4 mfma16(uint4 a, uint4 b, f32x4 c) {
  union { uint4 u; sh8 s; } ua, ub;
  ua.u = a; ub.u = b;
  return __builtin_amdgcn_mfma_f32_16x16x32_bf16(ua.s, ub.s, c, 0, 0, 0);
}

// ---------------------------------------------------------------------------
// prep_w: build MFMA B-operand fragment buffers for W1 (K=32 input layout:
// k=2h -> dot coeff, k=2h+1 -> cost coeff) and W2 (K-chunks p with
// k = 2*col + half  <->  j = 32p + half*16 + col), each split bf16 hi/lo.
// W1B*: [16 ntiles][64 lanes] uint4 ; W2B*: [8 chunks][64 lanes] uint4.
// ---------------------------------------------------------------------------
__global__ void prep_w(const float* __restrict__ W1, const float* __restrict__ W2,
                       uint4* __restrict__ W1Bhi, uint4* __restrict__ W1Blo,
                       uint4* __restrict__ W2Bhi, uint4* __restrict__ W2Blo) {
  int tid = blockIdx.x * 256 + threadIdx.x;
  if (tid < 1024) {
    int L = tid & 63;
    int j = (tid >> 6) * 16 + (L & 15), q = L >> 4;
    u32 hw[4] = {0,0,0,0}, lw[4] = {0,0,0,0};
#pragma unroll
    for (int jj = 0; jj < 8; jj++) {
      float wv = W1[j * 32 + q * 8 + jj];
      u16 hb = f2b(wv); u16 lb = f2b(wv - b2f(hb));
      hw[jj >> 1] |= ((u32)hb) << (16 * (jj & 1));
      lw[jj >> 1] |= ((u32)lb) << (16 * (jj & 1));
    }
    W1Bhi[tid] = make_uint4(hw[0], hw[1], hw[2], hw[3]);
    W1Blo[tid] = make_uint4(lw[0], lw[1], lw[2], lw[3]);
  } else if (tid < 1536) {
    int t = tid - 1024;
    int p = t >> 6, L = t & 63;
    int head = L & 15, q = L >> 4;
    u32 hw[4] = {0,0,0,0}, lw[4] = {0,0,0,0};
#pragma unroll
    for (int jj = 0; jj < 8; jj++) {
      int col = q * 4 + (jj >> 1), half = jj & 1;
      int j = p * 32 + half * 16 + col;
      float wv = W2[head * 256 + j];
      u16 hb = f2b(wv); u16 lb = f2b(wv - b2f(hb));
      hw[jj >> 1] |= ((u32)hb) << (16 * half);
      lw[jj >> 1] |= ((u32)lb) << (16 * half);
    }
    W2Bhi[t] = make_uint4(hw[0], hw[1], hw[2], hw[3]);
    W2Blo[t] = make_uint4(lw[0], lw[1], lw[2], lw[3]);
  }
}

// ---------------------------------------------------------------------------
// gemm_bt64: C = A @ B^T, f32, 64x64 tile, 4x4 microtile per thread.
// ---------------------------------------------------------------------------
__global__ void __launch_bounds__(256)
gemm_bt64(const float* __restrict__ A, const float* __restrict__ Bw,
          float* __restrict__ C, int M, int N, int K) {
  __shared__ float As[16][64];
  __shared__ float Bs[16][64];
  int t = threadIdx.x;
  int tx = t & 15, ty = t >> 4;
  int m0 = blockIdx.y * 64, n0 = blockIdx.x * 64;
  int lrow = t >> 2, lk = (t & 3) * 4;
  float acc[4][4];
#pragma unroll
  for (int i = 0; i < 4; i++)
#pragma unroll
    for (int j = 0; j < 4; j++) acc[i][j] = 0.f;

  for (int k0 = 0; k0 < K; k0 += 16) {
    float4 av = *(const float4*)(A + (size_t)(m0 + lrow) * K + k0 + lk);
    float4 bv = *(const float4*)(Bw + (size_t)(n0 + lrow) * K + k0 + lk);
    __syncthreads();
    As[lk + 0][lrow] = av.x; As[lk + 1][lrow] = av.y;
    As[lk + 2][lrow] = av.z; As[lk + 3][lrow] = av.w;
    Bs[lk + 0][lrow] = bv.x; Bs[lk + 1][lrow] = bv.y;
    Bs[lk + 2][lrow] = bv.z; Bs[lk + 3][lrow] = bv.w;
    __syncthreads();
#pragma unroll
    for (int kk = 0; kk < 16; kk++) {
      float a_[4], b_[4];
#pragma unroll
      for (int i = 0; i < 4; i++) { a_[i] = As[kk][ty * 4 + i]; b_[i] = Bs[kk][tx * 4 + i]; }
#pragma unroll
      for (int i = 0; i < 4; i++)
#pragma unroll
        for (int j = 0; j < 4; j++) acc[i][j] += a_[i] * b_[j];
    }
  }
#pragma unroll
  for (int i = 0; i < 4; i++) {
    float4 o; o.x = acc[i][0]; o.y = acc[i][1]; o.z = acc[i][2]; o.w = acc[i][3];
    *(float4*)(C + (size_t)(m0 + ty * 4 + i) * N + n0 + tx * 4) = o;
  }
}

// ---------------------------------------------------------------------------
// ms_mfma: fused QK^T*0.25 + MixedScoreFF via MFMA.
// Block = 4 waves; wave w handles r = by*4+w, c = bx*64..+63 (4 Mtiles of 16c).
// Layer1: X[cell][k32] (hi/lo) @ W1 frags -> H (relu, bf16) -> LDS transpose
// Layer2: H A-frags @ W2 frags (hi/lo) -> MS -> LDS transpose -> coalesced store.
// ---------------------------------------------------------------------------
__global__ void __launch_bounds__(256)
ms_mfma(const float* __restrict__ qv, const float* __restrict__ kv,
        const float* __restrict__ cost, const uint4* __restrict__ W1Bhi,
        const uint4* __restrict__ W1Blo, const uint4* __restrict__ W2Bhi,
        const uint4* __restrict__ W2Blo, u16* __restrict__ ms1) {
  __shared__ __align__(16) u32 lds[4 * 1280];
  int t = threadIdx.x, L = t & 63, w = t >> 6;
  int lo4 = L & 15, q = L >> 4;
  int b = blockIdx.z, r = blockIdx.y * 4 + w, c0 = blockIdx.x * 64;
  u32* wl = lds + w * 1280;

  // ---- phase 1: per-lane dots for h = 4q..4q+3, cells c0+16m+lo4 ----
  const float4* qrow = (const float4*)(qv + ((size_t)(b * 512 + r) << 9));
  const float4* kr[4];
  float dots[4][4];
  float cv[4];
#pragma unroll
  for (int m = 0; m < 4; m++) {
    int c = c0 + 16 * m + lo4;
    kr[m] = (const float4*)(kv + ((size_t)(b * 512 + c) << 9));
    cv[m] = cost[(((size_t)(b * 512 + r)) << 9) + c];
  }
#pragma unroll
  for (int tt = 0; tt < 4; tt++) {
    float4 q4[4];
#pragma unroll
    for (int d4 = 0; d4 < 4; d4++) q4[d4] = qrow[q * 16 + tt * 4 + d4];
#pragma unroll
    for (int m = 0; m < 4; m++) {
      float a = 0.f;
#pragma unroll
      for (int d4 = 0; d4 < 4; d4++) {
        float4 k4 = kr[m][q * 16 + tt * 4 + d4];
        a += q4[d4].x * k4.x + q4[d4].y * k4.y + q4[d4].z * k4.z + q4[d4].w * k4.w;
      }
      dots[m][tt] = a * 0.25f;
    }
  }

  // ---- X fragments (A-operand, k = 8q+jj: even->dot_{4q+jj/2}, odd->cost) ----
  uint4 xhi[4], xlo[4];
#pragma unroll
  for (int m = 0; m < 4; m++) {
    u16 chi = f2b(cv[m]); u16 clo = f2b(cv[m] - b2f(chi));
    u32 hw[4], lw[4];
#pragma unroll
    for (int tt = 0; tt < 4; tt++) {
      u16 dh = f2b(dots[m][tt]); u16 dl = f2b(dots[m][tt] - b2f(dh));
      hw[tt] = (u32)dh | ((u32)chi << 16);
      lw[tt] = (u32)dl | ((u32)clo << 16);
    }
    xhi[m] = make_uint4(hw[0], hw[1], hw[2], hw[3]);
    xlo[m] = make_uint4(lw[0], lw[1], lw[2], lw[3]);
  }

  // ---- phase 2: MLP over ntile-pairs ----
  f32x4 z; z[0] = 0.f; z[1] = 0.f; z[2] = 0.f; z[3] = 0.f;
  f32x4 acc2[4] = {z, z, z, z};
  for (int p = 0; p < 8; p++) {
    uint4 w1h0 = W1Bhi[(2 * p) * 64 + L], w1h1 = W1Bhi[(2 * p + 1) * 64 + L];
    uint4 w1l0 = W1Blo[(2 * p) * 64 + L], w1l1 = W1Blo[(2 * p + 1) * 64 + L];
    uint4 w2h  = W2Bhi[p * 64 + L],      w2l  = W2Blo[p * 64 + L];
#pragma unroll
    for (int m = 0; m < 4; m++) {
      f32x4 a0 = z, a1 = z;
      a0 = mfma16(xhi[m], w1h0, a0);
      a0 = mfma16(xlo[m], w1h0, a0);
      a0 = mfma16(xhi[m], w1l0, a0);
      a1 = mfma16(xhi[m], w1h1, a1);
      a1 = mfma16(xlo[m], w1h1, a1);
      a1 = mfma16(xhi[m], w1l1, a1);
      // H -> LDS, packed u32 = (bf16 relu a0 | bf16 relu a1 << 16)
#pragma unroll
      for (int i = 0; i < 4; i++) {
        u32 pv = (u32)f2b(fmaxf(a0[i], 0.f)) | ((u32)f2b(fmaxf(a1[i], 0.f)) << 16);
        wl[m * 320 + (q * 4 + i) * 20 + lo4] = pv;
      }
    }
#pragma unroll
    for (int m = 0; m < 4; m++) {
      uint4 hf = *(const uint4*)&wl[m * 320 + lo4 * 20 + q * 4];
      acc2[m] = mfma16(hf, w2h, acc2[m]);
      acc2[m] = mfma16(hf, w2l, acc2[m]);
    }
  }

  // ---- MS: LDS transpose (rows h=lo4, cols c-local), then coalesced store ----
#pragma unroll
  for (int m = 0; m < 4; m++)
#pragma unroll
    for (int i = 0; i < 4; i++)
      wl[lo4 * 66 + 16 * m + q * 4 + i] = __float_as_uint(acc2[m][i]);

  u32* ms1u = (u32*)ms1;
#pragma unroll
  for (int tt = 0; tt < 8; tt++) {
    int h = tt * 2 + (L >> 5);
    int cu = L & 31;
    uint2 pr = *(const uint2*)&wl[h * 66 + 2 * cu];
    u32 o = (u32)f2b(__uint_as_float(pr.x)) | ((u32)f2b(__uint_as_float(pr.y)) << 16);
    ms1u[(((size_t)(b * 16 + h) << 9) + r) * 256 + (c0 >> 1) + cu] = o;
  }
}

// ---------------------------------------------------------------------------
// 64x64 bf16 transpose per plane (plane = b*16+h), via LDS tile.
// ---------------------------------------------------------------------------
__global__ void __launch_bounds__(256)
tr16(const u16* __restrict__ src, u16* __restrict__ dst) {
  __shared__ u16 tile[64][65];
  int t = threadIdx.x;
  int rl = t >> 3, cw = t & 7;
  size_t base = (size_t)blockIdx.z * 262144;
  int r0 = blockIdx.y * 64, c0 = blockIdx.x * 64;
#pragma unroll
  for (int pass = 0; pass < 2; pass++) {
    int row = pass * 32 + rl;
    uint4 v = *(const uint4*)(src + base + (size_t)(r0 + row) * 512 + c0 + cw * 8);
    u16* tp = &tile[row][cw * 8];
    tp[0] = (u16)v.x; tp[1] = (u16)(v.x >> 16);
    tp[2] = (u16)v.y; tp[3] = (u16)(v.y >> 16);
    tp[4] = (u16)v.z; tp[5] = (u16)(v.z >> 16);
    tp[6] = (u16)v.w; tp[7] = (u16)(v.w >> 16);
  }
  __syncthreads();
#pragma unroll
  for (int pass = 0; pass < 2; pass++) {
    int crow = pass * 32 + rl;
    u32 wv[4];
#pragma unroll
    for (int d = 0; d < 4; d++) {
      u16 e0 = tile[cw * 8 + 2 * d][crow];
      u16 e1 = tile[cw * 8 + 2 * d + 1][crow];
      wv[d] = (u32)e0 | ((u32)e1 << 16);
    }
    *(uint4*)(dst + base + (size_t)(c0 + crow) * 512 + r0 + cw * 8) =
        make_uint4(wv[0], wv[1], wv[2], wv[3]);
  }
}

// ---------------------------------------------------------------------------
// 64x64 u32 transpose per plane (plane = b), for the attention mask.
// ---------------------------------------------------------------------------
__global__ void __launch_bounds__(256)
tr32(const u32* __restrict__ src, u32* __restrict__ dst) {
  __shared__ u32 tile[64][65];
  int t = threadIdx.x;
  int rl = t >> 4, cw = t & 15;
  size_t base = (size_t)blockIdx.z * 262144;
  int r0 = blockIdx.y * 64, c0 = blockIdx.x * 64;
#pragma unroll
  for (int pass = 0; pass < 4; pass++) {
    int row = pass * 16 + rl;
    uint4 v = *(const uint4*)(src + base + (size_t)(r0 + row) * 512 + c0 + cw * 4);
    tile[row][cw * 4 + 0] = v.x; tile[row][cw * 4 + 1] = v.y;
    tile[row][cw * 4 + 2] = v.z; tile[row][cw * 4 + 3] = v.w;
  }
  __syncthreads();
#pragma unroll
  for (int pass = 0; pass < 4; pass++) {
    int crow = pass * 16 + rl;
    uint4 o = make_uint4(tile[cw * 4 + 0][crow], tile[cw * 4 + 1][crow],
                         tile[cw * 4 + 2][crow], tile[cw * 4 + 3][crow]);
    *(uint4*)(dst + base + (size_t)(c0 + crow) * 512 + r0 + cw * 4) = o;
  }
}

// ---------------------------------------------------------------------------
// Masked softmax over 512 logits + weighted sum of V.  One wave per (b,h,fix).
// ---------------------------------------------------------------------------
__global__ void __launch_bounds__(64, 4)
softmax_av(const u16* __restrict__ ms, int msRed, int msFix,
           const int* __restrict__ mask, int mRed, int mFix,
           const float* __restrict__ vbuf, float* __restrict__ obuf) {
  int lane = threadIdx.x;
  int blk  = blockIdx.x;
  int fix  = blk & 511;
  int bh   = blk >> 9;
  int h    = bh & 15;
  int b    = bh >> 4;

  const u16* mbase = ms + (size_t)bh * 262144 + (size_t)fix * msFix;
  const int* kbase = mask + (size_t)b * 262144 + (size_t)fix * mFix;

  float lg[8];
  bool  vd[8];
#pragma unroll
  for (int i = 0; i < 8; i++) {
    int cc = i * 64 + lane;
    lg[i] = b2f(mbase[(size_t)cc * msRed]);
    vd[i] = kbase[(size_t)cc * mRed] != 0;
  }
  bool anyl = false;
#pragma unroll
  for (int i = 0; i < 8; i++) anyl |= vd[i];
  bool useMask = (__ballot(anyl) != 0ULL);

  float m = -3.4e38f;
#pragma unroll
  for (int i = 0; i < 8; i++)
    if (!(useMask && !vd[i])) m = fmaxf(m, lg[i]);
  for (int off = 32; off; off >>= 1) m = fmaxf(m, __shfl_xor(m, off));

  float p[8], s = 0.f;
#pragma unroll
  for (int i = 0; i < 8; i++) {
    p[i] = (useMask && !vd[i]) ? 0.f : __expf(lg[i] - m);
    s += p[i];
  }
  for (int off = 32; off; off >>= 1) s += __shfl_xor(s, off);

  float acc[16];
#pragma unroll
  for (int d = 0; d < 16; d++) acc[d] = 0.f;

#pragma unroll
  for (int i = 0; i < 8; i++) {
    int cc = i * 64 + lane;
    const float4* vrow = (const float4*)(vbuf + (((size_t)b * 512 + cc) << 9) + 256 + h * 16);
    float4 u0 = vrow[0], u1 = vrow[1], u2 = vrow[2], u3 = vrow[3];
    float pi = p[i];
    acc[0]  += pi * u0.x; acc[1]  += pi * u0.y; acc[2]  += pi * u0.z; acc[3]  += pi * u0.w;
    acc[4]  += pi * u1.x; acc[5]  += pi * u1.y; acc[6]  += pi * u1.z; acc[7]  += pi * u1.w;
    acc[8]  += pi * u2.x; acc[9]  += pi * u2.y; acc[10] += pi * u2.z; acc[11] += pi * u2.w;
    acc[12] += pi * u3.x; acc[13] += pi * u3.y; acc[14] += pi * u3.z; acc[15] += pi * u3.w;
  }
#pragma unroll
  for (int off = 1; off < 64; off <<= 1) {
#pragma unroll
    for (int d = 0; d < 16; d++) acc[d] += __shfl_xor(acc[d], off);
  }
  if (lane < 16) {
    float o = acc[lane] / s;
    obuf[((size_t)b * 512 + fix) * 256 + h * 16 + lane] = o;
  }
}

// ---------------------------------------------------------------------------
extern "C" void kernel_launch(void* const* d_in, const int* in_sizes, int n_in,
                              void* d_out, int out_size, void* d_ws, size_t ws_size,
                              hipStream_t stream) {
  const float* x1    = (const float*)d_in[0];
  const float* x2    = (const float*)d_in[1];
  const int*   attn  = (const int*)d_in[2];
  const float* cost  = (const float*)d_in[3];
  const float* Wqv1  = (const float*)d_in[4];
  const float* Wkv2  = (const float*)d_in[5];
  const float* W1    = (const float*)d_in[6];
  const float* W2    = (const float*)d_in[7];
  const float* Wout1 = (const float*)d_in[8];
  const float* Wout2 = (const float*)d_in[9];
  float* out = (float*)d_out;

  char* ws = (char*)d_ws;
  uint4* W1Bhi = (uint4*)(ws);                               // 16 KB
  uint4* W1Blo = (uint4*)(ws + (16 << 10));                  // 16 KB
  uint4* W2Bhi = (uint4*)(ws + (32 << 10));                  //  8 KB
  uint4* W2Blo = (uint4*)(ws + (40 << 10));                  //  8 KB
  float* qv  = (float*)(ws + (64 << 10));                    //   2 MB [b][r][512]
  float* kv  = (float*)(ws + (64 << 10) + (2 << 20));        //   2 MB [b][c][512]
  u16*   ms1 = (u16*)  (ws + (64 << 10) + (4 << 20));        //  16 MB [b][h][r][c]
  u16*   ms2 = (u16*)  (ws + (64 << 10) + (20 << 20));       //  16 MB [b][h][c][r]
  u32*   mT  = (u32*)  (ws + (64 << 10) + (36 << 20));       //   2 MB [b][c][r]
  float* o1  = (float*)(ws + (64 << 10) + (38 << 20));       //   1 MB [b][r][256]
  float* o2  = (float*)(ws + (64 << 10) + (39 << 20));       //   1 MB [b][c][256]

  prep_w<<<6, 256, 0, stream>>>(W1, W2, W1Bhi, W1Blo, W2Bhi, W2Blo);
  gemm_bt64<<<dim3(8, 16), 256, 0, stream>>>(x1, Wqv1, qv, 1024, 512, 256);
  gemm_bt64<<<dim3(8, 16), 256, 0, stream>>>(x2, Wkv2, kv, 1024, 512, 256);

  ms_mfma<<<dim3(8, 128, 2), 256, 0, stream>>>(qv, kv, cost, W1Bhi, W1Blo, W2Bhi, W2Blo, ms1);

  tr16<<<dim3(8, 8, 32), 256, 0, stream>>>(ms1, ms2);
  tr32<<<dim3(8, 8, 2), 256, 0, stream>>>((const u32*)attn, mT);

  softmax_av<<<16384, 64, 0, stream>>>(ms1, 1, 512, attn, 1, 512, kv, o1);
  softmax_av<<<16384, 64, 0, stream>>>(ms2, 1, 512, (const int*)mT, 1, 512, qv, o2);

  gemm_bt64<<<dim3(4, 16), 256, 0, stream>>>(o1, Wout1, out, 1024, 256, 256);
  gemm_bt64<<<dim3(4, 16), 256, 0, stream>>>(o2, Wout2, out + (size_t)262144, 1024, 256, 256);
}

// Round 4
// 319.785 us; speedup vs baseline: 1.7615x; 1.3560x over previous
//
#include <hip/hip_runtime.h>
#include <hip/hip_bf16.h>

typedef unsigned int   u32;
typedef unsigned short u16;

typedef __attribute__((ext_vector_type(8))) short sh8;
typedef __attribute__((ext_vector_type(4))) float f32x4;

__device__ __forceinline__ float b2f(u16 u) { union { u32 i; float f; } v; v.i = ((u32)u) << 16; return v.f; }
__device__ __forceinline__ u16   f2b(float f){
  union { float f; u32 i; } v; v.f = f;
  u32 u = v.i;
  u32 r = (u + 0x7fffu + ((u >> 16) & 1u)) >> 16;   // RNE
  return (u16)r;
}
// pack two f32 -> bf16x2 (RNE), lo = a, hi = b  (v_cvt_pk_bf16_f32 on gfx950)
__device__ __forceinline__ u32 pk2(float a, float b) {
  __hip_bfloat162 h2 = __float22bfloat162_rn(make_float2(a, b));
  union { __hip_bfloat162 h; u32 u; } v; v.h = h2; return v.u;
}

__device__ __forceinline__ f32x4 mfma16(uint4 a, uint4 b, f32x4 c) {
  union { uint4 u; sh8 s; } ua, ub;
  ua.u = a; ub.u = b;
  return __builtin_amdgcn_mfma_f32_16x16x32_bf16(ua.s, ub.s, c, 0, 0, 0);
}

// ---------------------------------------------------------------------------
// prep_w: MFMA B-operand fragments for W1 (hi/lo) and W2 (hi/lo).
// ---------------------------------------------------------------------------
__global__ void prep_w(const float* __restrict__ W1, const float* __restrict__ W2,
                       uint4* __restrict__ W1Bhi, uint4* __restrict__ W1Blo,
                       uint4* __restrict__ W2Bhi, uint4* __restrict__ W2Blo) {
  int tid = blockIdx.x * 256 + threadIdx.x;
  if (tid < 1024) {
    int L = tid & 63;
    int j = (tid >> 6) * 16 + (L & 15), q = L >> 4;
    u32 hw[4] = {0,0,0,0}, lw[4] = {0,0,0,0};
#pragma unroll
    for (int jj = 0; jj < 8; jj++) {
      float wv = W1[j * 32 + q * 8 + jj];
      u16 hb = f2b(wv); u16 lb = f2b(wv - b2f(hb));
      hw[jj >> 1] |= ((u32)hb) << (16 * (jj & 1));
      lw[jj >> 1] |= ((u32)lb) << (16 * (jj & 1));
    }
    W1Bhi[tid] = make_uint4(hw[0], hw[1], hw[2], hw[3]);
    W1Blo[tid] = make_uint4(lw[0], lw[1], lw[2], lw[3]);
  } else if (tid < 1536) {
    int t = tid - 1024;
    int p = t >> 6, L = t & 63;
    int head = L & 15, q = L >> 4;
    u32 hw[4] = {0,0,0,0}, lw[4] = {0,0,0,0};
#pragma unroll
    for (int jj = 0; jj < 8; jj++) {
      int col = q * 4 + (jj >> 1), half = jj & 1;
      int j = p * 32 + half * 16 + col;
      float wv = W2[head * 256 + j];
      u16 hb = f2b(wv); u16 lb = f2b(wv - b2f(hb));
      hw[jj >> 1] |= ((u32)hb) << (16 * half);
      lw[jj >> 1] |= ((u32)lb) << (16 * half);
    }
    W2Bhi[t] = make_uint4(hw[0], hw[1], hw[2], hw[3]);
    W2Blo[t] = make_uint4(lw[0], lw[1], lw[2], lw[3]);
  }
}

// ---------------------------------------------------------------------------
// gemm_bt64: C = A @ B^T, f32, 64x64 tile, 4x4 microtile per thread.
// ---------------------------------------------------------------------------
__global__ void __launch_bounds__(256)
gemm_bt64(const float* __restrict__ A, const float* __restrict__ Bw,
          float* __restrict__ C, int M, int N, int K) {
  __shared__ float As[16][64];
  __shared__ float Bs[16][64];
  int t = threadIdx.x;
  int tx = t & 15, ty = t >> 4;
  int m0 = blockIdx.y * 64, n0 = blockIdx.x * 64;
  int lrow = t >> 2, lk = (t & 3) * 4;
  float acc[4][4];
#pragma unroll
  for (int i = 0; i < 4; i++)
#pragma unroll
    for (int j = 0; j < 4; j++) acc[i][j] = 0.f;

  for (int k0 = 0; k0 < K; k0 += 16) {
    float4 av = *(const float4*)(A + (size_t)(m0 + lrow) * K + k0 + lk);
    float4 bv = *(const float4*)(Bw + (size_t)(n0 + lrow) * K + k0 + lk);
    __syncthreads();
    As[lk + 0][lrow] = av.x; As[lk + 1][lrow] = av.y;
    As[lk + 2][lrow] = av.z; As[lk + 3][lrow] = av.w;
    Bs[lk + 0][lrow] = bv.x; Bs[lk + 1][lrow] = bv.y;
    Bs[lk + 2][lrow] = bv.z; Bs[lk + 3][lrow] = bv.w;
    __syncthreads();
#pragma unroll
    for (int kk = 0; kk < 16; kk++) {
      float a_[4], b_[4];
#pragma unroll
      for (int i = 0; i < 4; i++) { a_[i] = As[kk][ty * 4 + i]; b_[i] = Bs[kk][tx * 4 + i]; }
#pragma unroll
      for (int i = 0; i < 4; i++)
#pragma unroll
        for (int j = 0; j < 4; j++) acc[i][j] += a_[i] * b_[j];
    }
  }
#pragma unroll
  for (int i = 0; i < 4; i++) {
    float4 o; o.x = acc[i][0]; o.y = acc[i][1]; o.z = acc[i][2]; o.w = acc[i][3];
    *(float4*)(C + (size_t)(m0 + ty * 4 + i) * N + n0 + tx * 4) = o;
  }
}

// ---------------------------------------------------------------------------
// ms_mfma: fused QK^T*0.25 + MixedScoreFF via MFMA (cvt_pk packing).
// ---------------------------------------------------------------------------
__global__ void __launch_bounds__(256)
ms_mfma(const float* __restrict__ qv, const float* __restrict__ kv,
        const float* __restrict__ cost, const uint4* __restrict__ W1Bhi,
        const uint4* __restrict__ W1Blo, const uint4* __restrict__ W2Bhi,
        const uint4* __restrict__ W2Blo, u16* __restrict__ ms1) {
  __shared__ __align__(16) u32 lds[4 * 1280];
  int t = threadIdx.x, L = t & 63, w = t >> 6;
  int lo4 = L & 15, q = L >> 4;
  int b = blockIdx.z, r = blockIdx.y * 4 + w, c0 = blockIdx.x * 64;
  u32* wl = lds + w * 1280;

  // ---- phase 1: per-lane dots for h = 4q..4q+3, cells c0+16m+lo4 ----
  const float4* qrow = (const float4*)(qv + ((size_t)(b * 512 + r) << 9));
  const float4* kr[4];
  float dots[4][4];
  float cv[4];
#pragma unroll
  for (int m = 0; m < 4; m++) {
    int c = c0 + 16 * m + lo4;
    kr[m] = (const float4*)(kv + ((size_t)(b * 512 + c) << 9));
    cv[m] = cost[(((size_t)(b * 512 + r)) << 9) + c];
  }
#pragma unroll
  for (int tt = 0; tt < 4; tt++) {
    float4 q4[4];
#pragma unroll
    for (int d4 = 0; d4 < 4; d4++) q4[d4] = qrow[q * 16 + tt * 4 + d4];
#pragma unroll
    for (int m = 0; m < 4; m++) {
      float a = 0.f;
#pragma unroll
      for (int d4 = 0; d4 < 4; d4++) {
        float4 k4 = kr[m][q * 16 + tt * 4 + d4];
        a += q4[d4].x * k4.x + q4[d4].y * k4.y + q4[d4].z * k4.z + q4[d4].w * k4.w;
      }
      dots[m][tt] = a * 0.25f;
    }
  }

  // ---- X fragments (A-operand, k-pair u32 = (dot_h | cost<<16)), hi/lo ----
  uint4 xhi[4], xlo[4];
#pragma unroll
  for (int m = 0; m < 4; m++) {
    float cvm = cv[m];
    u32 cp = pk2(cvm, cvm);
    float cres = cvm - __uint_as_float(cp & 0xffff0000u);
    u32 hw[4], lw[4];
#pragma unroll
    for (int tt = 0; tt < 4; tt++) {
      float d = dots[m][tt];
      u32 hp = pk2(d, cvm);
      float dres = d - __uint_as_float(hp << 16);
      hw[tt] = hp;
      lw[tt] = pk2(dres, cres);
    }
    xhi[m] = make_uint4(hw[0], hw[1], hw[2], hw[3]);
    xlo[m] = make_uint4(lw[0], lw[1], lw[2], lw[3]);
  }

  // ---- phase 2: MLP over ntile-pairs ----
  f32x4 z; z[0] = 0.f; z[1] = 0.f; z[2] = 0.f; z[3] = 0.f;
  f32x4 acc2[4] = {z, z, z, z};
  for (int p = 0; p < 8; p++) {
    uint4 w1h0 = W1Bhi[(2 * p) * 64 + L], w1h1 = W1Bhi[(2 * p + 1) * 64 + L];
    uint4 w1l0 = W1Blo[(2 * p) * 64 + L], w1l1 = W1Blo[(2 * p + 1) * 64 + L];
    uint4 w2h  = W2Bhi[p * 64 + L],      w2l  = W2Blo[p * 64 + L];
#pragma unroll
    for (int m = 0; m < 4; m++) {
      f32x4 a0 = z, a1 = z;
      a0 = mfma16(xhi[m], w1h0, a0);
      a0 = mfma16(xlo[m], w1h0, a0);
      a0 = mfma16(xhi[m], w1l0, a0);
      a1 = mfma16(xhi[m], w1h1, a1);
      a1 = mfma16(xlo[m], w1h1, a1);
      a1 = mfma16(xhi[m], w1l1, a1);
      // H -> LDS: u32 = (bf16 relu a0 | bf16 relu a1 << 16); row=cell(4q+i), col=j-pair(lo4)
#pragma unroll
      for (int i = 0; i < 4; i++) {
        wl[m * 320 + (q * 4 + i) * 20 + lo4] =
            pk2(fmaxf(a0[i], 0.f), fmaxf(a1[i], 0.f));
      }
    }
#pragma unroll
    for (int m = 0; m < 4; m++) {
      uint4 hf = *(const uint4*)&wl[m * 320 + lo4 * 20 + q * 4];
      acc2[m] = mfma16(hf, w2h, acc2[m]);
      acc2[m] = mfma16(hf, w2l, acc2[m]);
    }
  }

  // ---- MS: LDS transpose (row h=lo4, col c-local), then coalesced store ----
#pragma unroll
  for (int m = 0; m < 4; m++)
#pragma unroll
    for (int i = 0; i < 4; i++)
      wl[lo4 * 66 + 16 * m + q * 4 + i] = __float_as_uint(acc2[m][i]);

  u32* ms1u = (u32*)ms1;
#pragma unroll
  for (int tt = 0; tt < 8; tt++) {
    int h = tt * 2 + (L >> 5);
    int cu = L & 31;
    uint2 pr = *(const uint2*)&wl[h * 66 + 2 * cu];
    u32 o = pk2(__uint_as_float(pr.x), __uint_as_float(pr.y));
    ms1u[(((size_t)(b * 16 + h) << 9) + r) * 256 + (c0 >> 1) + cu] = o;
  }
}

// ---------------------------------------------------------------------------
// 64x64 bf16 transpose per plane (plane = b*16+h), via LDS tile.
// ---------------------------------------------------------------------------
__global__ void __launch_bounds__(256)
tr16(const u16* __restrict__ src, u16* __restrict__ dst) {
  __shared__ u16 tile[64][65];
  int t = threadIdx.x;
  int rl = t >> 3, cw = t & 7;
  size_t base = (size_t)blockIdx.z * 262144;
  int r0 = blockIdx.y * 64, c0 = blockIdx.x * 64;
#pragma unroll
  for (int pass = 0; pass < 2; pass++) {
    int row = pass * 32 + rl;
    uint4 v = *(const uint4*)(src + base + (size_t)(r0 + row) * 512 + c0 + cw * 8);
    u16* tp = &tile[row][cw * 8];
    tp[0] = (u16)v.x; tp[1] = (u16)(v.x >> 16);
    tp[2] = (u16)v.y; tp[3] = (u16)(v.y >> 16);
    tp[4] = (u16)v.z; tp[5] = (u16)(v.z >> 16);
    tp[6] = (u16)v.w; tp[7] = (u16)(v.w >> 16);
  }
  __syncthreads();
#pragma unroll
  for (int pass = 0; pass < 2; pass++) {
    int crow = pass * 32 + rl;
    u32 wv[4];
#pragma unroll
    for (int d = 0; d < 4; d++) {
      u16 e0 = tile[cw * 8 + 2 * d][crow];
      u16 e1 = tile[cw * 8 + 2 * d + 1][crow];
      wv[d] = (u32)e0 | ((u32)e1 << 16);
    }
    *(uint4*)(dst + base + (size_t)(c0 + crow) * 512 + r0 + cw * 8) =
        make_uint4(wv[0], wv[1], wv[2], wv[3]);
  }
}

// ---------------------------------------------------------------------------
// 64x64 u32 transpose per plane (plane = b), for the attention mask.
// ---------------------------------------------------------------------------
__global__ void __launch_bounds__(256)
tr32(const u32* __restrict__ src, u32* __restrict__ dst) {
  __shared__ u32 tile[64][65];
  int t = threadIdx.x;
  int rl = t >> 4, cw = t & 15;
  size_t base = (size_t)blockIdx.z * 262144;
  int r0 = blockIdx.y * 64, c0 = blockIdx.x * 64;
#pragma unroll
  for (int pass = 0; pass < 4; pass++) {
    int row = pass * 16 + rl;
    uint4 v = *(const uint4*)(src + base + (size_t)(r0 + row) * 512 + c0 + cw * 4);
    tile[row][cw * 4 + 0] = v.x; tile[row][cw * 4 + 1] = v.y;
    tile[row][cw * 4 + 2] = v.z; tile[row][cw * 4 + 3] = v.w;
  }
  __syncthreads();
#pragma unroll
  for (int pass = 0; pass < 4; pass++) {
    int crow = pass * 16 + rl;
    uint4 o = make_uint4(tile[cw * 4 + 0][crow], tile[cw * 4 + 1][crow],
                         tile[cw * 4 + 2][crow], tile[cw * 4 + 3][crow]);
    *(uint4*)(dst + base + (size_t)(c0 + crow) * 512 + r0 + cw * 4) = o;
  }
}

// ---------------------------------------------------------------------------
// softmax_av2: block (256 thr) per (b,fix).  Phase A: 4 waves x 4 heads
// compute masked softmax weights -> LDS.  Phase B: coalesced float4 V
// accumulation, cross-wave reduce, normalize by 1/s.
// ---------------------------------------------------------------------------
__global__ void __launch_bounds__(256)
softmax_av2(const u16* __restrict__ ms,     // [b*16+h][fix][512] bf16
            const int* __restrict__ mask,   // [b][fix][512]
            const float* __restrict__ vbuf, // [b][512][512]; V at cols 256..511
            float* __restrict__ obuf) {     // [b][fix][256]
  __shared__ float  pbuf[16 * 514];
  __shared__ float  sden[16];
  __shared__ float4 red[4][64];
  int t = threadIdx.x, lane = t & 63, w = t >> 6;
  int fix = blockIdx.x, b = blockIdx.y;

  const int* krow = mask + ((size_t)b * 512 + fix) * 512;
  bool vd[8];
#pragma unroll
  for (int i = 0; i < 8; i++) vd[i] = krow[i * 64 + lane] != 0;
  bool anyl = false;
#pragma unroll
  for (int i = 0; i < 8; i++) anyl |= vd[i];
  bool useMask = (__ballot(anyl) != 0ULL);   // fully-masked row => unmask all

#pragma unroll
  for (int hh = 0; hh < 4; hh++) {
    int h = w * 4 + hh;
    const u16* mrow = ms + ((size_t)(b * 16 + h) * 512 + fix) * 512;
    float lg[8];
#pragma unroll
    for (int i = 0; i < 8; i++) lg[i] = b2f(mrow[i * 64 + lane]);
    float mx = -3.4e38f;
#pragma unroll
    for (int i = 0; i < 8; i++)
      if (!(useMask && !vd[i])) mx = fmaxf(mx, lg[i]);
    for (int off = 32; off; off >>= 1) mx = fmaxf(mx, __shfl_xor(mx, off));
    float s = 0.f;
#pragma unroll
    for (int i = 0; i < 8; i++) {
      float p = (useMask && !vd[i]) ? 0.f : __expf(lg[i] - mx);
      pbuf[h * 514 + i * 64 + lane] = p;
      s += p;
    }
    for (int off = 32; off; off >>= 1) s += __shfl_xor(s, off);
    if (lane == 0) sden[h] = s;
  }
  __syncthreads();

  // phase B: thread (w, h=lane>>2, dq=lane&3) accumulates cc = 4*it + w
  int hb = lane >> 2, dq = lane & 3;
  const float* vb = vbuf + ((size_t)b * 512) * 512 + 256 + hb * 16 + dq * 4;
  float4 acc = make_float4(0.f, 0.f, 0.f, 0.f);
  for (int it = 0; it < 128; it += 4) {
#pragma unroll
    for (int u = 0; u < 4; u++) {
      int cc = (it + u) * 4 + w;
      float pv = pbuf[hb * 514 + cc];
      float4 v = *(const float4*)(vb + (size_t)cc * 512);
      acc.x += pv * v.x; acc.y += pv * v.y; acc.z += pv * v.z; acc.w += pv * v.w;
    }
  }
  red[w][lane] = acc;
  __syncthreads();
  if (w == 0) {
    float4 a = red[0][lane], b1 = red[1][lane], c1 = red[2][lane], d1 = red[3][lane];
    float inv = 1.f / sden[hb];
    float4 o;
    o.x = (a.x + b1.x + c1.x + d1.x) * inv;
    o.y = (a.y + b1.y + c1.y + d1.y) * inv;
    o.z = (a.z + b1.z + c1.z + d1.z) * inv;
    o.w = (a.w + b1.w + c1.w + d1.w) * inv;
    *(float4*)(obuf + ((size_t)b * 512 + fix) * 256 + lane * 4) = o;
  }
}

// ---------------------------------------------------------------------------
extern "C" void kernel_launch(void* const* d_in, const int* in_sizes, int n_in,
                              void* d_out, int out_size, void* d_ws, size_t ws_size,
                              hipStream_t stream) {
  const float* x1    = (const float*)d_in[0];
  const float* x2    = (const float*)d_in[1];
  const int*   attn  = (const int*)d_in[2];
  const float* cost  = (const float*)d_in[3];
  const float* Wqv1  = (const float*)d_in[4];
  const float* Wkv2  = (const float*)d_in[5];
  const float* W1    = (const float*)d_in[6];
  const float* W2    = (const float*)d_in[7];
  const float* Wout1 = (const float*)d_in[8];
  const float* Wout2 = (const float*)d_in[9];
  float* out = (float*)d_out;

  char* ws = (char*)d_ws;
  uint4* W1Bhi = (uint4*)(ws);                               // 16 KB
  uint4* W1Blo = (uint4*)(ws + (16 << 10));                  // 16 KB
  uint4* W2Bhi = (uint4*)(ws + (32 << 10));                  //  8 KB
  uint4* W2Blo = (uint4*)(ws + (40 << 10));                  //  8 KB
  float* qv  = (float*)(ws + (64 << 10));                    //   2 MB [b][r][512]
  float* kv  = (float*)(ws + (64 << 10) + (2 << 20));        //   2 MB [b][c][512]
  u16*   ms1 = (u16*)  (ws + (64 << 10) + (4 << 20));        //  16 MB [b][h][r][c]
  u16*   ms2 = (u16*)  (ws + (64 << 10) + (20 << 20));       //  16 MB [b][h][c][r]
  u32*   mT  = (u32*)  (ws + (64 << 10) + (36 << 20));       //   2 MB [b][c][r]
  float* o1  = (float*)(ws + (64 << 10) + (38 << 20));       //   1 MB [b][r][256]
  float* o2  = (float*)(ws + (64 << 10) + (39 << 20));       //   1 MB [b][c][256]

  prep_w<<<6, 256, 0, stream>>>(W1, W2, W1Bhi, W1Blo, W2Bhi, W2Blo);
  gemm_bt64<<<dim3(8, 16), 256, 0, stream>>>(x1, Wqv1, qv, 1024, 512, 256);
  gemm_bt64<<<dim3(8, 16), 256, 0, stream>>>(x2, Wkv2, kv, 1024, 512, 256);

  ms_mfma<<<dim3(8, 128, 2), 256, 0, stream>>>(qv, kv, cost, W1Bhi, W1Blo, W2Bhi, W2Blo, ms1);

  tr16<<<dim3(8, 8, 32), 256, 0, stream>>>(ms1, ms2);
  tr32<<<dim3(8, 8, 2), 256, 0, stream>>>((const u32*)attn, mT);

  softmax_av2<<<dim3(512, 2), 256, 0, stream>>>(ms1, attn, kv, o1);
  softmax_av2<<<dim3(512, 2), 256, 0, stream>>>(ms2, (const int*)mT, qv, o2);

  gemm_bt64<<<dim3(4, 16), 256, 0, stream>>>(o1, Wout1, out, 1024, 256, 256);
  gemm_bt64<<<dim3(4, 16), 256, 0, stream>>>(o2, Wout2, out + (size_t)262144, 1024, 256, 256);
}

// Round 5
// 265.517 us; speedup vs baseline: 2.1215x; 1.2044x over previous
//
#include <hip/hip_runtime.h>
#include <hip/hip_bf16.h>

typedef unsigned int   u32;
typedef unsigned short u16;

typedef __attribute__((ext_vector_type(8))) short sh8;
typedef __attribute__((ext_vector_type(4))) float f32x4;

__device__ __forceinline__ float b2f(u16 u) { union { u32 i; float f; } v; v.i = ((u32)u) << 16; return v.f; }
__device__ __forceinline__ u16   f2b(float f){
  union { float f; u32 i; } v; v.f = f;
  u32 u = v.i;
  u32 r = (u + 0x7fffu + ((u >> 16) & 1u)) >> 16;   // RNE
  return (u16)r;
}
// pack two f32 -> bf16x2 (RNE), lo half = a, hi half = b
__device__ __forceinline__ u32 pk2(float a, float b) {
  __hip_bfloat162 h2 = __float22bfloat162_rn(make_float2(a, b));
  union { __hip_bfloat162 h; u32 u; } v; v.h = h2; return v.u;
}

__device__ __forceinline__ f32x4 mfma16(uint4 a, uint4 b, f32x4 c) {
  union { uint4 u; sh8 s; } ua, ub;
  ua.u = a; ub.u = b;
  return __builtin_amdgcn_mfma_f32_16x16x32_bf16(ua.s, ub.s, c, 0, 0, 0);
}

// ---------------------------------------------------------------------------
// prep_w: MFMA B-operand fragments for W1 (hi/lo) and W2 (hi/lo).
// ---------------------------------------------------------------------------
__global__ void prep_w(const float* __restrict__ W1, const float* __restrict__ W2,
                       uint4* __restrict__ W1Bhi, uint4* __restrict__ W1Blo,
                       uint4* __restrict__ W2Bhi, uint4* __restrict__ W2Blo) {
  int tid = blockIdx.x * 256 + threadIdx.x;
  if (tid < 1024) {
    int L = tid & 63;
    int j = (tid >> 6) * 16 + (L & 15), q = L >> 4;
    u32 hw[4] = {0,0,0,0}, lw[4] = {0,0,0,0};
#pragma unroll
    for (int jj = 0; jj < 8; jj++) {
      float wv = W1[j * 32 + q * 8 + jj];
      u16 hb = f2b(wv); u16 lb = f2b(wv - b2f(hb));
      hw[jj >> 1] |= ((u32)hb) << (16 * (jj & 1));
      lw[jj >> 1] |= ((u32)lb) << (16 * (jj & 1));
    }
    W1Bhi[tid] = make_uint4(hw[0], hw[1], hw[2], hw[3]);
    W1Blo[tid] = make_uint4(lw[0], lw[1], lw[2], lw[3]);
  } else if (tid < 1536) {
    int t = tid - 1024;
    int p = t >> 6, L = t & 63;
    int head = L & 15, q = L >> 4;
    u32 hw[4] = {0,0,0,0}, lw[4] = {0,0,0,0};
#pragma unroll
    for (int jj = 0; jj < 8; jj++) {
      int col = q * 4 + (jj >> 1), half = jj & 1;
      int j = p * 32 + half * 16 + col;
      float wv = W2[head * 256 + j];
      u16 hb = f2b(wv); u16 lb = f2b(wv - b2f(hb));
      hw[jj >> 1] |= ((u32)hb) << (16 * half);
      lw[jj >> 1] |= ((u32)lb) << (16 * half);
    }
    W2Bhi[t] = make_uint4(hw[0], hw[1], hw[2], hw[3]);
    W2Blo[t] = make_uint4(lw[0], lw[1], lw[2], lw[3]);
  }
}

// ---------------------------------------------------------------------------
// gemm_bt64: C = A @ B^T, f32, 64x64 tile, 4x4 microtile per thread.
// ---------------------------------------------------------------------------
__global__ void __launch_bounds__(256)
gemm_bt64(const float* __restrict__ A, const float* __restrict__ Bw,
          float* __restrict__ C, int M, int N, int K) {
  __shared__ float As[16][64];
  __shared__ float Bs[16][64];
  int t = threadIdx.x;
  int tx = t & 15, ty = t >> 4;
  int m0 = blockIdx.y * 64, n0 = blockIdx.x * 64;
  int lrow = t >> 2, lk = (t & 3) * 4;
  float acc[4][4];
#pragma unroll
  for (int i = 0; i < 4; i++)
#pragma unroll
    for (int j = 0; j < 4; j++) acc[i][j] = 0.f;

  for (int k0 = 0; k0 < K; k0 += 16) {
    float4 av = *(const float4*)(A + (size_t)(m0 + lrow) * K + k0 + lk);
    float4 bv = *(const float4*)(Bw + (size_t)(n0 + lrow) * K + k0 + lk);
    __syncthreads();
    As[lk + 0][lrow] = av.x; As[lk + 1][lrow] = av.y;
    As[lk + 2][lrow] = av.z; As[lk + 3][lrow] = av.w;
    Bs[lk + 0][lrow] = bv.x; Bs[lk + 1][lrow] = bv.y;
    Bs[lk + 2][lrow] = bv.z; Bs[lk + 3][lrow] = bv.w;
    __syncthreads();
#pragma unroll
    for (int kk = 0; kk < 16; kk++) {
      float a_[4], b_[4];
#pragma unroll
      for (int i = 0; i < 4; i++) { a_[i] = As[kk][ty * 4 + i]; b_[i] = Bs[kk][tx * 4 + i]; }
#pragma unroll
      for (int i = 0; i < 4; i++)
#pragma unroll
        for (int j = 0; j < 4; j++) acc[i][j] += a_[i] * b_[j];
    }
  }
#pragma unroll
  for (int i = 0; i < 4; i++) {
    float4 o; o.x = acc[i][0]; o.y = acc[i][1]; o.z = acc[i][2]; o.w = acc[i][3];
    *(float4*)(C + (size_t)(m0 + ty * 4 + i) * N + n0 + tx * 4) = o;
  }
}

// ---------------------------------------------------------------------------
// pack_q: Q fragments (x0.25 folded).  QQ4[b][h][q][r] uint4:
//   q=0: hi(d0..7 pairs)  q=1: hi(d8..15)  q=2: lo(d0..7)  q=3: lo(d8..15)
// ---------------------------------------------------------------------------
__global__ void __launch_bounds__(256)
pack_q(const float* __restrict__ qv, uint4* __restrict__ QQ4) {
  int tid = blockIdx.x * 256 + threadIdx.x;  // ((b*512+r)*16+h)*4+q
  int q = tid & 3, h = (tid >> 2) & 15, r = (tid >> 6) & 511, b = tid >> 15;
  const float* src = qv + ((size_t)(b * 512 + r) << 9) + h * 16 + (q & 1) * 8;
  bool lo = q >= 2;
  u32 w[4];
#pragma unroll
  for (int t = 0; t < 4; t++) {
    float a = src[2 * t] * 0.25f, bb = src[2 * t + 1] * 0.25f;
    if (lo) { a -= b2f(f2b(a)); bb -= b2f(f2b(bb)); }
    w[t] = (u32)f2b(a) | ((u32)f2b(bb) << 16);
  }
  QQ4[((size_t)((b * 16 + h) * 4 + q) << 9) + r] = make_uint4(w[0], w[1], w[2], w[3]);
}

// ---------------------------------------------------------------------------
// pack_k: K fragments.  KH4[b][h][qq][c] (hi pairs), KL4z[b][h][q][c]
// (q<2: lo pairs, q>=2: zeros).
// ---------------------------------------------------------------------------
__global__ void __launch_bounds__(256)
pack_k(const float* __restrict__ kv, uint4* __restrict__ KH4, uint4* __restrict__ KL4z) {
  int tid = blockIdx.x * 256 + threadIdx.x;  // ((b*512+c)*16+h)*2+qq
  int qq = tid & 1, h = (tid >> 1) & 15, c = (tid >> 5) & 511, b = tid >> 14;
  const float* src = kv + ((size_t)(b * 512 + c) << 9) + h * 16 + qq * 8;
  u32 hw[4], lw[4];
#pragma unroll
  for (int t = 0; t < 4; t++) {
    float a = src[2 * t], bb = src[2 * t + 1];
    u16 ha = f2b(a), hb = f2b(bb);
    hw[t] = (u32)ha | ((u32)hb << 16);
    lw[t] = (u32)f2b(a - b2f(ha)) | ((u32)f2b(bb - b2f(hb)) << 16);
  }
  KH4[((size_t)((b * 16 + h) * 2 + qq) << 9) + c] = make_uint4(hw[0], hw[1], hw[2], hw[3]);
  KL4z[((size_t)((b * 16 + h) * 4 + qq) << 9) + c] = make_uint4(lw[0], lw[1], lw[2], lw[3]);
  KL4z[((size_t)((b * 16 + h) * 4 + 2 + qq) << 9) + c] = make_uint4(0, 0, 0, 0);
}

// ---------------------------------------------------------------------------
// ms_mfma2: all-MFMA fused QK^T + MixedScoreFF.
// Wave-tile = 16 r x 16 c.  Block = 4 waves (r-split).  Per-wave LDS only.
// Phase A: per head h, 2 MFMAs -> dots D[h][r][c] (f32, LDS, h-stride 260).
// Phase B: per r, X-frags from D + cost, layer1 (3 MFMA x2 Ntiles) -> H
// transpose (LDS) -> layer2 (2 MFMA), store MS from registers.
// ---------------------------------------------------------------------------
__global__ void __launch_bounds__(256)
ms_mfma2(const uint4* __restrict__ QQ4, const uint4* __restrict__ KH4,
         const uint4* __restrict__ KL4z, const float* __restrict__ cost,
         const uint4* __restrict__ W1Bhi, const uint4* __restrict__ W1Blo,
         const uint4* __restrict__ W2Bhi, const uint4* __restrict__ W2Blo,
         u16* __restrict__ ms1) {
  __shared__ __align__(16) u32 Dl[4 * 4160];
  __shared__ __align__(16) u32 Hb[4 * 320];
  int t = threadIdx.x, L = t & 63, w = t >> 6;
  int cl = L & 15, q = L >> 4;
  int b = blockIdx.z, c0 = blockIdx.x * 16, r0 = (blockIdx.y * 4 + w) * 16;
  u32* D  = Dl + w * 4160;
  u32* hb = Hb + w * 320;

  f32x4 z; z[0] = 0.f; z[1] = 0.f; z[2] = 0.f; z[3] = 0.f;

  // ---- phase A: QK^T (scaled) via MFMA, 16 heads ----
  for (int h = 0; h < 16; h++) {
    uint4 qa  = QQ4[((size_t)((b * 16 + h) * 4 + q) << 9) + r0 + cl];       // [qh|ql]
    uint4 qa2 = QQ4[((size_t)((b * 16 + h) * 4 + (q & 1)) << 9) + r0 + cl]; // [qh|qh]
    uint4 kb1 = KH4[((size_t)((b * 16 + h) * 2 + (q & 1)) << 9) + c0 + cl]; // [kh|kh]
    uint4 kb2 = KL4z[((size_t)((b * 16 + h) * 4 + q) << 9) + c0 + cl];      // [kl|0]
    f32x4 d = mfma16(qa, kb1, z);
    d = mfma16(qa2, kb2, d);
#pragma unroll
    for (int i = 0; i < 4; i++)
      D[h * 260 + (q * 4 + i) * 16 + cl] = __float_as_uint(d[i]);
  }

  // ---- phase B: MLP per r ----
  u32* ms1u = (u32*)ms1;
  for (int r = 0; r < 16; r++) {
    float cvm = cost[((size_t)(b * 512) + r0 + r) * 512 + c0 + cl];
    u32 cp = pk2(cvm, cvm);
    float cres = cvm - __uint_as_float(cp & 0xffff0000u);
    u32 hw[4], lw[4];
#pragma unroll
    for (int tt = 0; tt < 4; tt++) {
      float dd = __uint_as_float(D[(4 * q + tt) * 260 + r * 16 + cl]);
      u32 hp = pk2(dd, cvm);
      float dres = dd - __uint_as_float(hp << 16);
      hw[tt] = hp;
      lw[tt] = pk2(dres, cres);
    }
    uint4 xhi = make_uint4(hw[0], hw[1], hw[2], hw[3]);
    uint4 xlo = make_uint4(lw[0], lw[1], lw[2], lw[3]);

    f32x4 acc2 = z;
#pragma unroll 1
    for (int p = 0; p < 8; p++) {
      uint4 w1h0 = W1Bhi[(2 * p) * 64 + L], w1h1 = W1Bhi[(2 * p + 1) * 64 + L];
      uint4 w1l0 = W1Blo[(2 * p) * 64 + L], w1l1 = W1Blo[(2 * p + 1) * 64 + L];
      uint4 w2h  = W2Bhi[p * 64 + L],       w2l  = W2Blo[p * 64 + L];
      f32x4 a0 = z, a1 = z;
      a0 = mfma16(xhi, w1h0, a0);
      a0 = mfma16(xlo, w1h0, a0);
      a0 = mfma16(xhi, w1l0, a0);
      a1 = mfma16(xhi, w1h1, a1);
      a1 = mfma16(xlo, w1h1, a1);
      a1 = mfma16(xhi, w1l1, a1);
#pragma unroll
      for (int i = 0; i < 4; i++)
        hb[(q * 4 + i) * 20 + cl] = pk2(fmaxf(a0[i], 0.f), fmaxf(a1[i], 0.f));
      uint4 hf = *(const uint4*)&hb[cl * 20 + q * 4];
      acc2 = mfma16(hf, w2h, acc2);
      acc2 = mfma16(hf, w2l, acc2);
    }
    // MS store: lane holds MS[c = c0+q*4+i][h = cl] for this r
    size_t base = ((size_t)(b * 16 + cl) * 512 + (r0 + r)) * 256 + (c0 >> 1) + q * 2;
    ms1u[base]     = pk2(acc2[0], acc2[1]);
    ms1u[base + 1] = pk2(acc2[2], acc2[3]);
  }
}

// ---------------------------------------------------------------------------
// 64x64 bf16 transpose per plane (plane = b*16+h), via LDS tile.
// ---------------------------------------------------------------------------
__global__ void __launch_bounds__(256)
tr16(const u16* __restrict__ src, u16* __restrict__ dst) {
  __shared__ u16 tile[64][65];
  int t = threadIdx.x;
  int rl = t >> 3, cw = t & 7;
  size_t base = (size_t)blockIdx.z * 262144;
  int r0 = blockIdx.y * 64, c0 = blockIdx.x * 64;
#pragma unroll
  for (int pass = 0; pass < 2; pass++) {
    int row = pass * 32 + rl;
    uint4 v = *(const uint4*)(src + base + (size_t)(r0 + row) * 512 + c0 + cw * 8);
    u16* tp = &tile[row][cw * 8];
    tp[0] = (u16)v.x; tp[1] = (u16)(v.x >> 16);
    tp[2] = (u16)v.y; tp[3] = (u16)(v.y >> 16);
    tp[4] = (u16)v.z; tp[5] = (u16)(v.z >> 16);
    tp[6] = (u16)v.w; tp[7] = (u16)(v.w >> 16);
  }
  __syncthreads();
#pragma unroll
  for (int pass = 0; pass < 2; pass++) {
    int crow = pass * 32 + rl;
    u32 wv[4];
#pragma unroll
    for (int d = 0; d < 4; d++) {
      u16 e0 = tile[cw * 8 + 2 * d][crow];
      u16 e1 = tile[cw * 8 + 2 * d + 1][crow];
      wv[d] = (u32)e0 | ((u32)e1 << 16);
    }
    *(uint4*)(dst + base + (size_t)(c0 + crow) * 512 + r0 + cw * 8) =
        make_uint4(wv[0], wv[1], wv[2], wv[3]);
  }
}

// ---------------------------------------------------------------------------
// 64x64 u32 transpose per plane (plane = b), for the attention mask.
// ---------------------------------------------------------------------------
__global__ void __launch_bounds__(256)
tr32(const u32* __restrict__ src, u32* __restrict__ dst) {
  __shared__ u32 tile[64][65];
  int t = threadIdx.x;
  int rl = t >> 4, cw = t & 15;
  size_t base = (size_t)blockIdx.z * 262144;
  int r0 = blockIdx.y * 64, c0 = blockIdx.x * 64;
#pragma unroll
  for (int pass = 0; pass < 4; pass++) {
    int row = pass * 16 + rl;
    uint4 v = *(const uint4*)(src + base + (size_t)(r0 + row) * 512 + c0 + cw * 4);
    tile[row][cw * 4 + 0] = v.x; tile[row][cw * 4 + 1] = v.y;
    tile[row][cw * 4 + 2] = v.z; tile[row][cw * 4 + 3] = v.w;
  }
  __syncthreads();
#pragma unroll
  for (int pass = 0; pass < 4; pass++) {
    int crow = pass * 16 + rl;
    uint4 o = make_uint4(tile[cw * 4 + 0][crow], tile[cw * 4 + 1][crow],
                         tile[cw * 4 + 2][crow], tile[cw * 4 + 3][crow]);
    *(uint4*)(dst + base + (size_t)(c0 + crow) * 512 + r0 + cw * 4) = o;
  }
}

// ---------------------------------------------------------------------------
// softmax_av2: block (256 thr) per (b,fix).  Phase A: 4 waves x 4 heads
// masked softmax -> LDS.  Phase B: coalesced float4 V accumulation.
// ---------------------------------------------------------------------------
__global__ void __launch_bounds__(256)
softmax_av2(const u16* __restrict__ ms,     // [b*16+h][fix][512] bf16
            const int* __restrict__ mask,   // [b][fix][512]
            const float* __restrict__ vbuf, // [b][512][512]; V at cols 256..511
            float* __restrict__ obuf) {     // [b][fix][256]
  __shared__ float  pbuf[16 * 514];
  __shared__ float  sden[16];
  __shared__ float4 red[4][64];
  int t = threadIdx.x, lane = t & 63, w = t >> 6;
  int fix = blockIdx.x, b = blockIdx.y;

  const int* krow = mask + ((size_t)b * 512 + fix) * 512;
  bool vd[8];
#pragma unroll
  for (int i = 0; i < 8; i++) vd[i] = krow[i * 64 + lane] != 0;
  bool anyl = false;
#pragma unroll
  for (int i = 0; i < 8; i++) anyl |= vd[i];
  bool useMask = (__ballot(anyl) != 0ULL);   // fully-masked row => unmask all

#pragma unroll
  for (int hh = 0; hh < 4; hh++) {
    int h = w * 4 + hh;
    const u16* mrow = ms + ((size_t)(b * 16 + h) * 512 + fix) * 512;
    float lg[8];
#pragma unroll
    for (int i = 0; i < 8; i++) lg[i] = b2f(mrow[i * 64 + lane]);
    float mx = -3.4e38f;
#pragma unroll
    for (int i = 0; i < 8; i++)
      if (!(useMask && !vd[i])) mx = fmaxf(mx, lg[i]);
    for (int off = 32; off; off >>= 1) mx = fmaxf(mx, __shfl_xor(mx, off));
    float s = 0.f;
#pragma unroll
    for (int i = 0; i < 8; i++) {
      float p = (useMask && !vd[i]) ? 0.f : __expf(lg[i] - mx);
      pbuf[h * 514 + i * 64 + lane] = p;
      s += p;
    }
    for (int off = 32; off; off >>= 1) s += __shfl_xor(s, off);
    if (lane == 0) sden[h] = s;
  }
  __syncthreads();

  int hb = lane >> 2, dq = lane & 3;
  const float* vb = vbuf + ((size_t)b * 512) * 512 + 256 + hb * 16 + dq * 4;
  float4 acc = make_float4(0.f, 0.f, 0.f, 0.f);
  for (int it = 0; it < 128; it += 4) {
#pragma unroll
    for (int u = 0; u < 4; u++) {
      int cc = (it + u) * 4 + w;
      float pv = pbuf[hb * 514 + cc];
      float4 v = *(const float4*)(vb + (size_t)cc * 512);
      acc.x += pv * v.x; acc.y += pv * v.y; acc.z += pv * v.z; acc.w += pv * v.w;
    }
  }
  red[w][lane] = acc;
  __syncthreads();
  if (w == 0) {
    float4 a = red[0][lane], b1 = red[1][lane], c1 = red[2][lane], d1 = red[3][lane];
    float inv = 1.f / sden[hb];
    float4 o;
    o.x = (a.x + b1.x + c1.x + d1.x) * inv;
    o.y = (a.y + b1.y + c1.y + d1.y) * inv;
    o.z = (a.z + b1.z + c1.z + d1.z) * inv;
    o.w = (a.w + b1.w + c1.w + d1.w) * inv;
    *(float4*)(obuf + ((size_t)b * 512 + fix) * 256 + lane * 4) = o;
  }
}

// ---------------------------------------------------------------------------
extern "C" void kernel_launch(void* const* d_in, const int* in_sizes, int n_in,
                              void* d_out, int out_size, void* d_ws, size_t ws_size,
                              hipStream_t stream) {
  const float* x1    = (const float*)d_in[0];
  const float* x2    = (const float*)d_in[1];
  const int*   attn  = (const int*)d_in[2];
  const float* cost  = (const float*)d_in[3];
  const float* Wqv1  = (const float*)d_in[4];
  const float* Wkv2  = (const float*)d_in[5];
  const float* W1    = (const float*)d_in[6];
  const float* W2    = (const float*)d_in[7];
  const float* Wout1 = (const float*)d_in[8];
  const float* Wout2 = (const float*)d_in[9];
  float* out = (float*)d_out;

  char* ws = (char*)d_ws;
  uint4* W1Bhi = (uint4*)(ws);                               // 16 KB
  uint4* W1Blo = (uint4*)(ws + (16 << 10));                  // 16 KB
  uint4* W2Bhi = (uint4*)(ws + (32 << 10));                  //  8 KB
  uint4* W2Blo = (uint4*)(ws + (40 << 10));                  //  8 KB
  float* qv  = (float*)(ws + (64 << 10));                    //   2 MB [b][r][512]
  float* kv  = (float*)(ws + (64 << 10) + (2 << 20));        //   2 MB [b][c][512]
  u16*   ms1 = (u16*)  (ws + (64 << 10) + (4 << 20));        //  16 MB [b][h][r][c]
  char*  ms2c= (ws + (64 << 10) + (20 << 20));               //  16 MB [b][h][c][r]
  u16*   ms2 = (u16*)ms2c;
  u32*   mT  = (u32*)  (ws + (64 << 10) + (36 << 20));       //   2 MB [b][c][r]
  float* o1  = (float*)(ws + (64 << 10) + (38 << 20));       //   1 MB [b][r][256]
  float* o2  = (float*)(ws + (64 << 10) + (39 << 20));       //   1 MB [b][c][256]
  // Q/K fragment buffers overlap ms2 (consumed by ms_mfma2 before tr16 writes ms2)
  uint4* QQ4  = (uint4*)(ms2c);                              //   1 MB
  uint4* KH4  = (uint4*)(ms2c + (1 << 20));                  // 0.5 MB
  uint4* KL4z = (uint4*)(ms2c + (1 << 20) + (512 << 10));    //   1 MB

  prep_w<<<6, 256, 0, stream>>>(W1, W2, W1Bhi, W1Blo, W2Bhi, W2Blo);
  gemm_bt64<<<dim3(8, 16), 256, 0, stream>>>(x1, Wqv1, qv, 1024, 512, 256);
  gemm_bt64<<<dim3(8, 16), 256, 0, stream>>>(x2, Wkv2, kv, 1024, 512, 256);

  pack_q<<<256, 256, 0, stream>>>(qv, QQ4);
  pack_k<<<128, 256, 0, stream>>>(kv, KH4, KL4z);

  ms_mfma2<<<dim3(32, 8, 2), 256, 0, stream>>>(QQ4, KH4, KL4z, cost,
                                               W1Bhi, W1Blo, W2Bhi, W2Blo, ms1);

  tr16<<<dim3(8, 8, 32), 256, 0, stream>>>(ms1, ms2);
  tr32<<<dim3(8, 8, 2), 256, 0, stream>>>((const u32*)attn, mT);

  softmax_av2<<<dim3(512, 2), 256, 0, stream>>>(ms1, attn, kv, o1);
  softmax_av2<<<dim3(512, 2), 256, 0, stream>>>(ms2, (const int*)mT, qv, o2);

  gemm_bt64<<<dim3(4, 16), 256, 0, stream>>>(o1, Wout1, out, 1024, 256, 256);
  gemm_bt64<<<dim3(4, 16), 256, 0, stream>>>(o2, Wout2, out + (size_t)262144, 1024, 256, 256);
}

// Round 6
// 241.657 us; speedup vs baseline: 2.3309x; 1.0987x over previous
//
#include <hip/hip_runtime.h>
#include <hip/hip_bf16.h>

typedef unsigned int   u32;
typedef unsigned short u16;

typedef __attribute__((ext_vector_type(8))) short sh8;
typedef __attribute__((ext_vector_type(4))) float f32x4;

__device__ __forceinline__ float b2f(u16 u) { union { u32 i; float f; } v; v.i = ((u32)u) << 16; return v.f; }
__device__ __forceinline__ u16   f2b(float f){
  union { float f; u32 i; } v; v.f = f;
  u32 u = v.i;
  u32 r = (u + 0x7fffu + ((u >> 16) & 1u)) >> 16;   // RNE
  return (u16)r;
}
// pack two f32 -> bf16x2 (RNE), lo half = a, hi half = b
__device__ __forceinline__ u32 pk2(float a, float b) {
  __hip_bfloat162 h2 = __float22bfloat162_rn(make_float2(a, b));
  union { __hip_bfloat162 h; u32 u; } v; v.h = h2; return v.u;
}

__device__ __forceinline__ f32x4 mfma16(uint4 a, uint4 b, f32x4 c) {
  union { uint4 u; sh8 s; } ua, ub;
  ua.u = a; ub.u = b;
  return __builtin_amdgcn_mfma_f32_16x16x32_bf16(ua.s, ub.s, c, 0, 0, 0);
}

// ---------------------------------------------------------------------------
// prep_w: MFMA B-operand fragments for W1 (hi/lo) and W2 (hi/lo).
// ---------------------------------------------------------------------------
__global__ void prep_w(const float* __restrict__ W1, const float* __restrict__ W2,
                       uint4* __restrict__ W1Bhi, uint4* __restrict__ W1Blo,
                       uint4* __restrict__ W2Bhi, uint4* __restrict__ W2Blo) {
  int tid = blockIdx.x * 256 + threadIdx.x;
  if (tid < 1024) {
    int L = tid & 63;
    int j = (tid >> 6) * 16 + (L & 15), q = L >> 4;
    u32 hw[4] = {0,0,0,0}, lw[4] = {0,0,0,0};
#pragma unroll
    for (int jj = 0; jj < 8; jj++) {
      float wv = W1[j * 32 + q * 8 + jj];
      u16 hb = f2b(wv); u16 lb = f2b(wv - b2f(hb));
      hw[jj >> 1] |= ((u32)hb) << (16 * (jj & 1));
      lw[jj >> 1] |= ((u32)lb) << (16 * (jj & 1));
    }
    W1Bhi[tid] = make_uint4(hw[0], hw[1], hw[2], hw[3]);
    W1Blo[tid] = make_uint4(lw[0], lw[1], lw[2], lw[3]);
  } else if (tid < 1536) {
    int t = tid - 1024;
    int p = t >> 6, L = t & 63;
    int head = L & 15, q = L >> 4;
    u32 hw[4] = {0,0,0,0}, lw[4] = {0,0,0,0};
#pragma unroll
    for (int jj = 0; jj < 8; jj++) {
      int col = q * 4 + (jj >> 1), half = jj & 1;
      int j = p * 32 + half * 16 + col;
      float wv = W2[head * 256 + j];
      u16 hb = f2b(wv); u16 lb = f2b(wv - b2f(hb));
      hw[jj >> 1] |= ((u32)hb) << (16 * half);
      lw[jj >> 1] |= ((u32)lb) << (16 * half);
    }
    W2Bhi[t] = make_uint4(hw[0], hw[1], hw[2], hw[3]);
    W2Blo[t] = make_uint4(lw[0], lw[1], lw[2], lw[3]);
  }
}

// ---------------------------------------------------------------------------
// gemm_bt64: C = A @ B^T, f32, 64x64 tile, 4x4 microtile per thread.
// ---------------------------------------------------------------------------
__global__ void __launch_bounds__(256)
gemm_bt64(const float* __restrict__ A, const float* __restrict__ Bw,
          float* __restrict__ C, int M, int N, int K) {
  __shared__ float As[16][64];
  __shared__ float Bs[16][64];
  int t = threadIdx.x;
  int tx = t & 15, ty = t >> 4;
  int m0 = blockIdx.y * 64, n0 = blockIdx.x * 64;
  int lrow = t >> 2, lk = (t & 3) * 4;
  float acc[4][4];
#pragma unroll
  for (int i = 0; i < 4; i++)
#pragma unroll
    for (int j = 0; j < 4; j++) acc[i][j] = 0.f;

  for (int k0 = 0; k0 < K; k0 += 16) {
    float4 av = *(const float4*)(A + (size_t)(m0 + lrow) * K + k0 + lk);
    float4 bv = *(const float4*)(Bw + (size_t)(n0 + lrow) * K + k0 + lk);
    __syncthreads();
    As[lk + 0][lrow] = av.x; As[lk + 1][lrow] = av.y;
    As[lk + 2][lrow] = av.z; As[lk + 3][lrow] = av.w;
    Bs[lk + 0][lrow] = bv.x; Bs[lk + 1][lrow] = bv.y;
    Bs[lk + 2][lrow] = bv.z; Bs[lk + 3][lrow] = bv.w;
    __syncthreads();
#pragma unroll
    for (int kk = 0; kk < 16; kk++) {
      float a_[4], b_[4];
#pragma unroll
      for (int i = 0; i < 4; i++) { a_[i] = As[kk][ty * 4 + i]; b_[i] = Bs[kk][tx * 4 + i]; }
#pragma unroll
      for (int i = 0; i < 4; i++)
#pragma unroll
        for (int j = 0; j < 4; j++) acc[i][j] += a_[i] * b_[j];
    }
  }
#pragma unroll
  for (int i = 0; i < 4; i++) {
    float4 o; o.x = acc[i][0]; o.y = acc[i][1]; o.z = acc[i][2]; o.w = acc[i][3];
    *(float4*)(C + (size_t)(m0 + ty * 4 + i) * N + n0 + tx * 4) = o;
  }
}

// ---------------------------------------------------------------------------
// pack_q: Q fragments (x0.25 folded).  QQ4[b][h][q][r] uint4:
//   q=0: hi(d0..7 pairs)  q=1: hi(d8..15)  q=2: lo(d0..7)  q=3: lo(d8..15)
// ---------------------------------------------------------------------------
__global__ void __launch_bounds__(256)
pack_q(const float* __restrict__ qv, uint4* __restrict__ QQ4) {
  int tid = blockIdx.x * 256 + threadIdx.x;  // ((b*512+r)*16+h)*4+q
  int q = tid & 3, h = (tid >> 2) & 15, r = (tid >> 6) & 511, b = tid >> 15;
  const float* src = qv + ((size_t)(b * 512 + r) << 9) + h * 16 + (q & 1) * 8;
  bool lo = q >= 2;
  u32 w[4];
#pragma unroll
  for (int t = 0; t < 4; t++) {
    float a = src[2 * t] * 0.25f, bb = src[2 * t + 1] * 0.25f;
    if (lo) { a -= b2f(f2b(a)); bb -= b2f(f2b(bb)); }
    w[t] = (u32)f2b(a) | ((u32)f2b(bb) << 16);
  }
  QQ4[((size_t)((b * 16 + h) * 4 + q) << 9) + r] = make_uint4(w[0], w[1], w[2], w[3]);
}

// ---------------------------------------------------------------------------
// pack_k: K fragments.  KH4[b][h][qq][c] (hi pairs), KL4z[b][h][q][c]
// (q<2: lo pairs, q>=2: zeros).
// ---------------------------------------------------------------------------
__global__ void __launch_bounds__(256)
pack_k(const float* __restrict__ kv, uint4* __restrict__ KH4, uint4* __restrict__ KL4z) {
  int tid = blockIdx.x * 256 + threadIdx.x;  // ((b*512+c)*16+h)*2+qq
  int qq = tid & 1, h = (tid >> 1) & 15, c = (tid >> 5) & 511, b = tid >> 14;
  const float* src = kv + ((size_t)(b * 512 + c) << 9) + h * 16 + qq * 8;
  u32 hw[4], lw[4];
#pragma unroll
  for (int t = 0; t < 4; t++) {
    float a = src[2 * t], bb = src[2 * t + 1];
    u16 ha = f2b(a), hb = f2b(bb);
    hw[t] = (u32)ha | ((u32)hb << 16);
    lw[t] = (u32)f2b(a - b2f(ha)) | ((u32)f2b(bb - b2f(hb)) << 16);
  }
  KH4[((size_t)((b * 16 + h) * 2 + qq) << 9) + c] = make_uint4(hw[0], hw[1], hw[2], hw[3]);
  KL4z[((size_t)((b * 16 + h) * 4 + qq) << 9) + c] = make_uint4(lw[0], lw[1], lw[2], lw[3]);
  KL4z[((size_t)((b * 16 + h) * 4 + 2 + qq) << 9) + c] = make_uint4(0, 0, 0, 0);
}

// ---------------------------------------------------------------------------
// ms_mfma3: all-MFMA fused QK^T + MixedScoreFF, p-outer K-loop.
// Wave-tile = 16 r x 16 c.  Block = 4 waves (r-split).  Per-wave LDS only.
// Phase A: per head h, 2 MFMAs -> dots D[h][r][c] (f32, LDS, h-stride 260).
// Phase B: p outer (weights loaded once per p), r inner fully unrolled:
//   X-frags recomputed from D + cost, layer1 (6 MFMA) -> H transpose (LDS)
//   -> layer2 (2 MFMA) into acc2[r].  Epilogue stores BOTH ms1 and ms2.
// ---------------------------------------------------------------------------
__global__ void __launch_bounds__(256, 2)
ms_mfma3(const uint4* __restrict__ QQ4, const uint4* __restrict__ KH4,
         const uint4* __restrict__ KL4z, const float* __restrict__ cost,
         const uint4* __restrict__ W1Bhi, const uint4* __restrict__ W1Blo,
         const uint4* __restrict__ W2Bhi, const uint4* __restrict__ W2Blo,
         u16* __restrict__ ms1, u16* __restrict__ ms2) {
  __shared__ __align__(16) u32 Dl[4 * 4160];
  __shared__ __align__(16) u32 Hb[4 * 320];
  int t = threadIdx.x, L = t & 63, w = t >> 6;
  int cl = L & 15, q = L >> 4;
  int b = blockIdx.z, c0 = blockIdx.x * 16, r0 = (blockIdx.y * 4 + w) * 16;
  u32* D  = Dl + w * 4160;
  u32* hb = Hb + w * 320;

  f32x4 z; z[0] = 0.f; z[1] = 0.f; z[2] = 0.f; z[3] = 0.f;

  // ---- phase A: QK^T (scaled) via MFMA, 16 heads ----
  for (int h = 0; h < 16; h++) {
    uint4 qa  = QQ4[((size_t)((b * 16 + h) * 4 + q) << 9) + r0 + cl];       // [qh|ql]
    uint4 qa2 = QQ4[((size_t)((b * 16 + h) * 4 + (q & 1)) << 9) + r0 + cl]; // [qh|qh]
    uint4 kb1 = KH4[((size_t)((b * 16 + h) * 2 + (q & 1)) << 9) + c0 + cl]; // [kh|kh]
    uint4 kb2 = KL4z[((size_t)((b * 16 + h) * 4 + q) << 9) + c0 + cl];      // [kl|0]
    f32x4 d = mfma16(qa, kb1, z);
    d = mfma16(qa2, kb2, d);
#pragma unroll
    for (int i = 0; i < 4; i++)
      D[h * 260 + (q * 4 + i) * 16 + cl] = __float_as_uint(d[i]);
  }

  // ---- phase B: p-outer MLP ----
  float cvr[16];
#pragma unroll
  for (int r = 0; r < 16; r++)
    cvr[r] = cost[((size_t)(b * 512) + r0 + r) * 512 + c0 + cl];

  f32x4 acc2[16];
#pragma unroll
  for (int r = 0; r < 16; r++) acc2[r] = z;

#pragma unroll 1
  for (int p = 0; p < 8; p++) {
    uint4 w1h0 = W1Bhi[(2 * p) * 64 + L], w1h1 = W1Bhi[(2 * p + 1) * 64 + L];
    uint4 w1l0 = W1Blo[(2 * p) * 64 + L], w1l1 = W1Blo[(2 * p + 1) * 64 + L];
    uint4 w2h  = W2Bhi[p * 64 + L],       w2l  = W2Blo[p * 64 + L];
#pragma unroll
    for (int r = 0; r < 16; r++) {
      float cvm = cvr[r];
      u32 cp = pk2(cvm, cvm);
      float cres = cvm - __uint_as_float(cp & 0xffff0000u);
      u32 hw[4], lw[4];
#pragma unroll
      for (int tt = 0; tt < 4; tt++) {
        float dd = __uint_as_float(D[(4 * q + tt) * 260 + r * 16 + cl]);
        u32 hp = pk2(dd, cvm);
        float dres = dd - __uint_as_float(hp << 16);
        hw[tt] = hp;
        lw[tt] = pk2(dres, cres);
      }
      uint4 xhi = make_uint4(hw[0], hw[1], hw[2], hw[3]);
      uint4 xlo = make_uint4(lw[0], lw[1], lw[2], lw[3]);

      f32x4 a0 = z, a1 = z;
      a0 = mfma16(xhi, w1h0, a0);
      a0 = mfma16(xlo, w1h0, a0);
      a0 = mfma16(xhi, w1l0, a0);
      a1 = mfma16(xhi, w1h1, a1);
      a1 = mfma16(xlo, w1h1, a1);
      a1 = mfma16(xhi, w1l1, a1);
#pragma unroll
      for (int i = 0; i < 4; i++)
        hb[(q * 4 + i) * 20 + cl] = pk2(fmaxf(a0[i], 0.f), fmaxf(a1[i], 0.f));
      uint4 hf = *(const uint4*)&hb[cl * 20 + q * 4];
      acc2[r] = mfma16(hf, w2h, acc2[r]);
      acc2[r] = mfma16(hf, w2l, acc2[r]);
    }
  }

  // ---- epilogue: lane (q,cl) holds MS[h=cl][c=c0+4q+i][r0..r0+15] ----
  u32* ms1u = (u32*)ms1;
#pragma unroll
  for (int r = 0; r < 16; r++) {
    size_t base = ((size_t)(b * 16 + cl) * 512 + (r0 + r)) * 256 + (c0 >> 1) + q * 2;
    ms1u[base]     = pk2(acc2[r][0], acc2[r][1]);
    ms1u[base + 1] = pk2(acc2[r][2], acc2[r][3]);
  }
  u32* ms2u = (u32*)ms2;
#pragma unroll
  for (int i = 0; i < 4; i++) {
    int c = c0 + 4 * q + i;
    u32 o[8];
#pragma unroll
    for (int rr = 0; rr < 8; rr++)
      o[rr] = pk2(acc2[2 * rr][i], acc2[2 * rr + 1][i]);
    size_t base2 = ((size_t)(b * 16 + cl) * 512 + c) * 256 + (r0 >> 1);
    *(uint4*)&ms2u[base2]     = make_uint4(o[0], o[1], o[2], o[3]);
    *(uint4*)&ms2u[base2 + 4] = make_uint4(o[4], o[5], o[6], o[7]);
  }
}

// ---------------------------------------------------------------------------
// 64x64 u32 transpose per plane (plane = b), for the attention mask.
// ---------------------------------------------------------------------------
__global__ void __launch_bounds__(256)
tr32(const u32* __restrict__ src, u32* __restrict__ dst) {
  __shared__ u32 tile[64][65];
  int t = threadIdx.x;
  int rl = t >> 4, cw = t & 15;
  size_t base = (size_t)blockIdx.z * 262144;
  int r0 = blockIdx.y * 64, c0 = blockIdx.x * 64;
#pragma unroll
  for (int pass = 0; pass < 4; pass++) {
    int row = pass * 16 + rl;
    uint4 v = *(const uint4*)(src + base + (size_t)(r0 + row) * 512 + c0 + cw * 4);
    tile[row][cw * 4 + 0] = v.x; tile[row][cw * 4 + 1] = v.y;
    tile[row][cw * 4 + 2] = v.z; tile[row][cw * 4 + 3] = v.w;
  }
  __syncthreads();
#pragma unroll
  for (int pass = 0; pass < 4; pass++) {
    int crow = pass * 16 + rl;
    uint4 o = make_uint4(tile[cw * 4 + 0][crow], tile[cw * 4 + 1][crow],
                         tile[cw * 4 + 2][crow], tile[cw * 4 + 3][crow]);
    *(uint4*)(dst + base + (size_t)(c0 + crow) * 512 + r0 + cw * 4) = o;
  }
}

// ---------------------------------------------------------------------------
// softmax_av2: block (256 thr) per (b,fix).  Phase A: 4 waves x 4 heads
// masked softmax -> LDS.  Phase B: coalesced float4 V accumulation.
// ---------------------------------------------------------------------------
__global__ void __launch_bounds__(256)
softmax_av2(const u16* __restrict__ ms,     // [b*16+h][fix][512] bf16
            const int* __restrict__ mask,   // [b][fix][512]
            const float* __restrict__ vbuf, // [b][512][512]; V at cols 256..511
            float* __restrict__ obuf) {     // [b][fix][256]
  __shared__ float  pbuf[16 * 514];
  __shared__ float  sden[16];
  __shared__ float4 red[4][64];
  int t = threadIdx.x, lane = t & 63, w = t >> 6;
  int fix = blockIdx.x, b = blockIdx.y;

  const int* krow = mask + ((size_t)b * 512 + fix) * 512;
  bool vd[8];
#pragma unroll
  for (int i = 0; i < 8; i++) vd[i] = krow[i * 64 + lane] != 0;
  bool anyl = false;
#pragma unroll
  for (int i = 0; i < 8; i++) anyl |= vd[i];
  bool useMask = (__ballot(anyl) != 0ULL);   // fully-masked row => unmask all

#pragma unroll
  for (int hh = 0; hh < 4; hh++) {
    int h = w * 4 + hh;
    const u16* mrow = ms + ((size_t)(b * 16 + h) * 512 + fix) * 512;
    float lg[8];
#pragma unroll
    for (int i = 0; i < 8; i++) lg[i] = b2f(mrow[i * 64 + lane]);
    float mx = -3.4e38f;
#pragma unroll
    for (int i = 0; i < 8; i++)
      if (!(useMask && !vd[i])) mx = fmaxf(mx, lg[i]);
    for (int off = 32; off; off >>= 1) mx = fmaxf(mx, __shfl_xor(mx, off));
    float s = 0.f;
#pragma unroll
    for (int i = 0; i < 8; i++) {
      float p = (useMask && !vd[i]) ? 0.f : __expf(lg[i] - mx);
      pbuf[h * 514 + i * 64 + lane] = p;
      s += p;
    }
    for (int off = 32; off; off >>= 1) s += __shfl_xor(s, off);
    if (lane == 0) sden[h] = s;
  }
  __syncthreads();

  int hb = lane >> 2, dq = lane & 3;
  const float* vb = vbuf + ((size_t)b * 512) * 512 + 256 + hb * 16 + dq * 4;
  float4 acc = make_float4(0.f, 0.f, 0.f, 0.f);
  for (int it = 0; it < 128; it += 4) {
#pragma unroll
    for (int u = 0; u < 4; u++) {
      int cc = (it + u) * 4 + w;
      float pv = pbuf[hb * 514 + cc];
      float4 v = *(const float4*)(vb + (size_t)cc * 512);
      acc.x += pv * v.x; acc.y += pv * v.y; acc.z += pv * v.z; acc.w += pv * v.w;
    }
  }
  red[w][lane] = acc;
  __syncthreads();
  if (w == 0) {
    float4 a = red[0][lane], b1 = red[1][lane], c1 = red[2][lane], d1 = red[3][lane];
    float inv = 1.f / sden[hb];
    float4 o;
    o.x = (a.x + b1.x + c1.x + d1.x) * inv;
    o.y = (a.y + b1.y + c1.y + d1.y) * inv;
    o.z = (a.z + b1.z + c1.z + d1.z) * inv;
    o.w = (a.w + b1.w + c1.w + d1.w) * inv;
    *(float4*)(obuf + ((size_t)b * 512 + fix) * 256 + lane * 4) = o;
  }
}

// ---------------------------------------------------------------------------
extern "C" void kernel_launch(void* const* d_in, const int* in_sizes, int n_in,
                              void* d_out, int out_size, void* d_ws, size_t ws_size,
                              hipStream_t stream) {
  const float* x1    = (const float*)d_in[0];
  const float* x2    = (const float*)d_in[1];
  const int*   attn  = (const int*)d_in[2];
  const float* cost  = (const float*)d_in[3];
  const float* Wqv1  = (const float*)d_in[4];
  const float* Wkv2  = (const float*)d_in[5];
  const float* W1    = (const float*)d_in[6];
  const float* W2    = (const float*)d_in[7];
  const float* Wout1 = (const float*)d_in[8];
  const float* Wout2 = (const float*)d_in[9];
  float* out = (float*)d_out;

  char* ws = (char*)d_ws;
  uint4* W1Bhi = (uint4*)(ws);                               // 16 KB
  uint4* W1Blo = (uint4*)(ws + (16 << 10));                  // 16 KB
  uint4* W2Bhi = (uint4*)(ws + (32 << 10));                  //  8 KB
  uint4* W2Blo = (uint4*)(ws + (40 << 10));                  //  8 KB
  float* qv  = (float*)(ws + (64 << 10));                    //   2 MB [b][r][512]
  float* kv  = (float*)(ws + (64 << 10) + (2 << 20));        //   2 MB [b][c][512]
  u16*   ms1 = (u16*)  (ws + (64 << 10) + (4 << 20));        //  16 MB [b][h][r][c]
  u16*   ms2 = (u16*)  (ws + (64 << 10) + (20 << 20));       //  16 MB [b][h][c][r]
  char*  tail= (ws + (64 << 10) + (36 << 20));
  u32*   mT  = (u32*)  (tail);                               //   2 MB [b][c][r]
  float* o1  = (float*)(tail + (2 << 20));                   //   1 MB [b][r][256]
  float* o2  = (float*)(tail + (3 << 20));                   //   1 MB [b][c][256]
  // Q/K fragment buffers overlap mT+o1 (dead after ms_mfma3; tr32/softmax
  // write mT/o1 only after ms_mfma3 has consumed the fragments).
  uint4* QQ4  = (uint4*)(tail);                              //   1 MB
  uint4* KH4  = (uint4*)(tail + (1 << 20));                  // 0.5 MB
  uint4* KL4z = (uint4*)(tail + (1 << 20) + (512 << 10));    //   1 MB

  prep_w<<<6, 256, 0, stream>>>(W1, W2, W1Bhi, W1Blo, W2Bhi, W2Blo);
  gemm_bt64<<<dim3(8, 16), 256, 0, stream>>>(x1, Wqv1, qv, 1024, 512, 256);
  gemm_bt64<<<dim3(8, 16), 256, 0, stream>>>(x2, Wkv2, kv, 1024, 512, 256);

  pack_q<<<256, 256, 0, stream>>>(qv, QQ4);
  pack_k<<<128, 256, 0, stream>>>(kv, KH4, KL4z);

  ms_mfma3<<<dim3(32, 8, 2), 256, 0, stream>>>(QQ4, KH4, KL4z, cost,
                                               W1Bhi, W1Blo, W2Bhi, W2Blo, ms1, ms2);

  tr32<<<dim3(8, 8, 2), 256, 0, stream>>>((const u32*)attn, mT);

  softmax_av2<<<dim3(512, 2), 256, 0, stream>>>(ms1, attn, kv, o1);
  softmax_av2<<<dim3(512, 2), 256, 0, stream>>>(ms2, (const int*)mT, qv, o2);

  gemm_bt64<<<dim3(4, 16), 256, 0, stream>>>(o1, Wout1, out, 1024, 256, 256);
  gemm_bt64<<<dim3(4, 16), 256, 0, stream>>>(o2, Wout2, out + (size_t)262144, 1024, 256, 256);
}

// Round 7
// 220.796 us; speedup vs baseline: 2.5512x; 1.0945x over previous
//
#include <hip/hip_runtime.h>
#include <hip/hip_bf16.h>

typedef unsigned int   u32;
typedef unsigned short u16;

typedef __attribute__((ext_vector_type(8))) short sh8;
typedef __attribute__((ext_vector_type(4))) float f32x4;

__device__ __forceinline__ float b2f(u16 u) { union { u32 i; float f; } v; v.i = ((u32)u) << 16; return v.f; }
__device__ __forceinline__ u16   f2b(float f){
  union { float f; u32 i; } v; v.f = f;
  u32 u = v.i;
  u32 r = (u + 0x7fffu + ((u >> 16) & 1u)) >> 16;   // RNE
  return (u16)r;
}
// pack two f32 -> bf16x2 (RNE), lo half = a, hi half = b
__device__ __forceinline__ u32 pk2(float a, float b) {
  __hip_bfloat162 h2 = __float22bfloat162_rn(make_float2(a, b));
  union { __hip_bfloat162 h; u32 u; } v; v.h = h2; return v.u;
}

__device__ __forceinline__ f32x4 mfma16(uint4 a, uint4 b, f32x4 c) {
  union { uint4 u; sh8 s; } ua, ub;
  ua.u = a; ub.u = b;
  return __builtin_amdgcn_mfma_f32_16x16x32_bf16(ua.s, ub.s, c, 0, 0, 0);
}

// ---------------------------------------------------------------------------
// gemm_bt64: C = A @ B^T, f32, 64x64 tile, 4x4 microtile per thread.
// ---------------------------------------------------------------------------
__global__ void __launch_bounds__(256)
gemm_bt64(const float* __restrict__ A, const float* __restrict__ Bw,
          float* __restrict__ C, int M, int N, int K) {
  __shared__ float As[16][64];
  __shared__ float Bs[16][64];
  int t = threadIdx.x;
  int tx = t & 15, ty = t >> 4;
  int m0 = blockIdx.y * 64, n0 = blockIdx.x * 64;
  int lrow = t >> 2, lk = (t & 3) * 4;
  float acc[4][4];
#pragma unroll
  for (int i = 0; i < 4; i++)
#pragma unroll
    for (int j = 0; j < 4; j++) acc[i][j] = 0.f;

  for (int k0 = 0; k0 < K; k0 += 16) {
    float4 av = *(const float4*)(A + (size_t)(m0 + lrow) * K + k0 + lk);
    float4 bv = *(const float4*)(Bw + (size_t)(n0 + lrow) * K + k0 + lk);
    __syncthreads();
    As[lk + 0][lrow] = av.x; As[lk + 1][lrow] = av.y;
    As[lk + 2][lrow] = av.z; As[lk + 3][lrow] = av.w;
    Bs[lk + 0][lrow] = bv.x; Bs[lk + 1][lrow] = bv.y;
    Bs[lk + 2][lrow] = bv.z; Bs[lk + 3][lrow] = bv.w;
    __syncthreads();
#pragma unroll
    for (int kk = 0; kk < 16; kk++) {
      float4 a4 = *(const float4*)&As[kk][ty * 4];
      float4 b4 = *(const float4*)&Bs[kk][tx * 4];
      float a_[4] = {a4.x, a4.y, a4.z, a4.w};
      float b_[4] = {b4.x, b4.y, b4.z, b4.w};
#pragma unroll
      for (int i = 0; i < 4; i++)
#pragma unroll
        for (int j = 0; j < 4; j++) acc[i][j] += a_[i] * b_[j];
    }
  }
#pragma unroll
  for (int i = 0; i < 4; i++) {
    float4 o; o.x = acc[i][0]; o.y = acc[i][1]; o.z = acc[i][2]; o.w = acc[i][3];
    *(float4*)(C + (size_t)(m0 + ty * 4 + i) * N + n0 + tx * 4) = o;
  }
}

// ---------------------------------------------------------------------------
// pack_all: fuses pack_q (blocks 0..255), pack_k (256..383), prep_w (384..389).
// QQ4[b][h][q][r]: q=0 hi(d0..7) q=1 hi(d8..15) q=2 lo(d0..7) q=3 lo(d8..15)
// KH4[b][h][qq][c] hi pairs; KL4z[b][h][q][c]: q<2 lo pairs, q>=2 zeros.
// W1B*: [16 ntiles][64 lanes] uint4 ; W2B*: [8 chunks][64 lanes] uint4.
// ---------------------------------------------------------------------------
__global__ void __launch_bounds__(256)
pack_all(const float* __restrict__ qv, const float* __restrict__ kv,
         const float* __restrict__ W1, const float* __restrict__ W2,
         uint4* __restrict__ QQ4, uint4* __restrict__ KH4, uint4* __restrict__ KL4z,
         uint4* __restrict__ W1Bhi, uint4* __restrict__ W1Blo,
         uint4* __restrict__ W2Bhi, uint4* __restrict__ W2Blo) {
  int blk = blockIdx.x;
  if (blk < 256) {
    int tid = blk * 256 + threadIdx.x;       // ((b*512+r)*16+h)*4+q
    int q = tid & 3, h = (tid >> 2) & 15, r = (tid >> 6) & 511, b = tid >> 15;
    const float* src = qv + ((size_t)(b * 512 + r) << 9) + h * 16 + (q & 1) * 8;
    bool lo = q >= 2;
    u32 w[4];
#pragma unroll
    for (int t = 0; t < 4; t++) {
      float a = src[2 * t] * 0.25f, bb = src[2 * t + 1] * 0.25f;
      if (lo) { a -= b2f(f2b(a)); bb -= b2f(f2b(bb)); }
      w[t] = (u32)f2b(a) | ((u32)f2b(bb) << 16);
    }
    QQ4[((size_t)((b * 16 + h) * 4 + q) << 9) + r] = make_uint4(w[0], w[1], w[2], w[3]);
  } else if (blk < 384) {
    int tid = (blk - 256) * 256 + threadIdx.x;  // ((b*512+c)*16+h)*2+qq
    int qq = tid & 1, h = (tid >> 1) & 15, c = (tid >> 5) & 511, b = tid >> 14;
    const float* src = kv + ((size_t)(b * 512 + c) << 9) + h * 16 + qq * 8;
    u32 hw[4], lw[4];
#pragma unroll
    for (int t = 0; t < 4; t++) {
      float a = src[2 * t], bb = src[2 * t + 1];
      u16 ha = f2b(a), hb = f2b(bb);
      hw[t] = (u32)ha | ((u32)hb << 16);
      lw[t] = (u32)f2b(a - b2f(ha)) | ((u32)f2b(bb - b2f(hb)) << 16);
    }
    KH4[((size_t)((b * 16 + h) * 2 + qq) << 9) + c] = make_uint4(hw[0], hw[1], hw[2], hw[3]);
    KL4z[((size_t)((b * 16 + h) * 4 + qq) << 9) + c] = make_uint4(lw[0], lw[1], lw[2], lw[3]);
    KL4z[((size_t)((b * 16 + h) * 4 + 2 + qq) << 9) + c] = make_uint4(0, 0, 0, 0);
  } else {
    int tid = (blk - 384) * 256 + threadIdx.x;
    if (tid < 1024) {
      int L = tid & 63;
      int j = (tid >> 6) * 16 + (L & 15), q = L >> 4;
      u32 hw[4] = {0,0,0,0}, lw[4] = {0,0,0,0};
#pragma unroll
      for (int jj = 0; jj < 8; jj++) {
        float wv = W1[j * 32 + q * 8 + jj];
        u16 hb = f2b(wv); u16 lb = f2b(wv - b2f(hb));
        hw[jj >> 1] |= ((u32)hb) << (16 * (jj & 1));
        lw[jj >> 1] |= ((u32)lb) << (16 * (jj & 1));
      }
      W1Bhi[tid] = make_uint4(hw[0], hw[1], hw[2], hw[3]);
      W1Blo[tid] = make_uint4(lw[0], lw[1], lw[2], lw[3]);
    } else if (tid < 1536) {
      int t2 = tid - 1024;
      int p = t2 >> 6, L = t2 & 63;
      int head = L & 15, q = L >> 4;
      u32 hw[4] = {0,0,0,0}, lw[4] = {0,0,0,0};
#pragma unroll
      for (int jj = 0; jj < 8; jj++) {
        int col = q * 4 + (jj >> 1), half = jj & 1;
        int j = p * 32 + half * 16 + col;
        float wv = W2[head * 256 + j];
        u16 hb = f2b(wv); u16 lb = f2b(wv - b2f(hb));
        hw[jj >> 1] |= ((u32)hb) << (16 * half);
        lw[jj >> 1] |= ((u32)lb) << (16 * half);
      }
      W2Bhi[t2] = make_uint4(hw[0], hw[1], hw[2], hw[3]);
      W2Blo[t2] = make_uint4(lw[0], lw[1], lw[2], lw[3]);
    }
  }
}

// ---------------------------------------------------------------------------
// ms_mfma4: all-MFMA fused QK^T + MixedScoreFF, p-outer K-loop, X hoisted
// into registers (built once per r), weights loaded once per p.
// Wave-tile = 16 r x 16 c.  Block = 4 waves (r-split).  Per-wave LDS only.
// ---------------------------------------------------------------------------
__global__ void __launch_bounds__(256, 2)
ms_mfma4(const uint4* __restrict__ QQ4, const uint4* __restrict__ KH4,
         const uint4* __restrict__ KL4z, const float* __restrict__ cost,
         const uint4* __restrict__ W1Bhi, const uint4* __restrict__ W1Blo,
         const uint4* __restrict__ W2Bhi, const uint4* __restrict__ W2Blo,
         u16* __restrict__ ms1, u16* __restrict__ ms2) {
  __shared__ __align__(16) u32 Dl[4 * 4160];
  __shared__ __align__(16) u32 Hb[4 * 320];
  int t = threadIdx.x, L = t & 63, w = t >> 6;
  int cl = L & 15, q = L >> 4;
  int b = blockIdx.z, c0 = blockIdx.x * 16, r0 = (blockIdx.y * 4 + w) * 16;
  u32* D  = Dl + w * 4160;
  u32* hb = Hb + w * 320;

  f32x4 z; z[0] = 0.f; z[1] = 0.f; z[2] = 0.f; z[3] = 0.f;

  // ---- phase A: QK^T (scaled) via MFMA, 16 heads -> D[h][r][c] in LDS ----
  for (int h = 0; h < 16; h++) {
    uint4 qa  = QQ4[((size_t)((b * 16 + h) * 4 + q) << 9) + r0 + cl];       // [qh|ql]
    uint4 qa2 = QQ4[((size_t)((b * 16 + h) * 4 + (q & 1)) << 9) + r0 + cl]; // [qh|qh]
    uint4 kb1 = KH4[((size_t)((b * 16 + h) * 2 + (q & 1)) << 9) + c0 + cl]; // [kh|kh]
    uint4 kb2 = KL4z[((size_t)((b * 16 + h) * 4 + q) << 9) + c0 + cl];      // [kl|0]
    f32x4 d = mfma16(qa, kb1, z);
    d = mfma16(qa2, kb2, d);
#pragma unroll
    for (int i = 0; i < 4; i++)
      D[h * 260 + (q * 4 + i) * 16 + cl] = __float_as_uint(d[i]);
  }

  // ---- phase A2: build X fragments (once per r) into registers ----
  uint4 xhi[16], xlo[16];
#pragma unroll
  for (int r = 0; r < 16; r++) {
    float cvm = cost[((size_t)(b * 512) + r0 + r) * 512 + c0 + cl];
    u32 cp = pk2(cvm, cvm);
    float cres = cvm - __uint_as_float(cp & 0xffff0000u);
    u32 hw[4], lw[4];
#pragma unroll
    for (int tt = 0; tt < 4; tt++) {
      float dd = __uint_as_float(D[(4 * q + tt) * 260 + r * 16 + cl]);
      u32 hp = pk2(dd, cvm);
      float dres = dd - __uint_as_float(hp << 16);
      hw[tt] = hp;
      lw[tt] = pk2(dres, cres);
    }
    xhi[r] = make_uint4(hw[0], hw[1], hw[2], hw[3]);
    xlo[r] = make_uint4(lw[0], lw[1], lw[2], lw[3]);
  }

  // ---- phase B: p-outer MLP, weights loaded once per p ----
  f32x4 acc2[16];
#pragma unroll
  for (int r = 0; r < 16; r++) acc2[r] = z;

#pragma unroll 1
  for (int p = 0; p < 8; p++) {
    uint4 w1h0 = W1Bhi[(2 * p) * 64 + L], w1h1 = W1Bhi[(2 * p + 1) * 64 + L];
    uint4 w1l0 = W1Blo[(2 * p) * 64 + L], w1l1 = W1Blo[(2 * p + 1) * 64 + L];
    uint4 w2h  = W2Bhi[p * 64 + L],       w2l  = W2Blo[p * 64 + L];
#pragma unroll
    for (int r = 0; r < 16; r++) {
      f32x4 a0 = z, a1 = z;
      a0 = mfma16(xhi[r], w1h0, a0);
      a0 = mfma16(xlo[r], w1h0, a0);
      a0 = mfma16(xhi[r], w1l0, a0);
      a1 = mfma16(xhi[r], w1h1, a1);
      a1 = mfma16(xlo[r], w1h1, a1);
      a1 = mfma16(xhi[r], w1l1, a1);
#pragma unroll
      for (int i = 0; i < 4; i++)
        hb[(q * 4 + i) * 20 + cl] = pk2(fmaxf(a0[i], 0.f), fmaxf(a1[i], 0.f));
      uint4 hf = *(const uint4*)&hb[cl * 20 + q * 4];
      acc2[r] = mfma16(hf, w2h, acc2[r]);
      acc2[r] = mfma16(hf, w2l, acc2[r]);
    }
  }

  // ---- epilogue: lane (q,cl) holds MS[h=cl][c=c0+4q+i][r0..r0+15] ----
  u32* ms1u = (u32*)ms1;
#pragma unroll
  for (int r = 0; r < 16; r++) {
    size_t base = ((size_t)(b * 16 + cl) * 512 + (r0 + r)) * 256 + (c0 >> 1) + q * 2;
    ms1u[base]     = pk2(acc2[r][0], acc2[r][1]);
    ms1u[base + 1] = pk2(acc2[r][2], acc2[r][3]);
  }
  u32* ms2u = (u32*)ms2;
#pragma unroll
  for (int i = 0; i < 4; i++) {
    int c = c0 + 4 * q + i;
    u32 o[8];
#pragma unroll
    for (int rr = 0; rr < 8; rr++)
      o[rr] = pk2(acc2[2 * rr][i], acc2[2 * rr + 1][i]);
    size_t base2 = ((size_t)(b * 16 + cl) * 512 + c) * 256 + (r0 >> 1);
    *(uint4*)&ms2u[base2]     = make_uint4(o[0], o[1], o[2], o[3]);
    *(uint4*)&ms2u[base2 + 4] = make_uint4(o[4], o[5], o[6], o[7]);
  }
}

// ---------------------------------------------------------------------------
// 64x64 u32 transpose per plane (plane = b), for the attention mask.
// ---------------------------------------------------------------------------
__global__ void __launch_bounds__(256)
tr32(const u32* __restrict__ src, u32* __restrict__ dst) {
  __shared__ u32 tile[64][65];
  int t = threadIdx.x;
  int rl = t >> 4, cw = t & 15;
  size_t base = (size_t)blockIdx.z * 262144;
  int r0 = blockIdx.y * 64, c0 = blockIdx.x * 64;
#pragma unroll
  for (int pass = 0; pass < 4; pass++) {
    int row = pass * 16 + rl;
    uint4 v = *(const uint4*)(src + base + (size_t)(r0 + row) * 512 + c0 + cw * 4);
    tile[row][cw * 4 + 0] = v.x; tile[row][cw * 4 + 1] = v.y;
    tile[row][cw * 4 + 2] = v.z; tile[row][cw * 4 + 3] = v.w;
  }
  __syncthreads();
#pragma unroll
  for (int pass = 0; pass < 4; pass++) {
    int crow = pass * 16 + rl;
    uint4 o = make_uint4(tile[cw * 4 + 0][crow], tile[cw * 4 + 1][crow],
                         tile[cw * 4 + 2][crow], tile[cw * 4 + 3][crow]);
    *(uint4*)(dst + base + (size_t)(c0 + crow) * 512 + r0 + cw * 4) = o;
  }
}

// ---------------------------------------------------------------------------
// softmax_av3: block (256 thr) per (b, 2 fix rows).  Phase A: masked softmax
// weights for both rows -> LDS.  Phase B: each V float4 load feeds both rows.
// ---------------------------------------------------------------------------
__global__ void __launch_bounds__(256)
softmax_av3(const u16* __restrict__ ms,     // [b*16+h][fix][512] bf16
            const int* __restrict__ mask,   // [b][fix][512]
            const float* __restrict__ vbuf, // [b][512][512]; V at cols 256..511
            float* __restrict__ obuf) {     // [b][fix][256]
  __shared__ float  pbuf[2][8224];          // 16*514 per fix
  __shared__ float  sden[2][16];
  __shared__ float4 red[2][4][64];
  int t = threadIdx.x, lane = t & 63, w = t >> 6;
  int fix0 = blockIdx.x * 2, b = blockIdx.y;

#pragma unroll
  for (int f = 0; f < 2; f++) {
    int fix = fix0 + f;
    const int* krow = mask + ((size_t)b * 512 + fix) * 512;
    bool vd[8];
#pragma unroll
    for (int i = 0; i < 8; i++) vd[i] = krow[i * 64 + lane] != 0;
    bool anyl = false;
#pragma unroll
    for (int i = 0; i < 8; i++) anyl |= vd[i];
    bool useMask = (__ballot(anyl) != 0ULL);   // fully-masked row => unmask all

#pragma unroll
    for (int hh = 0; hh < 4; hh++) {
      int h = w * 4 + hh;
      const u16* mrow = ms + ((size_t)(b * 16 + h) * 512 + fix) * 512;
      float lg[8];
#pragma unroll
      for (int i = 0; i < 8; i++) lg[i] = b2f(mrow[i * 64 + lane]);
      float mx = -3.4e38f;
#pragma unroll
      for (int i = 0; i < 8; i++)
        if (!(useMask && !vd[i])) mx = fmaxf(mx, lg[i]);
      for (int off = 32; off; off >>= 1) mx = fmaxf(mx, __shfl_xor(mx, off));
      float s = 0.f;
#pragma unroll
      for (int i = 0; i < 8; i++) {
        float p = (useMask && !vd[i]) ? 0.f : __expf(lg[i] - mx);
        pbuf[f][h * 514 + i * 64 + lane] = p;
        s += p;
      }
      for (int off = 32; off; off >>= 1) s += __shfl_xor(s, off);
      if (lane == 0) sden[f][h] = s;
    }
  }
  __syncthreads();

  // phase B: thread (w, h=lane>>2, dq=lane&3) accumulates cc = 4*it + w
  int hb = lane >> 2, dq = lane & 3;
  const float* vb = vbuf + (size_t)b * 262144 + 256 + hb * 16 + dq * 4;
  float4 a0 = make_float4(0.f, 0.f, 0.f, 0.f);
  float4 a1 = make_float4(0.f, 0.f, 0.f, 0.f);
  for (int it = 0; it < 128; it++) {
    int cc = it * 4 + w;
    float4 v = *(const float4*)(vb + (size_t)cc * 512);
    float p0 = pbuf[0][hb * 514 + cc];
    float p1 = pbuf[1][hb * 514 + cc];
    a0.x += p0 * v.x; a0.y += p0 * v.y; a0.z += p0 * v.z; a0.w += p0 * v.w;
    a1.x += p1 * v.x; a1.y += p1 * v.y; a1.z += p1 * v.z; a1.w += p1 * v.w;
  }
  red[0][w][lane] = a0;
  red[1][w][lane] = a1;
  __syncthreads();
  if (w < 2) {
    float4 s0 = red[w][0][lane], s1 = red[w][1][lane];
    float4 s2 = red[w][2][lane], s3 = red[w][3][lane];
    float inv = 1.f / sden[w][hb];
    float4 o;
    o.x = (s0.x + s1.x + s2.x + s3.x) * inv;
    o.y = (s0.y + s1.y + s2.y + s3.y) * inv;
    o.z = (s0.z + s1.z + s2.z + s3.z) * inv;
    o.w = (s0.w + s1.w + s2.w + s3.w) * inv;
    *(float4*)(obuf + ((size_t)b * 512 + fix0 + w) * 256 + lane * 4) = o;
  }
}

// ---------------------------------------------------------------------------
extern "C" void kernel_launch(void* const* d_in, const int* in_sizes, int n_in,
                              void* d_out, int out_size, void* d_ws, size_t ws_size,
                              hipStream_t stream) {
  const float* x1    = (const float*)d_in[0];
  const float* x2    = (const float*)d_in[1];
  const int*   attn  = (const int*)d_in[2];
  const float* cost  = (const float*)d_in[3];
  const float* Wqv1  = (const float*)d_in[4];
  const float* Wkv2  = (const float*)d_in[5];
  const float* W1    = (const float*)d_in[6];
  const float* W2    = (const float*)d_in[7];
  const float* Wout1 = (const float*)d_in[8];
  const float* Wout2 = (const float*)d_in[9];
  float* out = (float*)d_out;

  char* ws = (char*)d_ws;
  uint4* W1Bhi = (uint4*)(ws);                               // 16 KB
  uint4* W1Blo = (uint4*)(ws + (16 << 10));                  // 16 KB
  uint4* W2Bhi = (uint4*)(ws + (32 << 10));                  //  8 KB
  uint4* W2Blo = (uint4*)(ws + (40 << 10));                  //  8 KB
  float* qv  = (float*)(ws + (64 << 10));                    //   2 MB [b][r][512]
  float* kv  = (float*)(ws + (64 << 10) + (2 << 20));        //   2 MB [b][c][512]
  u16*   ms1 = (u16*)  (ws + (64 << 10) + (4 << 20));        //  16 MB [b][h][r][c]
  u16*   ms2 = (u16*)  (ws + (64 << 10) + (20 << 20));       //  16 MB [b][h][c][r]
  char*  tail= (ws + (64 << 10) + (36 << 20));
  u32*   mT  = (u32*)  (tail);                               //   2 MB [b][c][r]
  float* o1  = (float*)(tail + (2 << 20));                   //   1 MB [b][r][256]
  float* o2  = (float*)(tail + (3 << 20));                   //   1 MB [b][c][256]
  // Q/K fragment buffers overlap mT+o1 (dead after ms_mfma4; tr32/softmax
  // write mT/o1 only after ms_mfma4 has consumed the fragments).
  uint4* QQ4  = (uint4*)(tail);                              //   1 MB
  uint4* KH4  = (uint4*)(tail + (1 << 20));                  // 0.5 MB
  uint4* KL4z = (uint4*)(tail + (1 << 20) + (512 << 10));    //   1 MB

  gemm_bt64<<<dim3(8, 16), 256, 0, stream>>>(x1, Wqv1, qv, 1024, 512, 256);
  gemm_bt64<<<dim3(8, 16), 256, 0, stream>>>(x2, Wkv2, kv, 1024, 512, 256);

  pack_all<<<390, 256, 0, stream>>>(qv, kv, W1, W2, QQ4, KH4, KL4z,
                                    W1Bhi, W1Blo, W2Bhi, W2Blo);

  ms_mfma4<<<dim3(32, 8, 2), 256, 0, stream>>>(QQ4, KH4, KL4z, cost,
                                               W1Bhi, W1Blo, W2Bhi, W2Blo, ms1, ms2);

  tr32<<<dim3(8, 8, 2), 256, 0, stream>>>((const u32*)attn, mT);

  softmax_av3<<<dim3(256, 2), 256, 0, stream>>>(ms1, attn, kv, o1);
  softmax_av3<<<dim3(256, 2), 256, 0, stream>>>(ms2, (const int*)mT, qv, o2);

  gemm_bt64<<<dim3(4, 16), 256, 0, stream>>>(o1, Wout1, out, 1024, 256, 256);
  gemm_bt64<<<dim3(4, 16), 256, 0, stream>>>(o2, Wout2, out + (size_t)262144, 1024, 256, 256);
}

// Round 8
// 187.422 us; speedup vs baseline: 3.0054x; 1.1781x over previous
//
#include <hip/hip_runtime.h>
#include <hip/hip_bf16.h>

typedef unsigned int   u32;
typedef unsigned short u16;

typedef __attribute__((ext_vector_type(8))) short    sh8;
typedef __attribute__((ext_vector_type(4))) float    f32x4;
typedef __attribute__((ext_vector_type(4))) _Float16 f16x4;

union F16x4 { f16x4 v; uint2 u; _Float16 h[4]; };

__device__ __forceinline__ float b2f(u16 u) { union { u32 i; float f; } v; v.i = ((u32)u) << 16; return v.f; }
__device__ __forceinline__ u16   f2b(float f){
  union { float f; u32 i; } v; v.f = f;
  u32 u = v.i;
  u32 r = (u + 0x7fffu + ((u >> 16) & 1u)) >> 16;   // RNE
  return (u16)r;
}
// pack two f32 -> bf16x2 (RNE), lo half = a, hi half = b
__device__ __forceinline__ u32 pk2(float a, float b) {
  __hip_bfloat162 h2 = __float22bfloat162_rn(make_float2(a, b));
  union { __hip_bfloat162 h; u32 u; } v; v.h = h2; return v.u;
}

__device__ __forceinline__ f32x4 mfma16(uint4 a, uint4 b, f32x4 c) {
  union { uint4 u; sh8 s; } ua, ub;
  ua.u = a; ub.u = b;
  return __builtin_amdgcn_mfma_f32_16x16x32_bf16(ua.s, ub.s, c, 0, 0, 0);
}
__device__ __forceinline__ f32x4 mfma_h16(f16x4 a, f16x4 b, f32x4 c) {
  return __builtin_amdgcn_mfma_f32_16x16x16f16(a, b, c, 0, 0, 0);
}

// ---------------------------------------------------------------------------
// gemm2: two independent C = A @ B^T f32 GEMMs in one launch (sel = by>>4).
// 64x64 tile, 4x4 microtile per thread.  M = 1024 per matrix.
// ---------------------------------------------------------------------------
__global__ void __launch_bounds__(256)
gemm2(const float* __restrict__ A0, const float* __restrict__ B0, float* __restrict__ C0,
      const float* __restrict__ A1, const float* __restrict__ B1, float* __restrict__ C1,
      int N, int K) {
  __shared__ float As[16][64];
  __shared__ float Bs[16][64];
  int t = threadIdx.x;
  int by = blockIdx.y, sel = by >> 4;
  const float* A  = sel ? A1 : A0;
  const float* Bw = sel ? B1 : B0;
  float*       C  = sel ? C1 : C0;
  int tx = t & 15, ty = t >> 4;
  int m0 = (by & 15) * 64, n0 = blockIdx.x * 64;
  int lrow = t >> 2, lk = (t & 3) * 4;
  float acc[4][4];
#pragma unroll
  for (int i = 0; i < 4; i++)
#pragma unroll
    for (int j = 0; j < 4; j++) acc[i][j] = 0.f;

  for (int k0 = 0; k0 < K; k0 += 16) {
    float4 av = *(const float4*)(A + (size_t)(m0 + lrow) * K + k0 + lk);
    float4 bv = *(const float4*)(Bw + (size_t)(n0 + lrow) * K + k0 + lk);
    __syncthreads();
    As[lk + 0][lrow] = av.x; As[lk + 1][lrow] = av.y;
    As[lk + 2][lrow] = av.z; As[lk + 3][lrow] = av.w;
    Bs[lk + 0][lrow] = bv.x; Bs[lk + 1][lrow] = bv.y;
    Bs[lk + 2][lrow] = bv.z; Bs[lk + 3][lrow] = bv.w;
    __syncthreads();
#pragma unroll
    for (int kk = 0; kk < 16; kk++) {
      float4 a4 = *(const float4*)&As[kk][ty * 4];
      float4 b4 = *(const float4*)&Bs[kk][tx * 4];
      float a_[4] = {a4.x, a4.y, a4.z, a4.w};
      float b_[4] = {b4.x, b4.y, b4.z, b4.w};
#pragma unroll
      for (int i = 0; i < 4; i++)
#pragma unroll
        for (int j = 0; j < 4; j++) acc[i][j] += a_[i] * b_[j];
    }
  }
#pragma unroll
  for (int i = 0; i < 4; i++) {
    float4 o; o.x = acc[i][0]; o.y = acc[i][1]; o.z = acc[i][2]; o.w = acc[i][3];
    *(float4*)(C + (size_t)(m0 + ty * 4 + i) * N + n0 + tx * 4) = o;
  }
}

// ---------------------------------------------------------------------------
// pack_all: pack_q (blocks 0..255), pack_k (256..383), W1/W2 frags (384..391).
// QQ4[b][h][q][r]: q=0 hi(d0..7) q=1 hi(d8..15) q=2 lo(d0..7) q=3 lo(d8..15)
// KH4[b][h][qq][c] hi pairs; KL4z[b][h][q][c]: q<2 lo pairs, q>=2 zeros.
// W1B*: [16 Mtiles][64 lanes] uint4 (operand layout; serves as MFMA A here).
// W2F*: [16 chunks][64 lanes] uint2 = f16x4, W2[h=cl][j=nt*16+4q+i], hi/lo.
// ---------------------------------------------------------------------------
__global__ void __launch_bounds__(256)
pack_all(const float* __restrict__ qv, const float* __restrict__ kv,
         const float* __restrict__ W1, const float* __restrict__ W2,
         uint4* __restrict__ QQ4, uint4* __restrict__ KH4, uint4* __restrict__ KL4z,
         uint4* __restrict__ W1Bhi, uint4* __restrict__ W1Blo,
         uint2* __restrict__ W2Fhi, uint2* __restrict__ W2Flo) {
  int blk = blockIdx.x;
  if (blk < 256) {
    int tid = blk * 256 + threadIdx.x;       // ((b*512+r)*16+h)*4+q
    int q = tid & 3, h = (tid >> 2) & 15, r = (tid >> 6) & 511, b = tid >> 15;
    const float* src = qv + ((size_t)(b * 512 + r) << 9) + h * 16 + (q & 1) * 8;
    bool lo = q >= 2;
    u32 w[4];
#pragma unroll
    for (int t = 0; t < 4; t++) {
      float a = src[2 * t] * 0.25f, bb = src[2 * t + 1] * 0.25f;
      if (lo) { a -= b2f(f2b(a)); bb -= b2f(f2b(bb)); }
      w[t] = (u32)f2b(a) | ((u32)f2b(bb) << 16);
    }
    QQ4[((size_t)((b * 16 + h) * 4 + q) << 9) + r] = make_uint4(w[0], w[1], w[2], w[3]);
  } else if (blk < 384) {
    int tid = (blk - 256) * 256 + threadIdx.x;  // ((b*512+c)*16+h)*2+qq
    int qq = tid & 1, h = (tid >> 1) & 15, c = (tid >> 5) & 511, b = tid >> 14;
    const float* src = kv + ((size_t)(b * 512 + c) << 9) + h * 16 + qq * 8;
    u32 hw[4], lw[4];
#pragma unroll
    for (int t = 0; t < 4; t++) {
      float a = src[2 * t], bb = src[2 * t + 1];
      u16 ha = f2b(a), hb = f2b(bb);
      hw[t] = (u32)ha | ((u32)hb << 16);
      lw[t] = (u32)f2b(a - b2f(ha)) | ((u32)f2b(bb - b2f(hb)) << 16);
    }
    KH4[((size_t)((b * 16 + h) * 2 + qq) << 9) + c] = make_uint4(hw[0], hw[1], hw[2], hw[3]);
    KL4z[((size_t)((b * 16 + h) * 4 + qq) << 9) + c] = make_uint4(lw[0], lw[1], lw[2], lw[3]);
    KL4z[((size_t)((b * 16 + h) * 4 + 2 + qq) << 9) + c] = make_uint4(0, 0, 0, 0);
  } else {
    int tid = (blk - 384) * 256 + threadIdx.x;   // 0..2047
    if (tid < 1024) {
      int L = tid & 63;
      int j = (tid >> 6) * 16 + (L & 15), q = L >> 4;
      u32 hw[4] = {0,0,0,0}, lw[4] = {0,0,0,0};
#pragma unroll
      for (int jj = 0; jj < 8; jj++) {
        float wv = W1[j * 32 + q * 8 + jj];
        u16 hb = f2b(wv); u16 lb = f2b(wv - b2f(hb));
        hw[jj >> 1] |= ((u32)hb) << (16 * (jj & 1));
        lw[jj >> 1] |= ((u32)lb) << (16 * (jj & 1));
      }
      W1Bhi[tid] = make_uint4(hw[0], hw[1], hw[2], hw[3]);
      W1Blo[tid] = make_uint4(lw[0], lw[1], lw[2], lw[3]);
    } else {
      int t2 = tid - 1024;                       // nt*64 + L
      int L = t2 & 63, nt = t2 >> 6;
      int h = L & 15, q = L >> 4;
      F16x4 hi, lo;
#pragma unroll
      for (int i = 0; i < 4; i++) {
        int j = nt * 16 + 4 * q + i;
        float wv = W2[h * 256 + j];
        hi.h[i] = (_Float16)wv;
        lo.h[i] = (_Float16)(wv - (float)hi.h[i]);
      }
      W2Fhi[t2] = hi.u;
      W2Flo[t2] = lo.u;
    }
  }
}

// ---------------------------------------------------------------------------
// ms_mfma5: all-MFMA fused QK^T + MixedScoreFF with NO layer-1/2 LDS
// round-trip.  Layer1 computes H^T directly (A=W1, B=X -> D[j][cell]);
// lane then relu+cvt-f16 its 4 H values, which are exactly the A-operand of
// the K=16 f16 MFMA for layer2 (A=H[m=cell][k=j], B=W2^T[k=j][n=h]) -> acc2
// lands in the SAME layout/epilogue as before.  Wave-tile 16r x 16c.
// ---------------------------------------------------------------------------
__global__ void __launch_bounds__(256, 2)
ms_mfma5(const uint4* __restrict__ QQ4, const uint4* __restrict__ KH4,
         const uint4* __restrict__ KL4z, const float* __restrict__ cost,
         const uint4* __restrict__ W1Bhi, const uint4* __restrict__ W1Blo,
         const uint2* __restrict__ W2Fhi, const uint2* __restrict__ W2Flo,
         u16* __restrict__ ms1, u16* __restrict__ ms2) {
  __shared__ __align__(16) u32 Dl[4 * 4160];
  int t = threadIdx.x, L = t & 63, w = t >> 6;
  int cl = L & 15, q = L >> 4;
  int b = blockIdx.z, c0 = blockIdx.x * 16, r0 = (blockIdx.y * 4 + w) * 16;
  u32* D = Dl + w * 4160;

  f32x4 z; z[0] = 0.f; z[1] = 0.f; z[2] = 0.f; z[3] = 0.f;

  // ---- phase A: QK^T (scaled) via MFMA, 16 heads -> D[h][r][c] in LDS ----
  for (int h = 0; h < 16; h++) {
    uint4 qa  = QQ4[((size_t)((b * 16 + h) * 4 + q) << 9) + r0 + cl];       // [qh|ql]
    uint4 qa2 = QQ4[((size_t)((b * 16 + h) * 4 + (q & 1)) << 9) + r0 + cl]; // [qh|qh]
    uint4 kb1 = KH4[((size_t)((b * 16 + h) * 2 + (q & 1)) << 9) + c0 + cl]; // [kh|kh]
    uint4 kb2 = KL4z[((size_t)((b * 16 + h) * 4 + q) << 9) + c0 + cl];      // [kl|0]
    f32x4 d = mfma16(qa, kb1, z);
    d = mfma16(qa2, kb2, d);
#pragma unroll
    for (int i = 0; i < 4; i++)
      D[h * 260 + (q * 4 + i) * 16 + cl] = __float_as_uint(d[i]);
  }

  // ---- phase A2: build X fragments (B-operand: n=cell=cl, k=8q+idx) ----
  uint4 xhi[16], xlo[16];
#pragma unroll
  for (int r = 0; r < 16; r++) {
    float cvm = cost[((size_t)(b * 512) + r0 + r) * 512 + c0 + cl];
    u32 cp = pk2(cvm, cvm);
    float cres = cvm - __uint_as_float(cp & 0xffff0000u);
    u32 hw[4], lw[4];
#pragma unroll
    for (int tt = 0; tt < 4; tt++) {
      float dd = __uint_as_float(D[(4 * q + tt) * 260 + r * 16 + cl]);
      u32 hp = pk2(dd, cvm);
      float dres = dd - __uint_as_float(hp << 16);
      hw[tt] = hp;
      lw[tt] = pk2(dres, cres);
    }
    xhi[r] = make_uint4(hw[0], hw[1], hw[2], hw[3]);
    xlo[r] = make_uint4(lw[0], lw[1], lw[2], lw[3]);
  }

  // ---- phase B: nt-outer MLP; layer1 -> H^T in regs -> f16 -> layer2 ----
  f32x4 acc2[16];
#pragma unroll
  for (int r = 0; r < 16; r++) acc2[r] = z;

#pragma unroll 1
  for (int nt = 0; nt < 16; nt++) {
    uint4 w1h = W1Bhi[nt * 64 + L];
    uint4 w1l = W1Blo[nt * 64 + L];
    F16x4 w2h, w2l;
    w2h.u = W2Fhi[nt * 64 + L];
    w2l.u = W2Flo[nt * 64 + L];
#pragma unroll
    for (int r = 0; r < 16; r++) {
      f32x4 a0 = z;
      a0 = mfma16(w1h, xhi[r], a0);   // W1hi . Xhi
      a0 = mfma16(w1h, xlo[r], a0);   // W1hi . Xlo
      a0 = mfma16(w1l, xhi[r], a0);   // W1lo . Xhi
      F16x4 hf;
      hf.h[0] = (_Float16)fmaxf(a0[0], 0.f);
      hf.h[1] = (_Float16)fmaxf(a0[1], 0.f);
      hf.h[2] = (_Float16)fmaxf(a0[2], 0.f);
      hf.h[3] = (_Float16)fmaxf(a0[3], 0.f);
      acc2[r] = mfma_h16(hf.v, w2h.v, acc2[r]);
      acc2[r] = mfma_h16(hf.v, w2l.v, acc2[r]);
    }
  }

  // ---- epilogue: lane (q,cl) holds MS[h=cl][c=c0+4q+i][r0..r0+15] ----
  u32* ms1u = (u32*)ms1;
#pragma unroll
  for (int r = 0; r < 16; r++) {
    size_t base = ((size_t)(b * 16 + cl) * 512 + (r0 + r)) * 256 + (c0 >> 1) + q * 2;
    ms1u[base]     = pk2(acc2[r][0], acc2[r][1]);
    ms1u[base + 1] = pk2(acc2[r][2], acc2[r][3]);
  }
  u32* ms2u = (u32*)ms2;
#pragma unroll
  for (int i = 0; i < 4; i++) {
    int c = c0 + 4 * q + i;
    u32 o[8];
#pragma unroll
    for (int rr = 0; rr < 8; rr++)
      o[rr] = pk2(acc2[2 * rr][i], acc2[2 * rr + 1][i]);
    size_t base2 = ((size_t)(b * 16 + cl) * 512 + c) * 256 + (r0 >> 1);
    *(uint4*)&ms2u[base2]     = make_uint4(o[0], o[1], o[2], o[3]);
    *(uint4*)&ms2u[base2 + 4] = make_uint4(o[4], o[5], o[6], o[7]);
  }
}

// ---------------------------------------------------------------------------
// softmax_all: both directions in one launch (dir = blockIdx.z).
// Block (256 thr) per (b, 2 fix rows).  dir0: ms1, mask rows, V=kv -> o1.
// dir1: ms2, mask columns (direct strided reads), V=qv -> o2.
// ---------------------------------------------------------------------------
__global__ void __launch_bounds__(256)
softmax_all(const u16* __restrict__ ms1s, const u16* __restrict__ ms2s,
            const int* __restrict__ mask,
            const float* __restrict__ qv, const float* __restrict__ kv,
            float* __restrict__ o1, float* __restrict__ o2) {
  __shared__ float  pbuf[2][8224];          // 16*514 per fix
  __shared__ float  sden[2][16];
  __shared__ float4 red[2][4][64];
  int t = threadIdx.x, lane = t & 63, w = t >> 6;
  int fix0 = blockIdx.x * 2, b = blockIdx.y, dir = blockIdx.z;
  const u16*   ms   = dir ? ms2s : ms1s;
  const float* vbuf = dir ? qv : kv;
  float*       obuf = dir ? o2 : o1;

#pragma unroll
  for (int f = 0; f < 2; f++) {
    int fix = fix0 + f;
    bool vd[8];
#pragma unroll
    for (int i = 0; i < 8; i++) {
      int cc = i * 64 + lane;
      int mv = dir ? mask[((size_t)b * 512 + cc) * 512 + fix]
                   : mask[((size_t)b * 512 + fix) * 512 + cc];
      vd[i] = mv != 0;
    }
    bool anyl = false;
#pragma unroll
    for (int i = 0; i < 8; i++) anyl |= vd[i];
    bool useMask = (__ballot(anyl) != 0ULL);   // fully-masked row => unmask all

#pragma unroll
    for (int hh = 0; hh < 4; hh++) {
      int h = w * 4 + hh;
      const u16* mrow = ms + ((size_t)(b * 16 + h) * 512 + fix) * 512;
      float lg[8];
#pragma unroll
      for (int i = 0; i < 8; i++) lg[i] = b2f(mrow[i * 64 + lane]);
      float mx = -3.4e38f;
#pragma unroll
      for (int i = 0; i < 8; i++)
        if (!(useMask && !vd[i])) mx = fmaxf(mx, lg[i]);
      for (int off = 32; off; off >>= 1) mx = fmaxf(mx, __shfl_xor(mx, off));
      float s = 0.f;
#pragma unroll
      for (int i = 0; i < 8; i++) {
        float p = (useMask && !vd[i]) ? 0.f : __expf(lg[i] - mx);
        pbuf[f][h * 514 + i * 64 + lane] = p;
        s += p;
      }
      for (int off = 32; off; off >>= 1) s += __shfl_xor(s, off);
      if (lane == 0) sden[f][h] = s;
    }
  }
  __syncthreads();

  // phase B: thread (w, h=lane>>2, dq=lane&3) accumulates cc = 4*it + w
  int hb = lane >> 2, dq = lane & 3;
  const float* vb = vbuf + (size_t)b * 262144 + 256 + hb * 16 + dq * 4;
  float4 a0 = make_float4(0.f, 0.f, 0.f, 0.f);
  float4 a1 = make_float4(0.f, 0.f, 0.f, 0.f);
  for (int it = 0; it < 128; it++) {
    int cc = it * 4 + w;
    float4 v = *(const float4*)(vb + (size_t)cc * 512);
    float p0 = pbuf[0][hb * 514 + cc];
    float p1 = pbuf[1][hb * 514 + cc];
    a0.x += p0 * v.x; a0.y += p0 * v.y; a0.z += p0 * v.z; a0.w += p0 * v.w;
    a1.x += p1 * v.x; a1.y += p1 * v.y; a1.z += p1 * v.z; a1.w += p1 * v.w;
  }
  red[0][w][lane] = a0;
  red[1][w][lane] = a1;
  __syncthreads();
  if (w < 2) {
    float4 s0 = red[w][0][lane], s1 = red[w][1][lane];
    float4 s2 = red[w][2][lane], s3 = red[w][3][lane];
    float inv = 1.f / sden[w][hb];
    float4 o;
    o.x = (s0.x + s1.x + s2.x + s3.x) * inv;
    o.y = (s0.y + s1.y + s2.y + s3.y) * inv;
    o.z = (s0.z + s1.z + s2.z + s3.z) * inv;
    o.w = (s0.w + s1.w + s2.w + s3.w) * inv;
    *(float4*)(obuf + ((size_t)b * 512 + fix0 + w) * 256 + lane * 4) = o;
  }
}

// ---------------------------------------------------------------------------
extern "C" void kernel_launch(void* const* d_in, const int* in_sizes, int n_in,
                              void* d_out, int out_size, void* d_ws, size_t ws_size,
                              hipStream_t stream) {
  const float* x1    = (const float*)d_in[0];
  const float* x2    = (const float*)d_in[1];
  const int*   attn  = (const int*)d_in[2];
  const float* cost  = (const float*)d_in[3];
  const float* Wqv1  = (const float*)d_in[4];
  const float* Wkv2  = (const float*)d_in[5];
  const float* W1    = (const float*)d_in[6];
  const float* W2    = (const float*)d_in[7];
  const float* Wout1 = (const float*)d_in[8];
  const float* Wout2 = (const float*)d_in[9];
  float* out = (float*)d_out;

  char* ws = (char*)d_ws;
  uint4* W1Bhi = (uint4*)(ws);                               // 16 KB
  uint4* W1Blo = (uint4*)(ws + (16 << 10));                  // 16 KB
  uint2* W2Fhi = (uint2*)(ws + (32 << 10));                  //  8 KB
  uint2* W2Flo = (uint2*)(ws + (40 << 10));                  //  8 KB
  float* qv  = (float*)(ws + (64 << 10));                    //   2 MB [b][r][512]
  float* kv  = (float*)(ws + (64 << 10) + (2 << 20));        //   2 MB [b][c][512]
  u16*   ms1 = (u16*)  (ws + (64 << 10) + (4 << 20));        //  16 MB [b][h][r][c]
  u16*   ms2 = (u16*)  (ws + (64 << 10) + (20 << 20));       //  16 MB [b][h][c][r]
  char*  tail= (ws + (64 << 10) + (36 << 20));
  // Q/K fragment buffers (dead after ms_mfma5) overlap o1/o2's region head.
  uint4* QQ4  = (uint4*)(tail);                              //   1 MB
  uint4* KH4  = (uint4*)(tail + (1 << 20));                  // 0.5 MB
  uint4* KL4z = (uint4*)(tail + (1 << 20) + (512 << 10));    //   1 MB
  float* o1  = (float*)(tail + (2 << 20));                   //   1 MB [b][r][256] (after ms_mfma5)
  float* o2  = (float*)(tail + (3 << 20));                   //   1 MB [b][c][256]

  gemm2<<<dim3(8, 32), 256, 0, stream>>>(x1, Wqv1, qv, x2, Wkv2, kv, 512, 256);

  pack_all<<<392, 256, 0, stream>>>(qv, kv, W1, W2, QQ4, KH4, KL4z,
                                    W1Bhi, W1Blo, W2Fhi, W2Flo);

  ms_mfma5<<<dim3(32, 8, 2), 256, 0, stream>>>(QQ4, KH4, KL4z, cost,
                                               W1Bhi, W1Blo, W2Fhi, W2Flo, ms1, ms2);

  softmax_all<<<dim3(256, 2, 2), 256, 0, stream>>>(ms1, ms2, attn, qv, kv, o1, o2);

  gemm2<<<dim3(4, 32), 256, 0, stream>>>(o1, Wout1, out, o2, Wout2, out + (size_t)262144, 256, 256);
}

// Round 9
// 178.725 us; speedup vs baseline: 3.1517x; 1.0487x over previous
//
#include <hip/hip_runtime.h>
#include <hip/hip_bf16.h>

typedef unsigned int   u32;
typedef unsigned short u16;

typedef __attribute__((ext_vector_type(8))) short    sh8;
typedef __attribute__((ext_vector_type(4))) float    f32x4;
typedef __attribute__((ext_vector_type(4))) _Float16 f16x4;

union F16x4 { f16x4 v; uint2 u; _Float16 h[4]; };

__device__ __forceinline__ float b2f(u16 u) { union { u32 i; float f; } v; v.i = ((u32)u) << 16; return v.f; }
__device__ __forceinline__ u16   f2b(float f){
  union { float f; u32 i; } v; v.f = f;
  u32 u = v.i;
  u32 r = (u + 0x7fffu + ((u >> 16) & 1u)) >> 16;   // RNE
  return (u16)r;
}
// pack two f32 -> bf16x2 (RNE), lo half = a, hi half = b
__device__ __forceinline__ u32 pk2(float a, float b) {
  __hip_bfloat162 h2 = __float22bfloat162_rn(make_float2(a, b));
  union { __hip_bfloat162 h; u32 u; } v; v.h = h2; return v.u;
}

__device__ __forceinline__ f32x4 mfma16(uint4 a, uint4 b, f32x4 c) {
  union { uint4 u; sh8 s; } ua, ub;
  ua.u = a; ub.u = b;
  return __builtin_amdgcn_mfma_f32_16x16x32_bf16(ua.s, ub.s, c, 0, 0, 0);
}
__device__ __forceinline__ f32x4 mfma_h16(f16x4 a, f16x4 b, f32x4 c) {
  return __builtin_amdgcn_mfma_f32_16x16x16f16(a, b, c, 0, 0, 0);
}

// split 8 consecutive f32 (one lane's K-chunk) into bf16 hi/lo A/B-operand words
__device__ __forceinline__ void split8(float4 v0, float4 v1, uint4& hi, uint4& lo) {
  float a[8] = {v0.x, v0.y, v0.z, v0.w, v1.x, v1.y, v1.z, v1.w};
  u32 hw[4], lw[4];
#pragma unroll
  for (int t = 0; t < 4; t++) {
    u32 hp = pk2(a[2 * t], a[2 * t + 1]);
    float r0 = a[2 * t]     - __uint_as_float(hp << 16);
    float r1 = a[2 * t + 1] - __uint_as_float(hp & 0xffff0000u);
    hw[t] = hp;
    lw[t] = pk2(r0, r1);
  }
  hi = make_uint4(hw[0], hw[1], hw[2], hw[3]);
  lo = make_uint4(lw[0], lw[1], lw[2], lw[3]);
}

// ---------------------------------------------------------------------------
// gemm_mf: two independent C = A @ B^T f32 GEMMs via MFMA (sel = by>>4).
// One wave per 16x16 C tile; on-the-fly bf16 hi/lo split (3 MFMAs / K32).
// M = 1024 per matrix; K multiple of 32.
// ---------------------------------------------------------------------------
__global__ void __launch_bounds__(256)
gemm_mf(const float* __restrict__ A0, const float* __restrict__ B0, float* __restrict__ C0,
        const float* __restrict__ A1, const float* __restrict__ B1, float* __restrict__ C1,
        int N, int K) {
  int t = threadIdx.x, L = t & 63, w = t >> 6;
  int cl = L & 15, q = L >> 4;
  int by = blockIdx.y, sel = by >> 4;
  const float* A  = sel ? A1 : A0;
  const float* Bw = sel ? B1 : B0;
  float*       C  = sel ? C1 : C0;
  int m0 = (by & 15) * 64 + w * 16;
  int n0 = blockIdx.x * 16;

  f32x4 acc; acc[0] = 0.f; acc[1] = 0.f; acc[2] = 0.f; acc[3] = 0.f;
  const float* ar = A  + (size_t)(m0 + cl) * K + 8 * q;
  const float* br = Bw + (size_t)(n0 + cl) * K + 8 * q;

  for (int k0 = 0; k0 < K; k0 += 32) {
    float4 av0 = *(const float4*)(ar + k0);
    float4 av1 = *(const float4*)(ar + k0 + 4);
    float4 bv0 = *(const float4*)(br + k0);
    float4 bv1 = *(const float4*)(br + k0 + 4);
    uint4 ahi, alo, bhi, blo;
    split8(av0, av1, ahi, alo);
    split8(bv0, bv1, bhi, blo);
    acc = mfma16(ahi, bhi, acc);
    acc = mfma16(ahi, blo, acc);
    acc = mfma16(alo, bhi, acc);
  }
#pragma unroll
  for (int i = 0; i < 4; i++)
    C[(size_t)(m0 + 4 * q + i) * N + n0 + cl] = acc[i];
}

// ---------------------------------------------------------------------------
// pack_all: pack_q (blocks 0..255), pack_k (256..383), W1/W2 frags (384..391).
// QQ4[b][h][q][r]: q=0 hi(d0..7) q=1 hi(d8..15) q=2 lo(d0..7) q=3 lo(d8..15)
// KH4[b][h][qq][c] hi pairs; KL4z[b][h][q][c]: q<2 lo pairs, q>=2 zeros.
// W1B*: [16 Mtiles][64 lanes] uint4 (MFMA A-operand layout).
// W2F*: [16 chunks][64 lanes] uint2 = f16x4, W2[h=cl][j=nt*16+4q+i], hi/lo.
// ---------------------------------------------------------------------------
__global__ void __launch_bounds__(256)
pack_all(const float* __restrict__ qv, const float* __restrict__ kv,
         const float* __restrict__ W1, const float* __restrict__ W2,
         uint4* __restrict__ QQ4, uint4* __restrict__ KH4, uint4* __restrict__ KL4z,
         uint4* __restrict__ W1Bhi, uint4* __restrict__ W1Blo,
         uint2* __restrict__ W2Fhi, uint2* __restrict__ W2Flo) {
  int blk = blockIdx.x;
  if (blk < 256) {
    int tid = blk * 256 + threadIdx.x;       // ((b*512+r)*16+h)*4+q
    int q = tid & 3, h = (tid >> 2) & 15, r = (tid >> 6) & 511, b = tid >> 15;
    const float* src = qv + ((size_t)(b * 512 + r) << 9) + h * 16 + (q & 1) * 8;
    bool lo = q >= 2;
    u32 w[4];
#pragma unroll
    for (int t = 0; t < 4; t++) {
      float a = src[2 * t] * 0.25f, bb = src[2 * t + 1] * 0.25f;
      if (lo) { a -= b2f(f2b(a)); bb -= b2f(f2b(bb)); }
      w[t] = (u32)f2b(a) | ((u32)f2b(bb) << 16);
    }
    QQ4[((size_t)((b * 16 + h) * 4 + q) << 9) + r] = make_uint4(w[0], w[1], w[2], w[3]);
  } else if (blk < 384) {
    int tid = (blk - 256) * 256 + threadIdx.x;  // ((b*512+c)*16+h)*2+qq
    int qq = tid & 1, h = (tid >> 1) & 15, c = (tid >> 5) & 511, b = tid >> 14;
    const float* src = kv + ((size_t)(b * 512 + c) << 9) + h * 16 + qq * 8;
    u32 hw[4], lw[4];
#pragma unroll
    for (int t = 0; t < 4; t++) {
      float a = src[2 * t], bb = src[2 * t + 1];
      u16 ha = f2b(a), hb = f2b(bb);
      hw[t] = (u32)ha | ((u32)hb << 16);
      lw[t] = (u32)f2b(a - b2f(ha)) | ((u32)f2b(bb - b2f(hb)) << 16);
    }
    KH4[((size_t)((b * 16 + h) * 2 + qq) << 9) + c] = make_uint4(hw[0], hw[1], hw[2], hw[3]);
    KL4z[((size_t)((b * 16 + h) * 4 + qq) << 9) + c] = make_uint4(lw[0], lw[1], lw[2], lw[3]);
    KL4z[((size_t)((b * 16 + h) * 4 + 2 + qq) << 9) + c] = make_uint4(0, 0, 0, 0);
  } else {
    int tid = (blk - 384) * 256 + threadIdx.x;   // 0..2047
    if (tid < 1024) {
      int L = tid & 63;
      int j = (tid >> 6) * 16 + (L & 15), q = L >> 4;
      u32 hw[4] = {0,0,0,0}, lw[4] = {0,0,0,0};
#pragma unroll
      for (int jj = 0; jj < 8; jj++) {
        float wv = W1[j * 32 + q * 8 + jj];
        u16 hb = f2b(wv); u16 lb = f2b(wv - b2f(hb));
        hw[jj >> 1] |= ((u32)hb) << (16 * (jj & 1));
        lw[jj >> 1] |= ((u32)lb) << (16 * (jj & 1));
      }
      W1Bhi[tid] = make_uint4(hw[0], hw[1], hw[2], hw[3]);
      W1Blo[tid] = make_uint4(lw[0], lw[1], lw[2], lw[3]);
    } else {
      int t2 = tid - 1024;                       // nt*64 + L
      int L = t2 & 63, nt = t2 >> 6;
      int h = L & 15, q = L >> 4;
      F16x4 hi, lo;
#pragma unroll
      for (int i = 0; i < 4; i++) {
        int j = nt * 16 + 4 * q + i;
        float wv = W2[h * 256 + j];
        hi.h[i] = (_Float16)wv;
        lo.h[i] = (_Float16)(wv - (float)hi.h[i]);
      }
      W2Fhi[t2] = hi.u;
      W2Flo[t2] = lo.u;
    }
  }
}

// ---------------------------------------------------------------------------
// ms_mfma5: all-MFMA fused QK^T + MixedScoreFF (layer1 emits H^T directly;
// relu+f16 cvt in regs; layer2 = 2 K=16 f16 MFMAs).  Wave-tile 16r x 16c.
// ---------------------------------------------------------------------------
__global__ void __launch_bounds__(256, 2)
ms_mfma5(const uint4* __restrict__ QQ4, const uint4* __restrict__ KH4,
         const uint4* __restrict__ KL4z, const float* __restrict__ cost,
         const uint4* __restrict__ W1Bhi, const uint4* __restrict__ W1Blo,
         const uint2* __restrict__ W2Fhi, const uint2* __restrict__ W2Flo,
         u16* __restrict__ ms1, u16* __restrict__ ms2) {
  __shared__ __align__(16) u32 Dl[4 * 4160];
  int t = threadIdx.x, L = t & 63, w = t >> 6;
  int cl = L & 15, q = L >> 4;
  int b = blockIdx.z, c0 = blockIdx.x * 16, r0 = (blockIdx.y * 4 + w) * 16;
  u32* D = Dl + w * 4160;

  f32x4 z; z[0] = 0.f; z[1] = 0.f; z[2] = 0.f; z[3] = 0.f;

  // ---- phase A: QK^T (scaled) via MFMA, 16 heads -> D[h][r][c] in LDS ----
  for (int h = 0; h < 16; h++) {
    uint4 qa  = QQ4[((size_t)((b * 16 + h) * 4 + q) << 9) + r0 + cl];       // [qh|ql]
    uint4 qa2 = QQ4[((size_t)((b * 16 + h) * 4 + (q & 1)) << 9) + r0 + cl]; // [qh|qh]
    uint4 kb1 = KH4[((size_t)((b * 16 + h) * 2 + (q & 1)) << 9) + c0 + cl]; // [kh|kh]
    uint4 kb2 = KL4z[((size_t)((b * 16 + h) * 4 + q) << 9) + c0 + cl];      // [kl|0]
    f32x4 d = mfma16(qa, kb1, z);
    d = mfma16(qa2, kb2, d);
#pragma unroll
    for (int i = 0; i < 4; i++)
      D[h * 260 + (q * 4 + i) * 16 + cl] = __float_as_uint(d[i]);
  }

  // ---- phase A2: build X fragments (B-operand: n=cell=cl, k=8q+idx) ----
  uint4 xhi[16], xlo[16];
#pragma unroll
  for (int r = 0; r < 16; r++) {
    float cvm = cost[((size_t)(b * 512) + r0 + r) * 512 + c0 + cl];
    u32 cp = pk2(cvm, cvm);
    float cres = cvm - __uint_as_float(cp & 0xffff0000u);
    u32 hw[4], lw[4];
#pragma unroll
    for (int tt = 0; tt < 4; tt++) {
      float dd = __uint_as_float(D[(4 * q + tt) * 260 + r * 16 + cl]);
      u32 hp = pk2(dd, cvm);
      float dres = dd - __uint_as_float(hp << 16);
      hw[tt] = hp;
      lw[tt] = pk2(dres, cres);
    }
    xhi[r] = make_uint4(hw[0], hw[1], hw[2], hw[3]);
    xlo[r] = make_uint4(lw[0], lw[1], lw[2], lw[3]);
  }

  // ---- phase B: nt-outer MLP; layer1 -> H^T in regs -> f16 -> layer2 ----
  f32x4 acc2[16];
#pragma unroll
  for (int r = 0; r < 16; r++) acc2[r] = z;

#pragma unroll 1
  for (int nt = 0; nt < 16; nt++) {
    uint4 w1h = W1Bhi[nt * 64 + L];
    uint4 w1l = W1Blo[nt * 64 + L];
    F16x4 w2h, w2l;
    w2h.u = W2Fhi[nt * 64 + L];
    w2l.u = W2Flo[nt * 64 + L];
#pragma unroll
    for (int r = 0; r < 16; r++) {
      f32x4 a0 = z;
      a0 = mfma16(w1h, xhi[r], a0);   // W1hi . Xhi
      a0 = mfma16(w1h, xlo[r], a0);   // W1hi . Xlo
      a0 = mfma16(w1l, xhi[r], a0);   // W1lo . Xhi
      F16x4 hf;
      hf.h[0] = (_Float16)fmaxf(a0[0], 0.f);
      hf.h[1] = (_Float16)fmaxf(a0[1], 0.f);
      hf.h[2] = (_Float16)fmaxf(a0[2], 0.f);
      hf.h[3] = (_Float16)fmaxf(a0[3], 0.f);
      acc2[r] = mfma_h16(hf.v, w2h.v, acc2[r]);
      acc2[r] = mfma_h16(hf.v, w2l.v, acc2[r]);
    }
  }

  // ---- epilogue: lane (q,cl) holds MS[h=cl][c=c0+4q+i][r0..r0+15] ----
  u32* ms1u = (u32*)ms1;
#pragma unroll
  for (int r = 0; r < 16; r++) {
    size_t base = ((size_t)(b * 16 + cl) * 512 + (r0 + r)) * 256 + (c0 >> 1) + q * 2;
    ms1u[base]     = pk2(acc2[r][0], acc2[r][1]);
    ms1u[base + 1] = pk2(acc2[r][2], acc2[r][3]);
  }
  u32* ms2u = (u32*)ms2;
#pragma unroll
  for (int i = 0; i < 4; i++) {
    int c = c0 + 4 * q + i;
    u32 o[8];
#pragma unroll
    for (int rr = 0; rr < 8; rr++)
      o[rr] = pk2(acc2[2 * rr][i], acc2[2 * rr + 1][i]);
    size_t base2 = ((size_t)(b * 16 + cl) * 512 + c) * 256 + (r0 >> 1);
    *(uint4*)&ms2u[base2]     = make_uint4(o[0], o[1], o[2], o[3]);
    *(uint4*)&ms2u[base2 + 4] = make_uint4(o[4], o[5], o[6], o[7]);
  }
}

// ---------------------------------------------------------------------------
// softmax_all4: both directions (dir = blockIdx.z); block = (b, 4 fix rows).
// Phase A: wave w owns fix0+w -> masked softmax of 16 heads, p stored f16 in
// LDS (h-stride 522: odd dword stride -> conflict-free broadcast reads).
// Phase B: each V float4 load feeds 4 fix rows; cross-wave reduce per fix.
// ---------------------------------------------------------------------------
__global__ void __launch_bounds__(256)
softmax_all4(const u16* __restrict__ ms1s, const u16* __restrict__ ms2s,
             const int* __restrict__ mask,
             const float* __restrict__ qv, const float* __restrict__ kv,
             float* __restrict__ o1, float* __restrict__ o2) {
  __shared__ _Float16 pbuf[4][16][522];
  __shared__ float    sden[4][16];
  __shared__ float4   red[4][64];
  int t = threadIdx.x, lane = t & 63, w = t >> 6;
  int fix0 = blockIdx.x * 4, b = blockIdx.y, dir = blockIdx.z;
  const u16*   ms   = dir ? ms2s : ms1s;
  const float* vbuf = dir ? qv : kv;
  float*       obuf = dir ? o2 : o1;

  // ---- phase A: wave w handles fix = fix0 + w ----
  int fix = fix0 + w;
  bool vd[8];
#pragma unroll
  for (int i = 0; i < 8; i++) {
    int cc = i * 64 + lane;
    int mv = dir ? mask[((size_t)b * 512 + cc) * 512 + fix]
                 : mask[((size_t)b * 512 + fix) * 512 + cc];
    vd[i] = mv != 0;
  }
  bool anyl = false;
#pragma unroll
  for (int i = 0; i < 8; i++) anyl |= vd[i];
  bool useMask = (__ballot(anyl) != 0ULL);   // fully-masked row => unmask all

#pragma unroll 1
  for (int h = 0; h < 16; h++) {
    const u16* mrow = ms + ((size_t)(b * 16 + h) * 512 + fix) * 512;
    float lg[8];
#pragma unroll
    for (int i = 0; i < 8; i++) lg[i] = b2f(mrow[i * 64 + lane]);
    float mx = -3.4e38f;
#pragma unroll
    for (int i = 0; i < 8; i++)
      if (!(useMask && !vd[i])) mx = fmaxf(mx, lg[i]);
    for (int off = 32; off; off >>= 1) mx = fmaxf(mx, __shfl_xor(mx, off));
    float s = 0.f;
#pragma unroll
    for (int i = 0; i < 8; i++) {
      float p = (useMask && !vd[i]) ? 0.f : __expf(lg[i] - mx);
      pbuf[w][h][i * 64 + lane] = (_Float16)p;
      s += p;
    }
    for (int off = 32; off; off >>= 1) s += __shfl_xor(s, off);
    if (lane == 0) sden[w][h] = s;
  }
  __syncthreads();

  // ---- phase B: thread (w, hb=lane>>2, dq=lane&3) accumulates cc = 4*it+w ----
  int hb = lane >> 2, dq = lane & 3;
  const float* vb = vbuf + (size_t)b * 262144 + 256 + hb * 16 + dq * 4;
  float4 acc[4];
#pragma unroll
  for (int f = 0; f < 4; f++) acc[f] = make_float4(0.f, 0.f, 0.f, 0.f);
  for (int it = 0; it < 128; it++) {
    int cc = it * 4 + w;
    float4 v = *(const float4*)(vb + (size_t)cc * 512);
#pragma unroll
    for (int f = 0; f < 4; f++) {
      float p = (float)pbuf[f][hb][cc];
      acc[f].x += p * v.x; acc[f].y += p * v.y;
      acc[f].z += p * v.z; acc[f].w += p * v.w;
    }
  }
#pragma unroll 1
  for (int f = 0; f < 4; f++) {
    red[w][lane] = acc[f];
    __syncthreads();
    if (w == 0) {
      float4 s0 = red[0][lane], s1 = red[1][lane];
      float4 s2 = red[2][lane], s3 = red[3][lane];
      float inv = 1.f / sden[f][hb];
      float4 o;
      o.x = (s0.x + s1.x + s2.x + s3.x) * inv;
      o.y = (s0.y + s1.y + s2.y + s3.y) * inv;
      o.z = (s0.z + s1.z + s2.z + s3.z) * inv;
      o.w = (s0.w + s1.w + s2.w + s3.w) * inv;
      *(float4*)(obuf + ((size_t)b * 512 + fix0 + f) * 256 + lane * 4) = o;
    }
    __syncthreads();
  }
}

// ---------------------------------------------------------------------------
extern "C" void kernel_launch(void* const* d_in, const int* in_sizes, int n_in,
                              void* d_out, int out_size, void* d_ws, size_t ws_size,
                              hipStream_t stream) {
  const float* x1    = (const float*)d_in[0];
  const float* x2    = (const float*)d_in[1];
  const int*   attn  = (const int*)d_in[2];
  const float* cost  = (const float*)d_in[3];
  const float* Wqv1  = (const float*)d_in[4];
  const float* Wkv2  = (const float*)d_in[5];
  const float* W1    = (const float*)d_in[6];
  const float* W2    = (const float*)d_in[7];
  const float* Wout1 = (const float*)d_in[8];
  const float* Wout2 = (const float*)d_in[9];
  float* out = (float*)d_out;

  char* ws = (char*)d_ws;
  uint4* W1Bhi = (uint4*)(ws);                               // 16 KB
  uint4* W1Blo = (uint4*)(ws + (16 << 10));                  // 16 KB
  uint2* W2Fhi = (uint2*)(ws + (32 << 10));                  //  8 KB
  uint2* W2Flo = (uint2*)(ws + (40 << 10));                  //  8 KB
  float* qv  = (float*)(ws + (64 << 10));                    //   2 MB [b][r][512]
  float* kv  = (float*)(ws + (64 << 10) + (2 << 20));        //   2 MB [b][c][512]
  u16*   ms1 = (u16*)  (ws + (64 << 10) + (4 << 20));        //  16 MB [b][h][r][c]
  u16*   ms2 = (u16*)  (ws + (64 << 10) + (20 << 20));       //  16 MB [b][h][c][r]
  char*  tail= (ws + (64 << 10) + (36 << 20));
  // Q/K fragment buffers (dead after ms_mfma5) overlap o1/o2's region head.
  uint4* QQ4  = (uint4*)(tail);                              //   1 MB
  uint4* KH4  = (uint4*)(tail + (1 << 20));                  // 0.5 MB
  uint4* KL4z = (uint4*)(tail + (1 << 20) + (512 << 10));    //   1 MB
  float* o1  = (float*)(tail + (3 << 20));                   //   1 MB [b][r][256] (after ms_mfma5)
  float* o2  = (float*)(tail + (4 << 20));                   //   1 MB [b][c][256]

  gemm_mf<<<dim3(32, 32), 256, 0, stream>>>(x1, Wqv1, qv, x2, Wkv2, kv, 512, 256);

  pack_all<<<392, 256, 0, stream>>>(qv, kv, W1, W2, QQ4, KH4, KL4z,
                                    W1Bhi, W1Blo, W2Fhi, W2Flo);

  ms_mfma5<<<dim3(32, 8, 2), 256, 0, stream>>>(QQ4, KH4, KL4z, cost,
                                               W1Bhi, W1Blo, W2Fhi, W2Flo, ms1, ms2);

  softmax_all4<<<dim3(128, 2, 2), 256, 0, stream>>>(ms1, ms2, attn, qv, kv, o1, o2);

  gemm_mf<<<dim3(16, 32), 256, 0, stream>>>(o1, Wout1, out, o2, Wout2, out + (size_t)262144, 256, 256);
}

// Round 11
// 178.605 us; speedup vs baseline: 3.1538x; 1.0007x over previous
//
#include <hip/hip_runtime.h>
#include <hip/hip_bf16.h>

typedef unsigned int   u32;
typedef unsigned short u16;

typedef __attribute__((ext_vector_type(8))) short    sh8;
typedef __attribute__((ext_vector_type(4))) float    f32x4;
typedef __attribute__((ext_vector_type(4))) _Float16 f16x4;
typedef __attribute__((ext_vector_type(2))) _Float16 f16x2;
typedef __attribute__((ext_vector_type(2))) __fp16   fp16x2raw;

union F16x4 { f16x4 v; uint2 u; _Float16 h[4]; f16x2 p[2]; };
union CvtU  { fp16x2raw r; f16x2 p; u32 u; };

__device__ __forceinline__ float b2f(u16 u) { union { u32 i; float f; } v; v.i = ((u32)u) << 16; return v.f; }
__device__ __forceinline__ u16   f2b(float f){
  union { float f; u32 i; } v; v.f = f;
  u32 u = v.i;
  u32 r = (u + 0x7fffu + ((u >> 16) & 1u)) >> 16;   // RNE
  return (u16)r;
}
// pack two f32 -> bf16x2 (RNE), lo half = a, hi half = b
__device__ __forceinline__ u32 pk2(float a, float b) {
  __hip_bfloat162 h2 = __float22bfloat162_rn(make_float2(a, b));
  union { __hip_bfloat162 h; u32 u; } v; v.h = h2; return v.u;
}
__device__ __forceinline__ f16x2 cvtpk(float a, float b) {
  CvtU c; c.r = __builtin_amdgcn_cvt_pkrtz(a, b); return c.p;
}

__device__ __forceinline__ f32x4 mfma16(uint4 a, uint4 b, f32x4 c) {
  union { uint4 u; sh8 s; } ua, ub;
  ua.u = a; ub.u = b;
  return __builtin_amdgcn_mfma_f32_16x16x32_bf16(ua.s, ub.s, c, 0, 0, 0);
}
__device__ __forceinline__ f32x4 mfma_h16(f16x4 a, f16x4 b, f32x4 c) {
  return __builtin_amdgcn_mfma_f32_16x16x16f16(a, b, c, 0, 0, 0);
}

// split 8 consecutive f32 (one lane's K-chunk) into bf16 hi/lo operand words
__device__ __forceinline__ void split8(float4 v0, float4 v1, uint4& hi, uint4& lo) {
  float a[8] = {v0.x, v0.y, v0.z, v0.w, v1.x, v1.y, v1.z, v1.w};
  u32 hw[4], lw[4];
#pragma unroll
  for (int t = 0; t < 4; t++) {
    u32 hp = pk2(a[2 * t], a[2 * t + 1]);
    float r0 = a[2 * t]     - __uint_as_float(hp << 16);
    float r1 = a[2 * t + 1] - __uint_as_float(hp & 0xffff0000u);
    hw[t] = hp;
    lw[t] = pk2(r0, r1);
  }
  hi = make_uint4(hw[0], hw[1], hw[2], hw[3]);
  lo = make_uint4(lw[0], lw[1], lw[2], lw[3]);
}

// ---------------------------------------------------------------------------
// gemm_mf: two independent C = A @ B^T f32 GEMMs via MFMA (sel = by>>4).
// One wave per 16x16 C tile; on-the-fly bf16 hi/lo split (3 MFMAs / K32).
// Used for the output projections (N=256, K=256).
// ---------------------------------------------------------------------------
__global__ void __launch_bounds__(256)
gemm_mf(const float* __restrict__ A0, const float* __restrict__ B0, float* __restrict__ C0,
        const float* __restrict__ A1, const float* __restrict__ B1, float* __restrict__ C1,
        int N, int K) {
  int t = threadIdx.x, L = t & 63, w = t >> 6;
  int cl = L & 15, q = L >> 4;
  int by = blockIdx.y, sel = by >> 4;
  const float* A  = sel ? A1 : A0;
  const float* Bw = sel ? B1 : B0;
  float*       C  = sel ? C1 : C0;
  int m0 = (by & 15) * 64 + w * 16;
  int n0 = blockIdx.x * 16;

  f32x4 acc; acc[0] = 0.f; acc[1] = 0.f; acc[2] = 0.f; acc[3] = 0.f;
  const float* ar = A  + (size_t)(m0 + cl) * K + 8 * q;
  const float* br = Bw + (size_t)(n0 + cl) * K + 8 * q;

  for (int k0 = 0; k0 < K; k0 += 32) {
    float4 av0 = *(const float4*)(ar + k0);
    float4 av1 = *(const float4*)(ar + k0 + 4);
    float4 bv0 = *(const float4*)(br + k0);
    float4 bv1 = *(const float4*)(br + k0 + 4);
    uint4 ahi, alo, bhi, blo;
    split8(av0, av1, ahi, alo);
    split8(bv0, bv1, bhi, blo);
    acc = mfma16(ahi, bhi, acc);
    acc = mfma16(ahi, blo, acc);
    acc = mfma16(alo, bhi, acc);
  }
#pragma unroll
  for (int i = 0; i < 4; i++)
    C[(size_t)(m0 + 4 * q + i) * N + n0 + cl] = acc[i];
}

// ---------------------------------------------------------------------------
// gemm_mf_pack: QKV projections (N=512, K=256) with FUSED fragment packing.
// by<32: gemm.  n0>=256 -> V half stored f32.  n0<256 (h = bx): Q/K tile is
// transposed in per-wave LDS and emitted directly as QQ4 / KH4+KL4z frags.
// by==32, bx<8: W1/W2 fragment packing (2048 threads of work).
// ---------------------------------------------------------------------------
__global__ void __launch_bounds__(256)
gemm_mf_pack(const float* __restrict__ x1, const float* __restrict__ Wqv1, float* __restrict__ qv,
             const float* __restrict__ x2, const float* __restrict__ Wkv2, float* __restrict__ kv,
             const float* __restrict__ W1, const float* __restrict__ W2,
             uint4* __restrict__ QQ4, uint4* __restrict__ KH4, uint4* __restrict__ KL4z,
             uint4* __restrict__ W1Bhi, uint4* __restrict__ W1Blo,
             uint2* __restrict__ W2Fhi, uint2* __restrict__ W2Flo) {
  __shared__ float Ld[4][16][17];
  int t = threadIdx.x, L = t & 63, w = t >> 6;
  int cl = L & 15, q = L >> 4;
  int by = blockIdx.y;

  if (by == 32) {                       // ---- W packing blocks ----
    if (blockIdx.x >= 8) return;
    int tid = blockIdx.x * 256 + t;     // 0..2047
    if (tid < 1024) {
      int LL = tid & 63;
      int j = (tid >> 6) * 16 + (LL & 15), qq = LL >> 4;
      u32 hw[4] = {0,0,0,0}, lw[4] = {0,0,0,0};
#pragma unroll
      for (int jj = 0; jj < 8; jj++) {
        float wv = W1[j * 32 + qq * 8 + jj];
        u16 hb = f2b(wv); u16 lb = f2b(wv - b2f(hb));
        hw[jj >> 1] |= ((u32)hb) << (16 * (jj & 1));
        lw[jj >> 1] |= ((u32)lb) << (16 * (jj & 1));
      }
      W1Bhi[tid] = make_uint4(hw[0], hw[1], hw[2], hw[3]);
      W1Blo[tid] = make_uint4(lw[0], lw[1], lw[2], lw[3]);
    } else {
      int t2 = tid - 1024;              // nt*64 + L
      int LL = t2 & 63, nt = t2 >> 6;
      int h = LL & 15, qq = LL >> 4;
      F16x4 hi, lo;
#pragma unroll
      for (int i = 0; i < 4; i++) {
        int j = nt * 16 + 4 * qq + i;
        float wv = W2[h * 256 + j];
        hi.h[i] = (_Float16)wv;
        lo.h[i] = (_Float16)(wv - (float)hi.h[i]);
      }
      W2Fhi[t2] = hi.u;
      W2Flo[t2] = lo.u;
    }
    return;
  }

  int sel = by >> 4;
  const float* A  = sel ? x2 : x1;
  const float* Bw = sel ? Wkv2 : Wqv1;
  float*       C  = sel ? kv : qv;
  int m0 = (by & 15) * 64 + w * 16;
  int n0 = blockIdx.x * 16;

  f32x4 acc; acc[0] = 0.f; acc[1] = 0.f; acc[2] = 0.f; acc[3] = 0.f;
  const float* ar = A  + (size_t)(m0 + cl) * 256 + 8 * q;
  const float* br = Bw + (size_t)(n0 + cl) * 256 + 8 * q;

  for (int k0 = 0; k0 < 256; k0 += 32) {
    float4 av0 = *(const float4*)(ar + k0);
    float4 av1 = *(const float4*)(ar + k0 + 4);
    float4 bv0 = *(const float4*)(br + k0);
    float4 bv1 = *(const float4*)(br + k0 + 4);
    uint4 ahi, alo, bhi, blo;
    split8(av0, av1, ahi, alo);
    split8(bv0, bv1, bhi, blo);
    acc = mfma16(ahi, bhi, acc);
    acc = mfma16(ahi, blo, acc);
    acc = mfma16(alo, bhi, acc);
  }

  if (n0 >= 256) {                      // V half: plain f32 store
#pragma unroll
    for (int i = 0; i < 4; i++)
      C[(size_t)(m0 + 4 * q + i) * 512 + n0 + cl] = acc[i];
    return;
  }

  // ---- Q/K half: per-wave 16x16 transpose, then fragment emit ----
#pragma unroll
  for (int i = 0; i < 4; i++) Ld[w][cl][4 * q + i] = acc[i];   // Ld[d][r_local]
  float v[8];
#pragma unroll
  for (int jj = 0; jj < 8; jj++) v[jj] = Ld[w][(q & 1) * 8 + jj][cl];

  int b = m0 >> 9;
  int r = (m0 & 511) + cl;
  int h = n0 >> 4;                      // == blockIdx.x

  if (sel == 0) {                       // Q: x0.25 folded; q<2 hi, q>=2 lo
    u32 wv[4];
#pragma unroll
    for (int t2 = 0; t2 < 4; t2++) {
      float a  = v[2 * t2] * 0.25f, bb = v[2 * t2 + 1] * 0.25f;
      u32 hp = pk2(a, bb);
      if (q >= 2) {
        float r0 = a  - __uint_as_float(hp << 16);
        float r1 = bb - __uint_as_float(hp & 0xffff0000u);
        wv[t2] = pk2(r0, r1);
      } else wv[t2] = hp;
    }
    QQ4[((size_t)((b * 16 + h) * 4 + q) << 9) + r] = make_uint4(wv[0], wv[1], wv[2], wv[3]);
  } else {                              // K: hi + lo + zero slots
    u32 hw[4], lw[4];
#pragma unroll
    for (int t2 = 0; t2 < 4; t2++) {
      float a = v[2 * t2], bb = v[2 * t2 + 1];
      u32 hp = pk2(a, bb);
      float r0 = a  - __uint_as_float(hp << 16);
      float r1 = bb - __uint_as_float(hp & 0xffff0000u);
      hw[t2] = hp;
      lw[t2] = pk2(r0, r1);
    }
    if (q < 2) {
      KH4[((size_t)((b * 16 + h) * 2 + q) << 9) + r]       = make_uint4(hw[0], hw[1], hw[2], hw[3]);
      KL4z[((size_t)((b * 16 + h) * 4 + 2 + q) << 9) + r]  = make_uint4(0, 0, 0, 0);
    } else {
      KL4z[((size_t)((b * 16 + h) * 4 + (q - 2)) << 9) + r] = make_uint4(lw[0], lw[1], lw[2], lw[3]);
    }
  }
}

// ---------------------------------------------------------------------------
// ms_mfma5p: all-MFMA fused QK^T + MixedScoreFF.  Weight fragments are
// register-double-buffered (prefetch nt+1 during nt's r-loop); H conversion
// uses v_cvt_pkrtz.  Wave-tile 16r x 16c.
// ---------------------------------------------------------------------------
__global__ void __launch_bounds__(256, 2)
ms_mfma5p(const uint4* __restrict__ QQ4, const uint4* __restrict__ KH4,
          const uint4* __restrict__ KL4z, const float* __restrict__ cost,
          const uint4* __restrict__ W1Bhi, const uint4* __restrict__ W1Blo,
          const uint2* __restrict__ W2Fhi, const uint2* __restrict__ W2Flo,
          u16* __restrict__ ms1, u16* __restrict__ ms2) {
  __shared__ __align__(16) u32 Dl[4 * 4160];
  int t = threadIdx.x, L = t & 63, w = t >> 6;
  int cl = L & 15, q = L >> 4;
  int b = blockIdx.z, c0 = blockIdx.x * 16, r0 = (blockIdx.y * 4 + w) * 16;
  u32* D = Dl + w * 4160;

  f32x4 z; z[0] = 0.f; z[1] = 0.f; z[2] = 0.f; z[3] = 0.f;

  // ---- phase A: QK^T (scaled) via MFMA, 16 heads -> D[h][r][c] in LDS ----
#pragma unroll 2
  for (int h = 0; h < 16; h++) {
    uint4 qa  = QQ4[((size_t)((b * 16 + h) * 4 + q) << 9) + r0 + cl];       // [qh|ql]
    uint4 qa2 = QQ4[((size_t)((b * 16 + h) * 4 + (q & 1)) << 9) + r0 + cl]; // [qh|qh]
    uint4 kb1 = KH4[((size_t)((b * 16 + h) * 2 + (q & 1)) << 9) + c0 + cl]; // [kh|kh]
    uint4 kb2 = KL4z[((size_t)((b * 16 + h) * 4 + q) << 9) + c0 + cl];      // [kl|0]
    f32x4 d = mfma16(qa, kb1, z);
    d = mfma16(qa2, kb2, d);
#pragma unroll
    for (int i = 0; i < 4; i++)
      D[h * 260 + (q * 4 + i) * 16 + cl] = __float_as_uint(d[i]);
  }

  // ---- phase A2: build X fragments (B-operand: n=cell=cl, k=8q+idx) ----
  uint4 xhi[16], xlo[16];
#pragma unroll
  for (int r = 0; r < 16; r++) {
    float cvm = cost[((size_t)(b * 512) + r0 + r) * 512 + c0 + cl];
    u32 cp = pk2(cvm, cvm);
    float cres = cvm - __uint_as_float(cp & 0xffff0000u);
    u32 hw[4], lw[4];
#pragma unroll
    for (int tt = 0; tt < 4; tt++) {
      float dd = __uint_as_float(D[(4 * q + tt) * 260 + r * 16 + cl]);
      u32 hp = pk2(dd, cvm);
      float dres = dd - __uint_as_float(hp << 16);
      hw[tt] = hp;
      lw[tt] = pk2(dres, cres);
    }
    xhi[r] = make_uint4(hw[0], hw[1], hw[2], hw[3]);
    xlo[r] = make_uint4(lw[0], lw[1], lw[2], lw[3]);
  }

  // ---- phase B: nt-outer MLP, weights register-double-buffered ----
  f32x4 acc2[16];
#pragma unroll
  for (int r = 0; r < 16; r++) acc2[r] = z;

  uint4 w1h = W1Bhi[L], w1l = W1Blo[L];
  uint2 w2hu = W2Fhi[L], w2lu = W2Flo[L];

#pragma unroll 1
  for (int nt = 0; nt < 16; nt++) {
    int np = (nt + 1) & 15;
    uint4 nw1h = W1Bhi[np * 64 + L];
    uint4 nw1l = W1Blo[np * 64 + L];
    uint2 nw2h = W2Fhi[np * 64 + L];
    uint2 nw2l = W2Flo[np * 64 + L];
    F16x4 w2h, w2l;
    w2h.u = w2hu; w2l.u = w2lu;
#pragma unroll
    for (int r = 0; r < 16; r++) {
      f32x4 a0 = z;
      a0 = mfma16(w1h, xhi[r], a0);   // W1hi . Xhi
      a0 = mfma16(w1h, xlo[r], a0);   // W1hi . Xlo
      a0 = mfma16(w1l, xhi[r], a0);   // W1lo . Xhi
      F16x4 hf;
      hf.p[0] = cvtpk(fmaxf(a0[0], 0.f), fmaxf(a0[1], 0.f));
      hf.p[1] = cvtpk(fmaxf(a0[2], 0.f), fmaxf(a0[3], 0.f));
      acc2[r] = mfma_h16(hf.v, w2h.v, acc2[r]);
      acc2[r] = mfma_h16(hf.v, w2l.v, acc2[r]);
    }
    w1h = nw1h; w1l = nw1l; w2hu = nw2h; w2lu = nw2l;
  }

  // ---- epilogue: lane (q,cl) holds MS[h=cl][c=c0+4q+i][r0..r0+15] ----
  u32* ms1u = (u32*)ms1;
#pragma unroll
  for (int r = 0; r < 16; r++) {
    size_t base = ((size_t)(b * 16 + cl) * 512 + (r0 + r)) * 256 + (c0 >> 1) + q * 2;
    ms1u[base]     = pk2(acc2[r][0], acc2[r][1]);
    ms1u[base + 1] = pk2(acc2[r][2], acc2[r][3]);
  }
  u32* ms2u = (u32*)ms2;
#pragma unroll
  for (int i = 0; i < 4; i++) {
    int c = c0 + 4 * q + i;
    u32 o[8];
#pragma unroll
    for (int rr = 0; rr < 8; rr++)
      o[rr] = pk2(acc2[2 * rr][i], acc2[2 * rr + 1][i]);
    size_t base2 = ((size_t)(b * 16 + cl) * 512 + c) * 256 + (r0 >> 1);
    *(uint4*)&ms2u[base2]     = make_uint4(o[0], o[1], o[2], o[3]);
    *(uint4*)&ms2u[base2 + 4] = make_uint4(o[4], o[5], o[6], o[7]);
  }
}

// ---------------------------------------------------------------------------
// softmax_all4: both directions (dir = blockIdx.z); block = (b, 4 fix rows).
// Phase A: wave w owns fix0+w -> masked softmax of 16 heads, p stored f16 in
// LDS.  Phase B: each V float4 load feeds 4 fix rows; cross-wave reduce.
// ---------------------------------------------------------------------------
__global__ void __launch_bounds__(256)
softmax_all4(const u16* __restrict__ ms1s, const u16* __restrict__ ms2s,
             const int* __restrict__ mask,
             const float* __restrict__ qv, const float* __restrict__ kv,
             float* __restrict__ o1, float* __restrict__ o2) {
  __shared__ _Float16 pbuf[4][16][522];
  __shared__ float    sden[4][16];
  __shared__ float4   red[4][64];
  int t = threadIdx.x, lane = t & 63, w = t >> 6;
  int fix0 = blockIdx.x * 4, b = blockIdx.y, dir = blockIdx.z;
  const u16*   ms   = dir ? ms2s : ms1s;
  const float* vbuf = dir ? qv : kv;
  float*       obuf = dir ? o2 : o1;

  // ---- phase A: wave w handles fix = fix0 + w ----
  int fix = fix0 + w;
  bool vd[8];
#pragma unroll
  for (int i = 0; i < 8; i++) {
    int cc = i * 64 + lane;
    int mv = dir ? mask[((size_t)b * 512 + cc) * 512 + fix]
                 : mask[((size_t)b * 512 + fix) * 512 + cc];
    vd[i] = mv != 0;
  }
  bool anyl = false;
#pragma unroll
  for (int i = 0; i < 8; i++) anyl |= vd[i];
  bool useMask = (__ballot(anyl) != 0ULL);   // fully-masked row => unmask all

#pragma unroll 2
  for (int h = 0; h < 16; h++) {
    const u16* mrow = ms + ((size_t)(b * 16 + h) * 512 + fix) * 512;
    float lg[8];
#pragma unroll
    for (int i = 0; i < 8; i++) lg[i] = b2f(mrow[i * 64 + lane]);
    float mx = -3.4e38f;
#pragma unroll
    for (int i = 0; i < 8; i++)
      if (!(useMask && !vd[i])) mx = fmaxf(mx, lg[i]);
    for (int off = 32; off; off >>= 1) mx = fmaxf(mx, __shfl_xor(mx, off));
    float s = 0.f;
#pragma unroll
    for (int i = 0; i < 8; i++) {
      float p = (useMask && !vd[i]) ? 0.f : __expf(lg[i] - mx);
      pbuf[w][h][i * 64 + lane] = (_Float16)p;
      s += p;
    }
    for (int off = 32; off; off >>= 1) s += __shfl_xor(s, off);
    if (lane == 0) sden[w][h] = s;
  }
  __syncthreads();

  // ---- phase B: thread (w, hb=lane>>2, dq=lane&3) accumulates cc = 4*it+w ----
  int hb = lane >> 2, dq = lane & 3;
  const float* vb = vbuf + (size_t)b * 262144 + 256 + hb * 16 + dq * 4;
  float4 acc[4];
#pragma unroll
  for (int f = 0; f < 4; f++) acc[f] = make_float4(0.f, 0.f, 0.f, 0.f);
  for (int it = 0; it < 128; it++) {
    int cc = it * 4 + w;
    float4 v = *(const float4*)(vb + (size_t)cc * 512);
#pragma unroll
    for (int f = 0; f < 4; f++) {
      float p = (float)pbuf[f][hb][cc];
      acc[f].x += p * v.x; acc[f].y += p * v.y;
      acc[f].z += p * v.z; acc[f].w += p * v.w;
    }
  }
#pragma unroll 1
  for (int f = 0; f < 4; f++) {
    red[w][lane] = acc[f];
    __syncthreads();
    if (w == 0) {
      float4 s0 = red[0][lane], s1 = red[1][lane];
      float4 s2 = red[2][lane], s3 = red[3][lane];
      float inv = 1.f / sden[f][hb];
      float4 o;
      o.x = (s0.x + s1.x + s2.x + s3.x) * inv;
      o.y = (s0.y + s1.y + s2.y + s3.y) * inv;
      o.z = (s0.z + s1.z + s2.z + s3.z) * inv;
      o.w = (s0.w + s1.w + s2.w + s3.w) * inv;
      *(float4*)(obuf + ((size_t)b * 512 + fix0 + f) * 256 + lane * 4) = o;
    }
    __syncthreads();
  }
}

// ---------------------------------------------------------------------------
extern "C" void kernel_launch(void* const* d_in, const int* in_sizes, int n_in,
                              void* d_out, int out_size, void* d_ws, size_t ws_size,
                              hipStream_t stream) {
  const float* x1    = (const float*)d_in[0];
  const float* x2    = (const float*)d_in[1];
  const int*   attn  = (const int*)d_in[2];
  const float* cost  = (const float*)d_in[3];
  const float* Wqv1  = (const float*)d_in[4];
  const float* Wkv2  = (const float*)d_in[5];
  const float* W1    = (const float*)d_in[6];
  const float* W2    = (const float*)d_in[7];
  const float* Wout1 = (const float*)d_in[8];
  const float* Wout2 = (const float*)d_in[9];
  float* out = (float*)d_out;

  char* ws = (char*)d_ws;
  uint4* W1Bhi = (uint4*)(ws);                               // 16 KB
  uint4* W1Blo = (uint4*)(ws + (16 << 10));                  // 16 KB
  uint2* W2Fhi = (uint2*)(ws + (32 << 10));                  //  8 KB
  uint2* W2Flo = (uint2*)(ws + (40 << 10));                  //  8 KB
  float* qv  = (float*)(ws + (64 << 10));                    //   2 MB [b][r][512] (V half live)
  float* kv  = (float*)(ws + (64 << 10) + (2 << 20));        //   2 MB [b][c][512] (V half live)
  u16*   ms1 = (u16*)  (ws + (64 << 10) + (4 << 20));        //  16 MB [b][h][r][c]
  u16*   ms2 = (u16*)  (ws + (64 << 10) + (20 << 20));       //  16 MB [b][h][c][r]
  char*  tail= (ws + (64 << 10) + (36 << 20));
  uint4* QQ4  = (uint4*)(tail);                              //   1 MB
  uint4* KH4  = (uint4*)(tail + (1 << 20));                  // 0.5 MB
  uint4* KL4z = (uint4*)(tail + (1 << 20) + (512 << 10));    //   1 MB
  float* o1  = (float*)(tail + (3 << 20));                   //   1 MB [b][r][256]
  float* o2  = (float*)(tail + (4 << 20));                   //   1 MB [b][c][256]

  gemm_mf_pack<<<dim3(32, 33), 256, 0, stream>>>(x1, Wqv1, qv, x2, Wkv2, kv,
                                                 W1, W2, QQ4, KH4, KL4z,
                                                 W1Bhi, W1Blo, W2Fhi, W2Flo);

  ms_mfma5p<<<dim3(32, 8, 2), 256, 0, stream>>>(QQ4, KH4, KL4z, cost,
                                                W1Bhi, W1Blo, W2Fhi, W2Flo, ms1, ms2);

  softmax_all4<<<dim3(128, 2, 2), 256, 0, stream>>>(ms1, ms2, attn, qv, kv, o1, o2);

  gemm_mf<<<dim3(16, 32), 256, 0, stream>>>(o1, Wout1, out, o2, Wout2, out + (size_t)262144, 256, 256);
}

// Round 12
// 172.822 us; speedup vs baseline: 3.2593x; 1.0335x over previous
//
#include <hip/hip_runtime.h>
#include <hip/hip_bf16.h>

typedef unsigned int   u32;
typedef unsigned short u16;

typedef __attribute__((ext_vector_type(8))) short    sh8;
typedef __attribute__((ext_vector_type(4))) float    f32x4;
typedef __attribute__((ext_vector_type(4))) _Float16 f16x4;
typedef __attribute__((ext_vector_type(8))) _Float16 f16x8;
typedef __attribute__((ext_vector_type(2))) _Float16 f16x2;
typedef __attribute__((ext_vector_type(2))) __fp16   fp16x2raw;

union F16x8 { f16x8 v; uint4 u; f16x2 p[4]; _Float16 h[8]; };
union F16x4u { uint2 u; _Float16 h[4]; };
union CvtU  { fp16x2raw r; f16x2 p; u32 u; };

__device__ __forceinline__ float b2f(u16 u) { union { u32 i; float f; } v; v.i = ((u32)u) << 16; return v.f; }
__device__ __forceinline__ u16   f2b(float f){
  union { float f; u32 i; } v; v.f = f;
  u32 u = v.i;
  u32 r = (u + 0x7fffu + ((u >> 16) & 1u)) >> 16;   // RNE
  return (u16)r;
}
// pack two f32 -> bf16x2 (RNE), lo half = a, hi half = b
__device__ __forceinline__ u32 pk2(float a, float b) {
  __hip_bfloat162 h2 = __float22bfloat162_rn(make_float2(a, b));
  union { __hip_bfloat162 h; u32 u; } v; v.h = h2; return v.u;
}
__device__ __forceinline__ f16x2 cvtpk(float a, float b) {
  CvtU c; c.r = __builtin_amdgcn_cvt_pkrtz(a, b); return c.p;
}
__device__ __forceinline__ u32 cvtpku(float a, float b) {
  CvtU c; c.r = __builtin_amdgcn_cvt_pkrtz(a, b); return c.u;
}

__device__ __forceinline__ f32x4 mfma16(uint4 a, uint4 b, f32x4 c) {
  union { uint4 u; sh8 s; } ua, ub;
  ua.u = a; ub.u = b;
  return __builtin_amdgcn_mfma_f32_16x16x32_bf16(ua.s, ub.s, c, 0, 0, 0);
}
__device__ __forceinline__ f32x4 mfma32h(f16x8 a, f16x8 b, f32x4 c) {
  return __builtin_amdgcn_mfma_f32_16x16x32_f16(a, b, c, 0, 0, 0);
}

// split 8 consecutive f32 (one lane's K-chunk) into bf16 hi/lo operand words
__device__ __forceinline__ void split8(float4 v0, float4 v1, uint4& hi, uint4& lo) {
  float a[8] = {v0.x, v0.y, v0.z, v0.w, v1.x, v1.y, v1.z, v1.w};
  u32 hw[4], lw[4];
#pragma unroll
  for (int t = 0; t < 4; t++) {
    u32 hp = pk2(a[2 * t], a[2 * t + 1]);
    float r0 = a[2 * t]     - __uint_as_float(hp << 16);
    float r1 = a[2 * t + 1] - __uint_as_float(hp & 0xffff0000u);
    hw[t] = hp;
    lw[t] = pk2(r0, r1);
  }
  hi = make_uint4(hw[0], hw[1], hw[2], hw[3]);
  lo = make_uint4(lw[0], lw[1], lw[2], lw[3]);
}

// ---------------------------------------------------------------------------
// gemm_mf: two independent C = A @ B^T f32 GEMMs via MFMA (sel = by>>4).
// One wave per 16x16 C tile.  Used for the output projections (N=256, K=256).
// ---------------------------------------------------------------------------
__global__ void __launch_bounds__(256)
gemm_mf(const float* __restrict__ A0, const float* __restrict__ B0, float* __restrict__ C0,
        const float* __restrict__ A1, const float* __restrict__ B1, float* __restrict__ C1,
        int N, int K) {
  int t = threadIdx.x, L = t & 63, w = t >> 6;
  int cl = L & 15, q = L >> 4;
  int by = blockIdx.y, sel = by >> 4;
  const float* A  = sel ? A1 : A0;
  const float* Bw = sel ? B1 : B0;
  float*       C  = sel ? C1 : C0;
  int m0 = (by & 15) * 64 + w * 16;
  int n0 = blockIdx.x * 16;

  f32x4 acc; acc[0] = 0.f; acc[1] = 0.f; acc[2] = 0.f; acc[3] = 0.f;
  const float* ar = A  + (size_t)(m0 + cl) * K + 8 * q;
  const float* br = Bw + (size_t)(n0 + cl) * K + 8 * q;

  for (int k0 = 0; k0 < K; k0 += 32) {
    float4 av0 = *(const float4*)(ar + k0);
    float4 av1 = *(const float4*)(ar + k0 + 4);
    float4 bv0 = *(const float4*)(br + k0);
    float4 bv1 = *(const float4*)(br + k0 + 4);
    uint4 ahi, alo, bhi, blo;
    split8(av0, av1, ahi, alo);
    split8(bv0, bv1, bhi, blo);
    acc = mfma16(ahi, bhi, acc);
    acc = mfma16(ahi, blo, acc);
    acc = mfma16(alo, bhi, acc);
  }
#pragma unroll
  for (int i = 0; i < 4; i++)
    C[(size_t)(m0 + 4 * q + i) * N + n0 + cl] = acc[i];
}

// ---------------------------------------------------------------------------
// gemm_mf_pack: QKV projections (N=512, K=256) with FUSED fragment packing.
// by<32: gemm.  n0>=256 -> V stored f16 [b][row][256] (via Ld transpose).
// n0<256 (h = bx): Q/K tile transposed in per-wave LDS, emitted as frags.
// by==32, bx<8: W1 (bf16 hi/lo) + W2 (f16x8 paired-nt mapping) packing.
// ---------------------------------------------------------------------------
__global__ void __launch_bounds__(256)
gemm_mf_pack(const float* __restrict__ x1, const float* __restrict__ Wqv1, u16* __restrict__ vh1,
             const float* __restrict__ x2, const float* __restrict__ Wkv2, u16* __restrict__ vh2,
             const float* __restrict__ W1, const float* __restrict__ W2,
             uint4* __restrict__ QQ4, uint4* __restrict__ KH4, uint4* __restrict__ KL4z,
             uint4* __restrict__ W1Bhi, uint4* __restrict__ W1Blo,
             uint4* __restrict__ W2F8hi, uint4* __restrict__ W2F8lo) {
  __shared__ float Ld[4][16][17];
  int t = threadIdx.x, L = t & 63, w = t >> 6;
  int cl = L & 15, q = L >> 4;
  int by = blockIdx.y;

  if (by == 32) {                       // ---- W packing blocks ----
    if (blockIdx.x >= 8) return;
    int tid = blockIdx.x * 256 + t;     // 0..2047
    if (tid < 1024) {
      int LL = tid & 63;
      int j = (tid >> 6) * 16 + (LL & 15), qq = LL >> 4;
      u32 hw[4] = {0,0,0,0}, lw[4] = {0,0,0,0};
#pragma unroll
      for (int jj = 0; jj < 8; jj++) {
        float wv = W1[j * 32 + qq * 8 + jj];
        u16 hb = f2b(wv); u16 lb = f2b(wv - b2f(hb));
        hw[jj >> 1] |= ((u32)hb) << (16 * (jj & 1));
        lw[jj >> 1] |= ((u32)lb) << (16 * (jj & 1));
      }
      W1Bhi[tid] = make_uint4(hw[0], hw[1], hw[2], hw[3]);
      W1Blo[tid] = make_uint4(lw[0], lw[1], lw[2], lw[3]);
    } else if (tid < 1536) {
      int t2 = tid - 1024;              // p*64 + L
      int LL = t2 & 63, p = t2 >> 6;
      int h = LL & 15, qq = LL >> 4;
      F16x8 hi, lo;
#pragma unroll
      for (int jj = 0; jj < 8; jj++) {
        int j = 32 * p + ((jj >> 2) << 4) + 4 * qq + (jj & 3);
        float wv = W2[h * 256 + j];
        hi.h[jj] = (_Float16)wv;
        lo.h[jj] = (_Float16)(wv - (float)hi.h[jj]);
      }
      W2F8hi[t2] = hi.u;
      W2F8lo[t2] = lo.u;
    }
    return;
  }

  int sel = by >> 4;
  const float* A  = sel ? x2 : x1;
  const float* Bw = sel ? Wkv2 : Wqv1;
  int m0 = (by & 15) * 64 + w * 16;
  int n0 = blockIdx.x * 16;

  f32x4 acc; acc[0] = 0.f; acc[1] = 0.f; acc[2] = 0.f; acc[3] = 0.f;
  const float* ar = A  + (size_t)(m0 + cl) * 256 + 8 * q;
  const float* br = Bw + (size_t)(n0 + cl) * 256 + 8 * q;

  for (int k0 = 0; k0 < 256; k0 += 32) {
    float4 av0 = *(const float4*)(ar + k0);
    float4 av1 = *(const float4*)(ar + k0 + 4);
    float4 bv0 = *(const float4*)(br + k0);
    float4 bv1 = *(const float4*)(br + k0 + 4);
    uint4 ahi, alo, bhi, blo;
    split8(av0, av1, ahi, alo);
    split8(bv0, bv1, bhi, blo);
    acc = mfma16(ahi, bhi, acc);
    acc = mfma16(ahi, blo, acc);
    acc = mfma16(alo, bhi, acc);
  }

  int b = m0 >> 9;
  int row = (m0 & 511) + cl;            // r (or c) index after transpose

  if (n0 >= 256) {                      // ---- V half: f16 store via transpose ----
#pragma unroll
    for (int i = 0; i < 4; i++) Ld[w][cl][4 * q + i] = acc[i];
    if (q < 2) {
      float v[8];
#pragma unroll
      for (int jj = 0; jj < 8; jj++) v[jj] = Ld[w][q * 8 + jj][cl];
      uint4 o = make_uint4(cvtpku(v[0], v[1]), cvtpku(v[2], v[3]),
                           cvtpku(v[4], v[5]), cvtpku(v[6], v[7]));
      u16* vh = sel ? vh2 : vh1;
      *(uint4*)(vh + ((size_t)(b * 512) + row) * 256 + (n0 - 256) + q * 8) = o;
    }
    return;
  }

  // ---- Q/K half: per-wave 16x16 transpose, then fragment emit ----
#pragma unroll
  for (int i = 0; i < 4; i++) Ld[w][cl][4 * q + i] = acc[i];   // Ld[d][r_local]
  float v[8];
#pragma unroll
  for (int jj = 0; jj < 8; jj++) v[jj] = Ld[w][(q & 1) * 8 + jj][cl];

  int r = row;
  int h = n0 >> 4;                      // == blockIdx.x

  if (sel == 0) {                       // Q: x0.25 folded; q<2 hi, q>=2 lo
    u32 wv[4];
#pragma unroll
    for (int t2 = 0; t2 < 4; t2++) {
      float a  = v[2 * t2] * 0.25f, bb = v[2 * t2 + 1] * 0.25f;
      u32 hp = pk2(a, bb);
      if (q >= 2) {
        float r0 = a  - __uint_as_float(hp << 16);
        float r1 = bb - __uint_as_float(hp & 0xffff0000u);
        wv[t2] = pk2(r0, r1);
      } else wv[t2] = hp;
    }
    QQ4[((size_t)((b * 16 + h) * 4 + q) << 9) + r] = make_uint4(wv[0], wv[1], wv[2], wv[3]);
  } else {                              // K: hi + lo + zero slots
    u32 hw[4], lw[4];
#pragma unroll
    for (int t2 = 0; t2 < 4; t2++) {
      float a = v[2 * t2], bb = v[2 * t2 + 1];
      u32 hp = pk2(a, bb);
      float r0 = a  - __uint_as_float(hp << 16);
      float r1 = bb - __uint_as_float(hp & 0xffff0000u);
      hw[t2] = hp;
      lw[t2] = pk2(r0, r1);
    }
    if (q < 2) {
      KH4[((size_t)((b * 16 + h) * 2 + q) << 9) + r]       = make_uint4(hw[0], hw[1], hw[2], hw[3]);
      KL4z[((size_t)((b * 16 + h) * 4 + 2 + q) << 9) + r]  = make_uint4(0, 0, 0, 0);
    } else {
      KL4z[((size_t)((b * 16 + h) * 4 + (q - 2)) << 9) + r] = make_uint4(lw[0], lw[1], lw[2], lw[3]);
    }
  }
}

// ---------------------------------------------------------------------------
// ms_mfma6: all-MFMA fused QK^T + MixedScoreFF.  Layer2 hi and lo of TWO
// nt-groups fused into single K=32 f16 MFMAs (A = [hf0|hf1]): 8 MFMAs per
// (p,r) instead of 10.  Plain in-loop weight loads (r11: prefetch regressed).
// ---------------------------------------------------------------------------
__global__ void __launch_bounds__(256, 2)
ms_mfma6(const uint4* __restrict__ QQ4, const uint4* __restrict__ KH4,
         const uint4* __restrict__ KL4z, const float* __restrict__ cost,
         const uint4* __restrict__ W1Bhi, const uint4* __restrict__ W1Blo,
         const uint4* __restrict__ W2F8hi, const uint4* __restrict__ W2F8lo,
         u16* __restrict__ ms1, u16* __restrict__ ms2) {
  __shared__ __align__(16) u32 Dl[4 * 4160];
  int t = threadIdx.x, L = t & 63, w = t >> 6;
  int cl = L & 15, q = L >> 4;
  int b = blockIdx.z, c0 = blockIdx.x * 16, r0 = (blockIdx.y * 4 + w) * 16;
  u32* D = Dl + w * 4160;

  f32x4 z; z[0] = 0.f; z[1] = 0.f; z[2] = 0.f; z[3] = 0.f;

  // ---- phase A: QK^T (scaled) via MFMA, 16 heads -> D[h][r][c] in LDS ----
#pragma unroll 2
  for (int h = 0; h < 16; h++) {
    uint4 qa  = QQ4[((size_t)((b * 16 + h) * 4 + q) << 9) + r0 + cl];       // [qh|ql]
    uint4 qa2 = QQ4[((size_t)((b * 16 + h) * 4 + (q & 1)) << 9) + r0 + cl]; // [qh|qh]
    uint4 kb1 = KH4[((size_t)((b * 16 + h) * 2 + (q & 1)) << 9) + c0 + cl]; // [kh|kh]
    uint4 kb2 = KL4z[((size_t)((b * 16 + h) * 4 + q) << 9) + c0 + cl];      // [kl|0]
    f32x4 d = mfma16(qa, kb1, z);
    d = mfma16(qa2, kb2, d);
#pragma unroll
    for (int i = 0; i < 4; i++)
      D[h * 260 + (q * 4 + i) * 16 + cl] = __float_as_uint(d[i]);
  }

  // ---- phase A2: build X fragments (B-operand: n=cell=cl, k=8q+idx) ----
  uint4 xhi[16], xlo[16];
#pragma unroll
  for (int r = 0; r < 16; r++) {
    float cvm = cost[((size_t)(b * 512) + r0 + r) * 512 + c0 + cl];
    u32 cp = pk2(cvm, cvm);
    float cres = cvm - __uint_as_float(cp & 0xffff0000u);
    u32 hw[4], lw[4];
#pragma unroll
    for (int tt = 0; tt < 4; tt++) {
      float dd = __uint_as_float(D[(4 * q + tt) * 260 + r * 16 + cl]);
      u32 hp = pk2(dd, cvm);
      float dres = dd - __uint_as_float(hp << 16);
      hw[tt] = hp;
      lw[tt] = pk2(dres, cres);
    }
    xhi[r] = make_uint4(hw[0], hw[1], hw[2], hw[3]);
    xlo[r] = make_uint4(lw[0], lw[1], lw[2], lw[3]);
  }

  // ---- phase B: p-outer MLP over nt-pairs (nt = 2p, 2p+1) ----
  f32x4 acc2[16];
#pragma unroll
  for (int r = 0; r < 16; r++) acc2[r] = z;

#pragma unroll 1
  for (int p = 0; p < 8; p++) {
    uint4 w1h0 = W1Bhi[(2 * p) * 64 + L],     w1l0 = W1Blo[(2 * p) * 64 + L];
    uint4 w1h1 = W1Bhi[(2 * p + 1) * 64 + L], w1l1 = W1Blo[(2 * p + 1) * 64 + L];
    F16x8 w2h, w2l;
    w2h.u = W2F8hi[p * 64 + L];
    w2l.u = W2F8lo[p * 64 + L];
#pragma unroll
    for (int r = 0; r < 16; r++) {
      f32x4 a0 = z, a1 = z;
      a0 = mfma16(w1h0, xhi[r], a0);
      a0 = mfma16(w1h0, xlo[r], a0);
      a0 = mfma16(w1l0, xhi[r], a0);
      a1 = mfma16(w1h1, xhi[r], a1);
      a1 = mfma16(w1h1, xlo[r], a1);
      a1 = mfma16(w1l1, xhi[r], a1);
      F16x8 hf;
      hf.p[0] = cvtpk(fmaxf(a0[0], 0.f), fmaxf(a0[1], 0.f));
      hf.p[1] = cvtpk(fmaxf(a0[2], 0.f), fmaxf(a0[3], 0.f));
      hf.p[2] = cvtpk(fmaxf(a1[0], 0.f), fmaxf(a1[1], 0.f));
      hf.p[3] = cvtpk(fmaxf(a1[2], 0.f), fmaxf(a1[3], 0.f));
      acc2[r] = mfma32h(hf.v, w2h.v, acc2[r]);
      acc2[r] = mfma32h(hf.v, w2l.v, acc2[r]);
    }
  }

  // ---- epilogue: lane (q,cl) holds MS[h=cl][c=c0+4q+i][r0..r0+15] ----
  u32* ms1u = (u32*)ms1;
#pragma unroll
  for (int r = 0; r < 16; r++) {
    size_t base = ((size_t)(b * 16 + cl) * 512 + (r0 + r)) * 256 + (c0 >> 1) + q * 2;
    ms1u[base]     = pk2(acc2[r][0], acc2[r][1]);
    ms1u[base + 1] = pk2(acc2[r][2], acc2[r][3]);
  }
  u32* ms2u = (u32*)ms2;
#pragma unroll
  for (int i = 0; i < 4; i++) {
    int c = c0 + 4 * q + i;
    u32 o[8];
#pragma unroll
    for (int rr = 0; rr < 8; rr++)
      o[rr] = pk2(acc2[2 * rr][i], acc2[2 * rr + 1][i]);
    size_t base2 = ((size_t)(b * 16 + cl) * 512 + c) * 256 + (r0 >> 1);
    *(uint4*)&ms2u[base2]     = make_uint4(o[0], o[1], o[2], o[3]);
    *(uint4*)&ms2u[base2 + 4] = make_uint4(o[4], o[5], o[6], o[7]);
  }
}

// ---------------------------------------------------------------------------
// softmax_all5: both directions (dir = blockIdx.z); block = (b, 4 fix rows).
// p stored f16 in swizzled LDS [cc][(h+cc)&15][f] -> phase B reads all 4 f
// values with ONE ds_read_b64 (conflict-free).  V read f16 (vh buffers).
// ---------------------------------------------------------------------------
__global__ void __launch_bounds__(256)
softmax_all5(const u16* __restrict__ ms1s, const u16* __restrict__ ms2s,
             const int* __restrict__ mask,
             const u16* __restrict__ vh1, const u16* __restrict__ vh2,
             float* __restrict__ o1, float* __restrict__ o2) {
  __shared__ _Float16 pbuf[512 * 16 * 4];   // [cc][(h+cc)&15][f]  64 KB
  __shared__ float    sden[4][16];
  __shared__ float4   red[4][64];
  int t = threadIdx.x, lane = t & 63, w = t >> 6;
  int fix0 = blockIdx.x * 4, b = blockIdx.y, dir = blockIdx.z;
  const u16* ms   = dir ? ms2s : ms1s;
  const u16* vbuf = dir ? vh1 : vh2;
  float*     obuf = dir ? o2 : o1;

  // ---- phase A: wave w handles fix = fix0 + w ----
  int fix = fix0 + w;
  bool vd[8];
#pragma unroll
  for (int i = 0; i < 8; i++) {
    int cc = i * 64 + lane;
    int mv = dir ? mask[((size_t)b * 512 + cc) * 512 + fix]
                 : mask[((size_t)b * 512 + fix) * 512 + cc];
    vd[i] = mv != 0;
  }
  bool anyl = false;
#pragma unroll
  for (int i = 0; i < 8; i++) anyl |= vd[i];
  bool useMask = (__ballot(anyl) != 0ULL);   // fully-masked row => unmask all

#pragma unroll 2
  for (int h = 0; h < 16; h++) {
    const u16* mrow = ms + ((size_t)(b * 16 + h) * 512 + fix) * 512;
    float lg[8];
#pragma unroll
    for (int i = 0; i < 8; i++) lg[i] = b2f(mrow[i * 64 + lane]);
    float mx = -3.4e38f;
#pragma unroll
    for (int i = 0; i < 8; i++)
      if (!(useMask && !vd[i])) mx = fmaxf(mx, lg[i]);
    for (int off = 32; off; off >>= 1) mx = fmaxf(mx, __shfl_xor(mx, off));
    float s = 0.f;
#pragma unroll
    for (int i = 0; i < 8; i++) {
      float p = (useMask && !vd[i]) ? 0.f : __expf(lg[i] - mx);
      int cc = i * 64 + lane;
      pbuf[(cc * 16 + ((h + cc) & 15)) * 4 + w] = (_Float16)p;
      s += p;
    }
    for (int off = 32; off; off >>= 1) s += __shfl_xor(s, off);
    if (lane == 0) sden[w][h] = s;
  }
  __syncthreads();

  // ---- phase B: thread (w, hb=lane>>2, dq=lane&3) accumulates cc = 4*it+w ----
  int hb = lane >> 2, dq = lane & 3;
  const u16* vb = vbuf + (size_t)b * 131072 + hb * 16 + dq * 4;
  float4 acc[4];
#pragma unroll
  for (int f = 0; f < 4; f++) acc[f] = make_float4(0.f, 0.f, 0.f, 0.f);
  for (int it = 0; it < 128; it++) {
    int cc = it * 4 + w;
    F16x4u vv; vv.u = *(const uint2*)(vb + (size_t)cc * 256);
    F16x4u pv; pv.u = *(const uint2*)&pbuf[(cc * 16 + ((hb + cc) & 15)) * 4];
    float v0 = (float)vv.h[0], v1 = (float)vv.h[1];
    float v2 = (float)vv.h[2], v3 = (float)vv.h[3];
#pragma unroll
    for (int f = 0; f < 4; f++) {
      float p = (float)pv.h[f];
      acc[f].x += p * v0; acc[f].y += p * v1;
      acc[f].z += p * v2; acc[f].w += p * v3;
    }
  }
#pragma unroll 1
  for (int f = 0; f < 4; f++) {
    red[w][lane] = acc[f];
    __syncthreads();
    if (w == 0) {
      float4 s0 = red[0][lane], s1 = red[1][lane];
      float4 s2 = red[2][lane], s3 = red[3][lane];
      float inv = 1.f / sden[f][hb];
      float4 o;
      o.x = (s0.x + s1.x + s2.x + s3.x) * inv;
      o.y = (s0.y + s1.y + s2.y + s3.y) * inv;
      o.z = (s0.z + s1.z + s2.z + s3.z) * inv;
      o.w = (s0.w + s1.w + s2.w + s3.w) * inv;
      *(float4*)(obuf + ((size_t)b * 512 + fix0 + f) * 256 + lane * 4) = o;
    }
    __syncthreads();
  }
}

// ---------------------------------------------------------------------------
extern "C" void kernel_launch(void* const* d_in, const int* in_sizes, int n_in,
                              void* d_out, int out_size, void* d_ws, size_t ws_size,
                              hipStream_t stream) {
  const float* x1    = (const float*)d_in[0];
  const float* x2    = (const float*)d_in[1];
  const int*   attn  = (const int*)d_in[2];
  const float* cost  = (const float*)d_in[3];
  const float* Wqv1  = (const float*)d_in[4];
  const float* Wkv2  = (const float*)d_in[5];
  const float* W1    = (const float*)d_in[6];
  const float* W2    = (const float*)d_in[7];
  const float* Wout1 = (const float*)d_in[8];
  const float* Wout2 = (const float*)d_in[9];
  float* out = (float*)d_out;

  char* ws = (char*)d_ws;
  uint4* W1Bhi  = (uint4*)(ws);                              // 16 KB
  uint4* W1Blo  = (uint4*)(ws + (16 << 10));                 // 16 KB
  uint4* W2F8hi = (uint4*)(ws + (32 << 10));                 //  8 KB
  uint4* W2F8lo = (uint4*)(ws + (40 << 10));                 //  8 KB
  u16*   vh1 = (u16*)(ws + (64 << 10));                      // 512 KB [b][r][256] f16 (v1)
  u16*   vh2 = (u16*)(ws + (64 << 10) + (512 << 10));        // 512 KB [b][c][256] f16 (v2)
  u16*   ms1 = (u16*)(ws + (64 << 10) + (4 << 20));          //  16 MB [b][h][r][c]
  u16*   ms2 = (u16*)(ws + (64 << 10) + (20 << 20));         //  16 MB [b][h][c][r]
  char*  tail= (ws + (64 << 10) + (36 << 20));
  uint4* QQ4  = (uint4*)(tail);                              //   1 MB
  uint4* KH4  = (uint4*)(tail + (1 << 20));                  // 0.5 MB
  uint4* KL4z = (uint4*)(tail + (1 << 20) + (512 << 10));    //   1 MB
  float* o1  = (float*)(tail + (3 << 20));                   //   1 MB [b][r][256]
  float* o2  = (float*)(tail + (4 << 20));                   //   1 MB [b][c][256]

  gemm_mf_pack<<<dim3(32, 33), 256, 0, stream>>>(x1, Wqv1, vh1, x2, Wkv2, vh2,
                                                 W1, W2, QQ4, KH4, KL4z,
                                                 W1Bhi, W1Blo, W2F8hi, W2F8lo);

  ms_mfma6<<<dim3(32, 8, 2), 256, 0, stream>>>(QQ4, KH4, KL4z, cost,
                                               W1Bhi, W1Blo, W2F8hi, W2F8lo, ms1, ms2);

  softmax_all5<<<dim3(128, 2, 2), 256, 0, stream>>>(ms1, ms2, attn, vh1, vh2, o1, o2);

  gemm_mf<<<dim3(16, 32), 256, 0, stream>>>(o1, Wout1, out, o2, Wout2, out + (size_t)262144, 256, 256);
}